// Round 11
// baseline (2828.147 us; speedup 1.0000x reference)
//
#include <hip/hip_runtime.h>
#include <math.h>

#define SS 512
#define BB 8
#define NHH 12
#define DD 64
#define HH 768
#define II 2048
#define LL 12
#define SCALE_F 0.07216878364870323f  /* 1/sqrt(3*64) */

typedef __attribute__((ext_vector_type(8))) short bf16x8;
typedef __attribute__((ext_vector_type(4))) float f32x4;

// f32 -> bf16 (RNE, finite values)
__device__ __forceinline__ unsigned short f2b(float f) {
    union { float f; unsigned int u; } x; x.f = f;
    unsigned int r = x.u + 0x7fffu + ((x.u >> 16) & 1u);
    return (unsigned short)(r >> 16);
}
__device__ __forceinline__ float b2f(unsigned short u) {
    union { unsigned int u; float f; } x; x.u = ((unsigned int)u) << 16;
    return x.f;
}

// ---------------------------------------------------------------------------
// block reduction helpers (blockDim.x == 256)
// ---------------------------------------------------------------------------
__device__ __forceinline__ float2 blockReduceSum2(float a, float b) {
    __shared__ float2 sm[4];
    __shared__ float2 bc;
#pragma unroll
    for (int o = 32; o > 0; o >>= 1) {
        a += __shfl_down(a, o);
        b += __shfl_down(b, o);
    }
    int t = threadIdx.x;
    if ((t & 63) == 0) sm[t >> 6] = make_float2(a, b);
    __syncthreads();
    if (t == 0) {
        float xa = sm[0].x + sm[1].x + sm[2].x + sm[3].x;
        float xb = sm[0].y + sm[1].y + sm[2].y + sm[3].y;
        bc = make_float2(xa, xb);
    }
    __syncthreads();
    return bc;
}

__device__ __forceinline__ float gelu_erf(float v) {
    return 0.5f * v * (1.0f + erff(v * 0.70710678118654752f));
}
__device__ __forceinline__ float gelu_tanh(float v) {
    const float c = 0.7978845608028654f;
    return 0.5f * v * (1.0f + tanhf(c * (v + 0.044715f * v * v * v)));
}

// ---------------------------------------------------------------------------
// mask decode: handle bool-as-u8 or bool-as-int32 layouts
// ---------------------------------------------------------------------------
__global__ __launch_bounds__(256) void k_decode_mask(const unsigned char* __restrict__ raw,
                                                     int* __restrict__ mask, int n) {
    __shared__ int s_any;
    if (threadIdx.x == 0) s_any = 0;
    __syncthreads();
    int local = 0;
    for (int i = threadIdx.x; i < n; i += blockDim.x)
        if ((i & 3) && raw[i]) local = 1;
    if (local) atomicOr(&s_any, 1);
    __syncthreads();
    bool isU8 = (s_any != 0);
    const int* as_int = (const int*)raw;
    for (int i = threadIdx.x; i < n; i += blockDim.x)
        mask[i] = isU8 ? (raw[i] != 0) : (as_int[i] != 0);
}

// ---------------------------------------------------------------------------
// DeBERTa log-bucket table: rel in [-511,511] -> idx in [0,62]
// ---------------------------------------------------------------------------
__global__ __launch_bounds__(256) void k_bucket(int* __restrict__ tab) {
    int i = blockIdx.x * 256 + threadIdx.x;
    if (i >= 1023) return;
    int rel = i - 511;
    int a = rel < 0 ? -rel : rel;
    int abs_pos = (a < 16) ? 15 : (a < 511 ? a : 511);
    int bucket;
    if (abs_pos <= 16) {
        bucket = rel;
    } else {
        double lp = ceil(log((double)abs_pos / 16.0) / log(511.0 / 16.0) * 15.0);
        int l = (int)lp + 16;
        bucket = (rel > 0) ? l : -l;
    }
    int idx = bucket + 31;
    if (idx < 0) idx = 0;
    if (idx > 62) idx = 62;
    tab[i] = idx;
}

// ---------------------------------------------------------------------------
// generic f32 -> bf16 bulk conversion (8 elems/thread)
// ---------------------------------------------------------------------------
__global__ __launch_bounds__(256) void k_f2b(const float* __restrict__ in,
                                             unsigned short* __restrict__ out, int n8) {
    int i = blockIdx.x * 256 + threadIdx.x;
    if (i >= n8) return;
    float4 a = ((const float4*)in)[2 * (size_t)i];
    float4 b = ((const float4*)in)[2 * (size_t)i + 1];
    ushort4 lo, hi;
    lo.x = f2b(a.x); lo.y = f2b(a.y); lo.z = f2b(a.z); lo.w = f2b(a.w);
    hi.x = f2b(b.x); hi.y = f2b(b.y); hi.z = f2b(b.z); hi.w = f2b(b.w);
    ((ushort4*)out)[2 * (size_t)i] = lo;
    ((ushort4*)out)[2 * (size_t)i + 1] = hi;
}

// ---------------------------------------------------------------------------
// merged: per-layer weight conversion (blocks 0..3168) + LN of x (blocks 3169..7264)
// ---------------------------------------------------------------------------
__global__ __launch_bounds__(256) void k_f2b_ln(const float* __restrict__ wvg,
                                                const float* __restrict__ wout,
                                                const float* __restrict__ w1,
                                                const float* __restrict__ w2,
                                                unsigned short* __restrict__ wbf,
                                                const float* __restrict__ x,
                                                unsigned short* __restrict__ hs) {
    int bid = blockIdx.x;
    int t = threadIdx.x;
    if (bid < 3169) {
        int i = bid * 256 + t;
        if (i >= 811008) return;
        const float* src;
        int off;
        if (i < 221184) {
            if (i < 147456) { src = wvg;  off = i; }
            else            { src = wout; off = i - 147456; }
        } else if (i < 614400) { src = w1; off = i - 221184; }
        else                   { src = w2; off = i - 614400; }
        float4 a = ((const float4*)src)[2 * (size_t)off];
        float4 b = ((const float4*)src)[2 * (size_t)off + 1];
        ushort4 lo, hi;
        lo.x = f2b(a.x); lo.y = f2b(a.y); lo.z = f2b(a.z); lo.w = f2b(a.w);
        hi.x = f2b(b.x); hi.y = f2b(b.y); hi.z = f2b(b.z); hi.w = f2b(b.w);
        ((ushort4*)wbf)[2 * (size_t)i] = lo;
        ((ushort4*)wbf)[2 * (size_t)i + 1] = hi;
    } else {
        int row = bid - 3169;
        const float* r = x + (size_t)row * HH;
        float v0 = r[t], v1 = r[t + 256], v2 = r[t + 512];
        float s = v0 + v1 + v2;
        float ss = v0 * v0 + v1 * v1 + v2 * v2;
        float2 r2 = blockReduceSum2(s, ss);
        float mean = r2.x * (1.0f / HH);
        float var = r2.y * (1.0f / HH) - mean * mean;
        float rs = rsqrtf(var + 1e-7f);
        unsigned short* o = hs + (size_t)row * HH;
        o[t] = f2b((v0 - mean) * rs);
        o[t + 256] = f2b((v1 - mean) * rs);
        o[t + 512] = f2b((v2 - mean) * rs);
    }
}

// ---------------------------------------------------------------------------
// LayerNorm family; EPS = 1e-7, biased variance
// ---------------------------------------------------------------------------
__global__ __launch_bounds__(256) void k_ln_bf(const float* __restrict__ in,
                                               unsigned short* __restrict__ out) {
    int row = blockIdx.x, t = threadIdx.x;
    const float* r = in + (size_t)row * HH;
    float v0 = r[t], v1 = r[t + 256], v2 = r[t + 512];
    float s = v0 + v1 + v2;
    float ss = v0 * v0 + v1 * v1 + v2 * v2;
    float2 r2 = blockReduceSum2(s, ss);
    float mean = r2.x * (1.0f / HH);
    float var = r2.y * (1.0f / HH) - mean * mean;
    float rs = rsqrtf(var + 1e-7f);
    unsigned short* o = out + (size_t)row * HH;
    o[t] = f2b((v0 - mean) * rs);
    o[t + 256] = f2b((v1 - mean) * rs);
    o[t + 512] = f2b((v2 - mean) * rs);
}

__global__ __launch_bounds__(256) void k_embed_ln(const int* __restrict__ ids,
                                                  const float* __restrict__ emb,
                                                  float* __restrict__ out) {
    int row = blockIdx.x, t = threadIdx.x;
    const float* r = emb + (size_t)ids[row] * HH;
    float v0 = r[t], v1 = r[t + 256], v2 = r[t + 512];
    float s = v0 + v1 + v2;
    float ss = v0 * v0 + v1 * v1 + v2 * v2;
    float2 r2 = blockReduceSum2(s, ss);
    float mean = r2.x * (1.0f / HH);
    float var = r2.y * (1.0f / HH) - mean * mean;
    float rs = rsqrtf(var + 1e-7f);
    float* o = out + (size_t)row * HH;
    o[t] = (v0 - mean) * rs;
    o[t + 256] = (v1 - mean) * rs;
    o[t + 512] = (v2 - mean) * rs;
}

// rel LN -> bf16, padded to 128 rows (rows 63..127 zero)
__global__ __launch_bounds__(256) void k_rel_ln_bf(const float* __restrict__ rel_emb,
                                                   const float* __restrict__ g,
                                                   const float* __restrict__ b,
                                                   unsigned short* __restrict__ out) {
    int row = blockIdx.x, t = threadIdx.x;
    unsigned short* o = out + (size_t)row * HH;
    if (row >= 63) {
        o[t] = 0; o[t + 256] = 0; o[t + 512] = 0;
        return;
    }
    const float* r = rel_emb + (size_t)row * HH;
    float v0 = r[t], v1 = r[t + 256], v2 = r[t + 512];
    float s = v0 + v1 + v2;
    float ss = v0 * v0 + v1 * v1 + v2 * v2;
    float2 r2 = blockReduceSum2(s, ss);
    float mean = r2.x * (1.0f / HH);
    float var = r2.y * (1.0f / HH) - mean * mean;
    float rs = rsqrtf(var + 1e-7f);
    o[t] = f2b((v0 - mean) * rs * g[t] + b[t]);
    o[t + 256] = f2b((v1 - mean) * rs * g[t + 256] + b[t + 256]);
    o[t + 512] = f2b((v2 - mean) * rs * g[t + 512] + b[t + 512]);
}

// ctx_bf = bf16(LN(ctxr * gelu_exact(g))), g = qkvg[..., 2304:3072] (bf16)
__global__ __launch_bounds__(256) void k_gated_ln(const float* __restrict__ ctxr,
                                                  const unsigned short* __restrict__ qkvg,
                                                  unsigned short* __restrict__ out) {
    int row = blockIdx.x, t = threadIdx.x;
    const float* cr = ctxr + (size_t)row * HH;
    const unsigned short* gr = qkvg + (size_t)row * 3072 + 2304;
    float v[3];
    float s = 0.f, ss = 0.f;
#pragma unroll
    for (int e = 0; e < 3; ++e) {
        int i = t + e * 256;
        float x = cr[i] * gelu_erf(b2f(gr[i]));
        v[e] = x;
        s += x; ss += x * x;
    }
    float2 r2 = blockReduceSum2(s, ss);
    float mean = r2.x * (1.0f / HH);
    float var = r2.y * (1.0f / HH) - mean * mean;
    float rs = rsqrtf(var + 1e-7f);
    unsigned short* o = out + (size_t)row * HH;
#pragma unroll
    for (int e = 0; e < 3; ++e) o[t + e * 256] = f2b((v[e] - mean) * rs);
}

// h2_bf = bf16(LN(ffh[:, :I] * gelu_tanh(ffh[:, I:])))  (ffh bf16 [row][4096])
__global__ __launch_bounds__(256) void k_ffn_ln(const unsigned short* __restrict__ ffh,
                                                unsigned short* __restrict__ out) {
    int row = blockIdx.x, t = threadIdx.x;
    const unsigned short* ar = ffh + (size_t)row * 4096 + t * 8;
    const unsigned short* gr = ar + II;
    ushort4 a0 = *(const ushort4*)ar;
    ushort4 a1 = *(const ushort4*)(ar + 4);
    ushort4 g0 = *(const ushort4*)gr;
    ushort4 g1 = *(const ushort4*)(gr + 4);
    float av[8] = {b2f(a0.x), b2f(a0.y), b2f(a0.z), b2f(a0.w),
                   b2f(a1.x), b2f(a1.y), b2f(a1.z), b2f(a1.w)};
    float gv[8] = {b2f(g0.x), b2f(g0.y), b2f(g0.z), b2f(g0.w),
                   b2f(g1.x), b2f(g1.y), b2f(g1.z), b2f(g1.w)};
    float v[8];
    float s = 0.f, ss = 0.f;
#pragma unroll
    for (int e = 0; e < 8; ++e) {
        float x = av[e] * gelu_tanh(gv[e]);
        v[e] = x;
        s += x; ss += x * x;
    }
    float2 r2 = blockReduceSum2(s, ss);
    float mean = r2.x * (1.0f / II);
    float var = r2.y * (1.0f / II) - mean * mean;
    float rs = rsqrtf(var + 1e-7f);
    ushort4 o0, o1;
    o0.x = f2b((v[0] - mean) * rs); o0.y = f2b((v[1] - mean) * rs);
    o0.z = f2b((v[2] - mean) * rs); o0.w = f2b((v[3] - mean) * rs);
    o1.x = f2b((v[4] - mean) * rs); o1.y = f2b((v[5] - mean) * rs);
    o1.z = f2b((v[6] - mean) * rs); o1.w = f2b((v[7] - mean) * rs);
    unsigned short* o = out + (size_t)row * II + t * 8;
    *(ushort4*)o = o0;
    *(ushort4*)(o + 4) = o1;
}

// ---------------------------------------------------------------------------
// bf16 MFMA GEMM (m97 structure + bijective XCD swizzle + z-batch) —
// used only for the batched posproj at setup.
// ---------------------------------------------------------------------------
template <int OBF>
__global__ __launch_bounds__(256) void k_gemm_bf16(const unsigned short* __restrict__ A, int lda,
                                                   const unsigned short* __restrict__ W, int ldw,
                                                   void* __restrict__ Cv, int ldc,
                                                   int M, int N, int K,
                                                   const float* __restrict__ bias,
                                                   const float* __restrict__ bias2,
                                                   const float* __restrict__ res,
                                                   size_t wz, size_t cz, size_t bz) {
    __shared__ unsigned short As[128 * 32];
    __shared__ unsigned short Ws[128 * 32];
    int zz = blockIdx.z;
    W += (size_t)zz * wz;
    if (bias) bias += (size_t)zz * bz;
    int nwg = gridDim.x * gridDim.y;
    int orig = blockIdx.y * gridDim.x + blockIdx.x;
    int qq = nwg >> 3, rr = nwg & 7;
    int xcd = orig & 7, idx = orig >> 3;
    int wg = (xcd < rr ? xcd * (qq + 1) : rr * (qq + 1) + (xcd - rr) * qq) + idx;
    int bx = wg % gridDim.x, by = wg / gridDim.x;

    const int t = threadIdx.x;
    const int lane = t & 63, wid = t >> 6;
    const int row0 = by * 128, col0 = bx * 128;
    const int wr = (wid >> 1) * 64, wc = (wid & 1) * 64;
    const int rA = lane & 15, kA = (lane >> 4) * 8;

    f32x4 acc[4][4] = {};

    for (int k0 = 0; k0 < K; k0 += 32) {
#pragma unroll
        for (int j = 0; j < 2; ++j) {
            int c = t + j * 256;
            int r = c >> 2, ko = (c & 3) * 8;
            const unsigned short* srcA = A + (size_t)(row0 + r) * lda + k0 + ko;
            const unsigned short* srcB = W + (size_t)(col0 + r) * ldw + k0 + ko;
            unsigned short* dstA = As + (size_t)(j * 256 + wid * 64) * 8;
            unsigned short* dstB = Ws + (size_t)(j * 256 + wid * 64) * 8;
            __builtin_amdgcn_global_load_lds(
                (const __attribute__((address_space(1))) void*)srcA,
                (__attribute__((address_space(3))) void*)dstA, 16, 0, 0);
            __builtin_amdgcn_global_load_lds(
                (const __attribute__((address_space(1))) void*)srcB,
                (__attribute__((address_space(3))) void*)dstB, 16, 0, 0);
        }
        __syncthreads();
        bf16x8 af[4], bfr[4];
#pragma unroll
        for (int m = 0; m < 4; ++m)
            af[m] = *(const bf16x8*)&As[(wr + m * 16 + rA) * 32 + kA];
#pragma unroll
        for (int n = 0; n < 4; ++n)
            bfr[n] = *(const bf16x8*)&Ws[(wc + n * 16 + rA) * 32 + kA];
#pragma unroll
        for (int m = 0; m < 4; ++m)
#pragma unroll
            for (int n = 0; n < 4; ++n)
                acc[m][n] = __builtin_amdgcn_mfma_f32_16x16x32_bf16(af[m], bfr[n], acc[m][n], 0, 0, 0);
        __syncthreads();
    }

    float* Cf = (float*)Cv + (size_t)zz * cz;
    unsigned short* Cb = (unsigned short*)Cv + (size_t)zz * cz;
    const int cl = lane & 15, rg = (lane >> 4) * 4;
#pragma unroll
    for (int n = 0; n < 4; ++n) {
        int gc = col0 + wc + n * 16 + cl;
        float bv = 0.0f;
        if (bias) bv = (bias2 && gc >= 1536) ? bias2[gc - 1536] : bias[gc];
#pragma unroll
        for (int m = 0; m < 4; ++m) {
#pragma unroll
            for (int i = 0; i < 4; ++i) {
                int gr = row0 + wr + m * 16 + rg + i;
                float v = acc[m][n][i] + bv;
                if (OBF) {
                    Cb[(size_t)gr * ldc + gc] = f2b(v);
                } else {
                    if (res) v += res[(size_t)gr * ldc + gc];
                    Cf[(size_t)gr * ldc + gc] = v;
                }
            }
        }
    }
}

// ---------------------------------------------------------------------------
// Skinny bf16 MFMA GEMM for N=768 (Wout, W2), 2-slot pipelined (round 10)
// ---------------------------------------------------------------------------
#define SKSLOT 16384  /* 16 KB per slot: A 8KB @0, B 8KB @8192 */

__device__ __forceinline__ void sk_stage(const unsigned short* __restrict__ Ab, int lda,
                                         const unsigned short* __restrict__ Wb, int ldw,
                                         unsigned char* slot, int t, int wid) {
    int rit = t >> 3;
    int kb = (t & 7) << 4;
#pragma unroll
    for (int c = 0; c < 2; ++c) {
        int row = c * 32 + rit;
        int gkb = kb ^ ((row & 7) << 4);
        const unsigned short* src = Ab + (size_t)row * lda + (gkb >> 1);
        unsigned char* dst = slot + c * 4096 + wid * 1024;
        __builtin_amdgcn_global_load_lds(
            (const __attribute__((address_space(1))) void*)src,
            (__attribute__((address_space(3))) void*)dst, 16, 0, 0);
    }
#pragma unroll
    for (int c = 0; c < 2; ++c) {
        int row = c * 32 + rit;
        int gkb = kb ^ ((row & 7) << 4);
        const unsigned short* src = Wb + (size_t)row * ldw + (gkb >> 1);
        unsigned char* dst = slot + 8192 + c * 4096 + wid * 1024;
        __builtin_amdgcn_global_load_lds(
            (const __attribute__((address_space(1))) void*)src,
            (__attribute__((address_space(3))) void*)dst, 16, 0, 0);
    }
}

__device__ __forceinline__ void sk_compute(const unsigned char* slot, int wr, int wc,
                                           int rA, int g16, f32x4 acc[2][2]) {
    const unsigned char* Ab = slot;
    const unsigned char* Bb = slot + 8192;
    bf16x8 a[2][2], b[2][2];
#pragma unroll
    for (int m = 0; m < 2; ++m) {
        int row = wr + m * 16 + rA;
        int sw = (row & 7) << 4;
#pragma unroll
        for (int s = 0; s < 2; ++s)
            a[m][s] = *(const bf16x8*)(Ab + row * 128 + ((s * 64 + g16 * 16) ^ sw));
    }
#pragma unroll
    for (int n = 0; n < 2; ++n) {
        int row = wc + n * 16 + rA;
        int sw = (row & 7) << 4;
#pragma unroll
        for (int s = 0; s < 2; ++s)
            b[n][s] = *(const bf16x8*)(Bb + row * 128 + ((s * 64 + g16 * 16) ^ sw));
    }
    __builtin_amdgcn_s_setprio(1);
#pragma unroll
    for (int m = 0; m < 2; ++m)
#pragma unroll
        for (int n = 0; n < 2; ++n) {
            acc[m][n] = __builtin_amdgcn_mfma_f32_16x16x32_bf16(a[m][0], b[n][0], acc[m][n], 0, 0, 0);
            acc[m][n] = __builtin_amdgcn_mfma_f32_16x16x32_bf16(a[m][1], b[n][1], acc[m][n], 0, 0, 0);
        }
    __builtin_amdgcn_s_setprio(0);
}

__global__ __launch_bounds__(256) void k_gemm_skinny(const unsigned short* __restrict__ A, int lda,
                                                     const unsigned short* __restrict__ W, int ldw,
                                                     float* __restrict__ C, int ldc,
                                                     int M, int N, int K,
                                                     const float* __restrict__ bias,
                                                     const float* __restrict__ res) {
    __shared__ unsigned char smem[2 * SKSLOT];
    int nwg = gridDim.x * gridDim.y;
    int orig = blockIdx.y * gridDim.x + blockIdx.x;
    int qq = nwg >> 3, rr = nwg & 7;
    int xcd = orig & 7, idx = orig >> 3;
    int wg = (xcd < rr ? xcd * (qq + 1) : rr * (qq + 1) + (xcd - rr) * qq) + idx;
    int bx = wg % gridDim.x, by = wg / gridDim.x;

    const int t = threadIdx.x;
    const int lane = t & 63, wid = t >> 6;
    const int row0 = by * 64, col0 = bx * 64;
    const int wr = (wid >> 1) * 32, wc = (wid & 1) * 32;
    const int rA = lane & 15, g16 = lane >> 4;
    const unsigned short* Abase = A + (size_t)row0 * lda;
    const unsigned short* Wbase = W + (size_t)col0 * ldw;

    const int nt = K >> 6;
    f32x4 acc[2][2] = {};

    sk_stage(Abase, lda, Wbase, ldw, smem, t, wid);

    for (int tt = 0; tt < nt; ++tt) {
        asm volatile("s_barrier" ::: "memory");
        if (tt + 1 < nt) {
            sk_stage(Abase + (size_t)(tt + 1) * 64, lda, Wbase + (size_t)(tt + 1) * 64,
                     ldw, smem + (size_t)((tt + 1) & 1) * SKSLOT, t, wid);
            asm volatile("s_waitcnt vmcnt(4)" ::: "memory");
        } else {
            asm volatile("s_waitcnt vmcnt(0)" ::: "memory");
        }
        asm volatile("s_barrier" ::: "memory");
        sk_compute(smem + (size_t)(tt & 1) * SKSLOT, wr, wc, rA, g16, acc);
    }

    const int cl = lane & 15, rg = (lane >> 4) * 4;
#pragma unroll
    for (int n = 0; n < 2; ++n) {
        int gc = col0 + wc + n * 16 + cl;
        float bv = bias ? bias[gc] : 0.0f;
#pragma unroll
        for (int m = 0; m < 2; ++m) {
#pragma unroll
            for (int i = 0; i < 4; ++i) {
                int gr = row0 + wr + m * 16 + rg + i;
                float v = acc[m][n][i] + bv;
                if (res) v += res[(size_t)gr * ldc + gc];
                C[(size_t)gr * ldc + gc] = v;
            }
        }
    }
}

// ---------------------------------------------------------------------------
// Pipelined bf16 MFMA GEMM for the large GEMMs (qkvg, W1)
// ---------------------------------------------------------------------------
#define GSLOT 49152  /* 48 KB: A 16KB @0, B 32KB @16384 */

__device__ __forceinline__ void g_stage(const unsigned short* __restrict__ Abase, int lda,
                                        const unsigned short* __restrict__ Wbase, int ldw,
                                        unsigned char* slot, int t, int wid) {
    int rit = t >> 3;
    int kb = (t & 7) << 4;
#pragma unroll
    for (int c = 0; c < 2; ++c) {
        int row = c * 64 + rit;
        int gkb = kb ^ ((row & 7) << 4);
        const unsigned short* src = Abase + (size_t)row * lda + (gkb >> 1);
        unsigned char* dst = slot + c * 8192 + wid * 1024;
        __builtin_amdgcn_global_load_lds(
            (const __attribute__((address_space(1))) void*)src,
            (__attribute__((address_space(3))) void*)dst, 16, 0, 0);
    }
#pragma unroll
    for (int c = 0; c < 4; ++c) {
        int row = c * 64 + rit;
        int gkb = kb ^ ((row & 7) << 4);
        const unsigned short* src = Wbase + (size_t)row * ldw + (gkb >> 1);
        unsigned char* dst = slot + 16384 + c * 8192 + wid * 1024;
        __builtin_amdgcn_global_load_lds(
            (const __attribute__((address_space(1))) void*)src,
            (__attribute__((address_space(3))) void*)dst, 16, 0, 0);
    }
}

__device__ __forceinline__ void g_compute(const unsigned char* slot, int wm, int wn,
                                          int rA, int g16, f32x4 acc[4][4]) {
    const unsigned char* Ab = slot;
    const unsigned char* Bb = slot + 16384;
    bf16x8 a[4][2], b[4][2];
#pragma unroll
    for (int m = 0; m < 4; ++m) {
        int row = wm * 64 + m * 16 + rA;
        int sw = (row & 7) << 4;
#pragma unroll
        for (int s = 0; s < 2; ++s)
            a[m][s] = *(const bf16x8*)(Ab + row * 128 + ((s * 64 + g16 * 16) ^ sw));
    }
#pragma unroll
    for (int n = 0; n < 4; ++n) {
        int row = wn * 64 + n * 16 + rA;
        int sw = (row & 7) << 4;
#pragma unroll
        for (int s = 0; s < 2; ++s)
            b[n][s] = *(const bf16x8*)(Bb + row * 128 + ((s * 64 + g16 * 16) ^ sw));
    }
    __builtin_amdgcn_s_setprio(1);
#pragma unroll
    for (int m = 0; m < 4; ++m)
#pragma unroll
        for (int n = 0; n < 4; ++n) {
            acc[m][n] = __builtin_amdgcn_mfma_f32_16x16x32_bf16(a[m][0], b[n][0], acc[m][n], 0, 0, 0);
            acc[m][n] = __builtin_amdgcn_mfma_f32_16x16x32_bf16(a[m][1], b[n][1], acc[m][n], 0, 0, 0);
        }
    __builtin_amdgcn_s_setprio(0);
}

template <int OBF>
__global__ __launch_bounds__(512, 1) void k_gemm_big(const unsigned short* __restrict__ A, int lda,
                                                     const unsigned short* __restrict__ W,
                                                     const unsigned short* __restrict__ Wb2, int ldw,
                                                     void* __restrict__ Cv, int ldc,
                                                     int M, int N, int K,
                                                     const float* __restrict__ bias,
                                                     const float* __restrict__ bias2,
                                                     const float* __restrict__ res) {
    extern __shared__ unsigned char smem[];
    int nwg = gridDim.x * gridDim.y;
    int orig = blockIdx.y * gridDim.x + blockIdx.x;
    int qq = nwg >> 3, rr = nwg & 7;
    int xcd = orig & 7, idx = orig >> 3;
    int wg = (xcd < rr ? xcd * (qq + 1) : rr * (qq + 1) + (xcd - rr) * qq) + idx;
    int bx = wg % gridDim.x, by = wg / gridDim.x;

    const int t = threadIdx.x;
    const int lane = t & 63, wid = t >> 6;
    const int wm = wid >> 2, wn = wid & 3;
    const int rA = lane & 15, g16 = lane >> 4;
    const int row0 = by * 128, col0 = bx * 256;
    const unsigned short* Abase = A + (size_t)row0 * lda;
    const unsigned short* Wbase = (Wb2 && col0 >= 1536)
                                      ? Wb2 + (size_t)(col0 - 1536) * ldw
                                      : W + (size_t)col0 * ldw;

    const int nt = K >> 6;
    f32x4 acc[4][4] = {};

    g_stage(Abase, lda, Wbase, ldw, smem, t, wid);
    g_stage(Abase + 64, lda, Wbase + 64, ldw, smem + GSLOT, t, wid);

#define GBAR() asm volatile("s_barrier" ::: "memory")
#define GITER(T, STG, VMSTR)                                                        \
    do {                                                                            \
        GBAR();                                                                     \
        if (STG)                                                                    \
            g_stage(Abase + (size_t)(T + 2) * 64, lda, Wbase + (size_t)(T + 2) * 64,\
                    ldw, smem + (size_t)((T + 2) % 3) * GSLOT, t, wid);             \
        asm volatile(VMSTR ::: "memory");                                           \
        GBAR();                                                                     \
        g_compute(smem + (size_t)((T) % 3) * GSLOT, wm, wn, rA, g16, acc);          \
    } while (0)

    int tt = 0;
    for (; tt < nt - 2; ++tt) GITER(tt, true, "s_waitcnt vmcnt(12)");
    GITER(tt, false, "s_waitcnt vmcnt(6)");
    ++tt;
    GITER(tt, false, "s_waitcnt vmcnt(0)");
#undef GITER
#undef GBAR

    float* Cf = (float*)Cv;
    unsigned short* Cb = (unsigned short*)Cv;
    const int cl = lane & 15, rg = (lane >> 4) * 4;
#pragma unroll
    for (int n = 0; n < 4; ++n) {
        int gc = col0 + wn * 64 + n * 16 + cl;
        float bv = 0.0f;
        if (bias) bv = (bias2 && gc >= 1536) ? bias2[gc - 1536] : bias[gc];
#pragma unroll
        for (int m = 0; m < 4; ++m) {
#pragma unroll
            for (int i = 0; i < 4; ++i) {
                int gr = row0 + wm * 64 + m * 16 + rg + i;
                float v = acc[m][n][i] + bv;
                if (OBF) {
                    Cb[(size_t)gr * ldc + gc] = f2b(v);
                } else {
                    if (res) v += res[(size_t)gr * ldc + gc];
                    Cf[(size_t)gr * ldc + gc] = v;
                }
            }
        }
    }
}

// ---------------------------------------------------------------------------
// merged: repack (blockIdx.x<8) + cp/pc MFMA (blockIdx.x>=8); grid (16, 96)
// ---------------------------------------------------------------------------
__global__ __launch_bounds__(256) void k_repack_cppc(const unsigned short* __restrict__ qkvg,
                                                     const unsigned short* __restrict__ pp,
                                                     unsigned short* __restrict__ qT,
                                                     unsigned short* __restrict__ kT,
                                                     unsigned short* __restrict__ vT,
                                                     float* __restrict__ cp,
                                                     float* __restrict__ pc) {
    __shared__ unsigned char shmem[12288];
    int t = threadIdx.x;
    if (blockIdx.x < 8) {
        unsigned short (*tile)[72] = (unsigned short(*)[72])shmem;
        int bh = blockIdx.y;
        int b = bh / NHH, h = bh % NHH;
        int s0 = blockIdx.x * 64;
#pragma unroll
        for (int j = 0; j < 2; ++j) {
            int idx = t + j * 256;
            int r = idx >> 3, dc = idx & 7;
            const unsigned short* src = qkvg + ((size_t)(s0 + r) * BB + b) * 3072 + h * DD + dc * 8;
            ushort4 a = *(const ushort4*)src;
            ushort4 c = *(const ushort4*)(src + 4);
            unsigned short* dq = qT + ((size_t)bh * SS + s0 + r) * DD + dc * 8;
            *(ushort4*)dq = a; *(ushort4*)(dq + 4) = c;
            const unsigned short* srck = src + HH;
            ushort4 a2 = *(const ushort4*)srck;
            ushort4 c2 = *(const ushort4*)(srck + 4);
            unsigned short* dk = kT + ((size_t)bh * SS + s0 + r) * DD + dc * 8;
            *(ushort4*)dk = a2; *(ushort4*)(dk + 4) = c2;
        }
#pragma unroll
        for (int j = 0; j < 4; ++j) {
            int idx = t + j * 256;
            int r = idx >> 4, c4 = idx & 15;
            ushort4 u = *(const ushort4*)(qkvg + ((size_t)(s0 + r) * BB + b) * 3072 + 1536 + h * DD + c4 * 4);
            *(ushort4*)&tile[r][c4 * 4] = u;
        }
        __syncthreads();
#pragma unroll
        for (int j = 0; j < 2; ++j) {
            int idx = t + j * 256;
            int d = idx >> 3, s8 = idx & 7;
            ushort4 a, c;
            a.x = tile[s8 * 8 + 0][d]; a.y = tile[s8 * 8 + 1][d];
            a.z = tile[s8 * 8 + 2][d]; a.w = tile[s8 * 8 + 3][d];
            c.x = tile[s8 * 8 + 4][d]; c.y = tile[s8 * 8 + 5][d];
            c.z = tile[s8 * 8 + 6][d]; c.w = tile[s8 * 8 + 7][d];
            unsigned short* dst = vT + ((size_t)bh * DD + d) * SS + s0 + s8 * 8;
            *(ushort4*)dst = a; *(ushort4*)(dst + 4) = c;
        }
    } else {
        int cid = (blockIdx.x - 8) * 96 + blockIdx.y;
        int z = cid >= 384;
        int rem = cid - (z ? 384 : 0);
        int h = rem >> 5;
        int mt = rem & 31;
        int aoff = z ? HH : 0;
        int toff = z ? 0 : HH;
        float* out = z ? pc : cp;
        unsigned short* As = (unsigned short*)shmem;
        unsigned short* Bs = (unsigned short*)(shmem + 8192);
        const int lane = t & 63, wid = t >> 6;
        const int rA = lane & 15, kA = (lane >> 4) * 8;

        f32x4 acc[2][4] = {};

        for (int k0 = 0; k0 < 64; k0 += 32) {
#pragma unroll
            for (int j = 0; j < 2; ++j) {
                int c = t + j * 256;
                int r = c >> 2, ko = (c & 3) * 8;
                const unsigned short* srcA = qkvg + (size_t)(mt * 128 + r) * 3072 + aoff + h * DD + k0 + ko;
                unsigned short* dstA = As + (size_t)(j * 256 + wid * 64) * 8;
                __builtin_amdgcn_global_load_lds(
                    (const __attribute__((address_space(1))) void*)srcA,
                    (__attribute__((address_space(3))) void*)dstA, 16, 0, 0);
            }
            {
                int r = t >> 2, ko = (t & 3) * 8;
                const unsigned short* srcB = pp + (size_t)r * 1536 + toff + h * DD + k0 + ko;
                unsigned short* dstB = Bs + (size_t)(wid * 64) * 8;
                __builtin_amdgcn_global_load_lds(
                    (const __attribute__((address_space(1))) void*)srcB,
                    (__attribute__((address_space(3))) void*)dstB, 16, 0, 0);
            }
            __syncthreads();
            bf16x8 af[2], bfr[4];
#pragma unroll
            for (int m = 0; m < 2; ++m)
                af[m] = *(const bf16x8*)&As[(wid * 32 + m * 16 + rA) * 32 + kA];
#pragma unroll
            for (int n = 0; n < 4; ++n)
                bfr[n] = *(const bf16x8*)&Bs[(n * 16 + rA) * 32 + kA];
#pragma unroll
            for (int m = 0; m < 2; ++m)
#pragma unroll
                for (int n = 0; n < 4; ++n)
                    acc[m][n] = __builtin_amdgcn_mfma_f32_16x16x32_bf16(af[m], bfr[n], acc[m][n], 0, 0, 0);
            __syncthreads();
        }

        const int cl = lane & 15, rg = (lane >> 4) * 4;
#pragma unroll
        for (int m = 0; m < 2; ++m)
#pragma unroll
            for (int n = 0; n < 4; ++n) {
                int gc = n * 16 + cl;
                if (gc < 63) {
#pragma unroll
                    for (int i = 0; i < 4; ++i) {
                        int gr = mt * 128 + wid * 32 + m * 16 + rg + i;
                        int sIdx = gr >> 3, bIdx = gr & 7;
                        out[(((size_t)(bIdx * NHH + h)) * SS + sIdx) * 63 + gc] = acc[m][n][i];
                    }
                }
            }
    }
}

// ---------------------------------------------------------------------------
// fused disentangled flash attention v3: cps/pcs bias tables in LDS as bf16
// (LDS 45.5 KB -> 29.4 KB => 3 -> 5 blocks/CU; softmax is VALU-bound, TLP is
// the lever). Same arithmetic otherwise.
// ---------------------------------------------------------------------------
__global__ __launch_bounds__(256) void k_attn_fused(
    const unsigned short* __restrict__ qT, const unsigned short* __restrict__ kT,
    const unsigned short* __restrict__ vT, const float* __restrict__ cp,
    const float* __restrict__ pc, const int* __restrict__ bucket,
    const int* __restrict__ mask, float* __restrict__ ctxr) {
    __shared__ unsigned short cps[64 * 63];        // 8064 B (bf16)
    __shared__ unsigned short pcs[64 * 63];        // 8064 B (bf16)
    __shared__ unsigned short pb_all[4][16 * 72];  // 9216 B
    __shared__ int btab[1023];                     // 4092 B
    int t = threadIdx.x;
    int lane = t & 63, wid = t >> 6;
    int bh = blockIdx.y;
    int b = bh / NHH, h = bh % NHH;
    int qb0 = blockIdx.x * 64;
    int q0 = qb0 + wid * 16;
    int rA = lane & 15, g = lane >> 4, kA = g * 8;
    unsigned short* pb = pb_all[wid];
    const unsigned short* qTb = qT + (size_t)bh * SS * DD;
    const unsigned short* kTb = kT + (size_t)bh * SS * DD;
    const unsigned short* vTb = vT + (size_t)bh * DD * SS;
    const float* cpb = cp + (size_t)bh * SS * 63 + (size_t)qb0 * 63;
    const float* pcb = pc + (size_t)bh * SS * 63;
    const int* mkb = mask + b * SS;

    for (int i = t; i < 1023; i += 256) btab[i] = bucket[i];
    for (int i = t; i < 1008; i += 256) {
        float4 d = ((const float4*)cpb)[i];
        ushort4 u;
        u.x = f2b(d.x); u.y = f2b(d.y); u.z = f2b(d.z); u.w = f2b(d.w);
        ((ushort4*)cps)[i] = u;
    }

    bf16x8 aq[2];
#pragma unroll
    for (int dc = 0; dc < 2; ++dc)
        aq[dc] = *(const bf16x8*)&qTb[(size_t)(q0 + rA) * DD + dc * 32 + kA];

    f32x4 o[4] = {};
    float mrow[4], lrow[4];
#pragma unroll
    for (int i = 0; i < 4; ++i) { mrow[i] = -INFINITY; lrow[i] = 0.f; }

    for (int kt = 0; kt < 8; ++kt) {
        int k0 = kt * 64;
        __syncthreads();  // all waves done reading pcs (prev iter); covers cps+btab on kt=0
        {
            const float4* src = (const float4*)(pcb + (size_t)k0 * 63);
            for (int i = t; i < 1008; i += 256) {
                float4 d = src[i];
                ushort4 u;
                u.x = f2b(d.x); u.y = f2b(d.y); u.z = f2b(d.z); u.w = f2b(d.w);
                ((ushort4*)pcs)[i] = u;
            }
        }
        // ---- S = Q.K^T (independent of pcs; covers stage latency) ----
        f32x4 sa[4] = {};
#pragma unroll
        for (int n = 0; n < 4; ++n) {
            bf16x8 bk0 = *(const bf16x8*)&kTb[(size_t)(k0 + n * 16 + rA) * DD + kA];
            bf16x8 bk1 = *(const bf16x8*)&kTb[(size_t)(k0 + n * 16 + rA) * DD + 32 + kA];
            sa[n] = __builtin_amdgcn_mfma_f32_16x16x32_bf16(aq[0], bk0, sa[n], 0, 0, 0);
            sa[n] = __builtin_amdgcn_mfma_f32_16x16x32_bf16(aq[1], bk1, sa[n], 0, 0, 0);
        }
        int mk[4];
#pragma unroll
        for (int n = 0; n < 4; ++n) mk[n] = mkb[k0 + n * 16 + rA];
        __syncthreads();  // pcs visible

        // ---- bias + mask + online softmax (gathers in LDS) ----
        float pv[4][4];
#pragma unroll
        for (int i = 0; i < 4; ++i) {
            int qr = wid * 16 + g * 4 + i;
            int q = qb0 + qr;
            float sv[4];
            float tmax = -INFINITY;
#pragma unroll
            for (int n = 0; n < 4; ++n) {
                int kr = n * 16 + rA;
                int id = btab[q - (k0 + kr) + 511];
                float v = (sa[n][i] + b2f(cps[qr * 63 + id]) + b2f(pcs[kr * 63 + id])) * SCALE_F;
                v = mk[n] ? -1e9f : v;
                sv[n] = v;
                tmax = fmaxf(tmax, v);
            }
            tmax = fmaxf(tmax, __shfl_xor(tmax, 1, 16));
            tmax = fmaxf(tmax, __shfl_xor(tmax, 2, 16));
            tmax = fmaxf(tmax, __shfl_xor(tmax, 4, 16));
            tmax = fmaxf(tmax, __shfl_xor(tmax, 8, 16));
            float mold = mrow[i];
            float mnew = fmaxf(mold, tmax);
            float ls = 0.f;
#pragma unroll
            for (int n = 0; n < 4; ++n) {
                float p = __expf(sv[n] - mnew);
                pv[n][i] = p;
                ls += p;
            }
            ls += __shfl_xor(ls, 1, 16);
            ls += __shfl_xor(ls, 2, 16);
            ls += __shfl_xor(ls, 4, 16);
            ls += __shfl_xor(ls, 8, 16);
            if (mnew > mold) {
                float alpha = __expf(mold - mnew);
                lrow[i] = lrow[i] * alpha + ls;
                mrow[i] = mnew;
#pragma unroll
                for (int n = 0; n < 4; ++n) o[n][i] *= alpha;
            } else {
                lrow[i] += ls;
            }
        }
        // ---- P -> bf16 via wave-local LDS transpose ----
#pragma unroll
        for (int n = 0; n < 4; ++n)
#pragma unroll
            for (int i = 0; i < 4; ++i)
                pb[(g * 4 + i) * 72 + n * 16 + rA] = f2b(pv[n][i]);
        // ---- O += P.V ----
        bf16x8 ap[2];
#pragma unroll
        for (int kc = 0; kc < 2; ++kc)
            ap[kc] = *(const bf16x8*)&pb[rA * 72 + kc * 32 + kA];
#pragma unroll
        for (int n = 0; n < 4; ++n) {
            bf16x8 bv0 = *(const bf16x8*)&vTb[(size_t)(n * 16 + rA) * SS + k0 + kA];
            bf16x8 bv1 = *(const bf16x8*)&vTb[(size_t)(n * 16 + rA) * SS + k0 + 32 + kA];
            o[n] = __builtin_amdgcn_mfma_f32_16x16x32_bf16(ap[0], bv0, o[n], 0, 0, 0);
            o[n] = __builtin_amdgcn_mfma_f32_16x16x32_bf16(ap[1], bv1, o[n], 0, 0, 0);
        }
    }
#pragma unroll
    for (int i = 0; i < 4; ++i) {
        int q = q0 + g * 4 + i;
        float inv = 1.0f / lrow[i];
#pragma unroll
        for (int n = 0; n < 4; ++n)
            ctxr[((size_t)q * BB + b) * HH + h * DD + n * 16 + rA] = o[n][i] * inv;
    }
}

// ---------------------------------------------------------------------------
// host launcher
// ---------------------------------------------------------------------------
static inline void gemm_big(const unsigned short* A, int lda,
                            const unsigned short* W, const unsigned short* Wb2, int ldw,
                            void* C, int ldc, int M, int N, int K,
                            const float* bias, const float* bias2, const float* res,
                            int obf, hipStream_t st) {
    dim3 g(N / 256, M / 128);
    if (obf)
        k_gemm_big<1><<<g, 512, 3 * GSLOT, st>>>(A, lda, W, Wb2, ldw, C, ldc, M, N, K, bias, bias2, res);
    else
        k_gemm_big<0><<<g, 512, 3 * GSLOT, st>>>(A, lda, W, Wb2, ldw, C, ldc, M, N, K, bias, bias2, res);
}

extern "C" void kernel_launch(void* const* d_in, const int* in_sizes, int n_in,
                              void* d_out, int out_size, void* d_ws, size_t ws_size,
                              hipStream_t stream) {
    static int attr_done = 0;
    if (!attr_done) {
        hipFuncSetAttribute((const void*)&k_gemm_big<1>,
                            hipFuncAttributeMaxDynamicSharedMemorySize, 3 * GSLOT);
        hipFuncSetAttribute((const void*)&k_gemm_big<0>,
                            hipFuncAttributeMaxDynamicSharedMemorySize, 3 * GSLOT);
        attr_done = 1;
    }

    const int* ids = (const int*)d_in[0];
    const unsigned char* maskraw = (const unsigned char*)d_in[1];
    const float* word_emb = (const float*)d_in[2];
    const float* rel_emb = (const float*)d_in[3];
    const float* rel_g = (const float*)d_in[4];
    const float* rel_b = (const float*)d_in[5];
    const float* Wqk = (const float*)d_in[6];
    const float* bqk = (const float*)d_in[7];
    const float* Wvg = (const float*)d_in[8];
    const float* bvg = (const float*)d_in[9];
    const float* Wout = (const float*)d_in[10];
    const float* bout = (const float*)d_in[11];
    const float* W1 = (const float*)d_in[12];
    const float* W2 = (const float*)d_in[13];

    const size_t N_X = (size_t)SS * BB * HH;
    const size_t N_CP = (size_t)SS * BB * NHH * 63;
    const size_t N_H2 = (size_t)SS * BB * II;
    const size_t N_WQK = (size_t)2 * HH * HH;
    const size_t N_WOUT = (size_t)HH * HH;
    const size_t N_W1 = (size_t)2 * II * HH;
    const size_t N_W2 = (size_t)HH * II;
    const size_t N_HD = (size_t)BB * NHH * SS * DD;
    const size_t N_QKVG = (size_t)SS * BB * 3072;
    const size_t N_FFH = (size_t)SS * BB * 4096;
    const size_t N_PP = (size_t)128 * 1536;

    float* ws = (float*)d_ws;
    float* x = ws;
    float* ctxr = x + N_X;
    float* cp = ctxr + N_X;
    float* pc = cp + N_CP;
    unsigned short* us = (unsigned short*)(pc + N_CP);
    unsigned short* qkvg = us;
    unsigned short* hs_bf = qkvg + N_QKVG;
    unsigned short* ctx_bf = hs_bf + N_X;
    unsigned short* h2_bf = ctx_bf + N_X;
    unsigned short* ffh = h2_bf + N_H2;
    unsigned short* wqk_all = ffh + N_FFH;
    unsigned short* wvg_bf = wqk_all + 12 * N_WQK;
    unsigned short* wout_bf = wvg_bf + N_WQK;
    unsigned short* w1_bf = wout_bf + N_WOUT;
    unsigned short* w2_bf = w1_bf + N_W1;
    unsigned short* ppall = w2_bf + N_W2;
    unsigned short* rel_bf = ppall + 12 * N_PP;
    unsigned short* qT = rel_bf + 128 * HH;
    unsigned short* kT = qT + N_HD;
    unsigned short* vT = kT + N_HD;
    int* bucket = (int*)(vT + N_HD);
    int* maski = bucket + 1024;

    size_t need_bytes = ((size_t)(maski + BB * SS) - (size_t)d_ws);
    if (ws_size < need_bytes) return;  // ~205 MB required

    // ---- setup ----
    k_decode_mask<<<1, 256, 0, stream>>>(maskraw, maski, BB * SS);
    k_bucket<<<4, 256, 0, stream>>>(bucket);
    k_embed_ln<<<SS * BB, 256, 0, stream>>>(ids, word_emb, x);
    k_rel_ln_bf<<<128, 256, 0, stream>>>(rel_emb, rel_g, rel_b, rel_bf);
    k_f2b<<<(int)((12 * N_WQK / 8 + 255) / 256), 256, 0, stream>>>(Wqk, wqk_all,
                                                                   (int)(12 * N_WQK / 8));
    {
        dim3 gpp(1536 / 128, 1, 12);
        k_gemm_bf16<1><<<gpp, 256, 0, stream>>>(rel_bf, HH, wqk_all, HH, ppall, 1536,
                                                128, 1536, HH, bqk, nullptr, nullptr,
                                                N_WQK, N_PP, 2 * HH);
    }

    for (int l = 0; l < LL; ++l) {
        const unsigned short* wqk_l = wqk_all + (size_t)l * N_WQK;
        const float* bqk_l = bqk + (size_t)l * 2 * HH;
        const float* Wvg_l = Wvg + (size_t)l * N_WQK;
        const float* bvg_l = bvg + (size_t)l * 2 * HH;
        const float* Wout_l = Wout + (size_t)l * N_WOUT;
        const float* bout_l = bout + (size_t)l * HH;
        const float* W1_l = W1 + (size_t)l * N_W1;
        const float* W2_l = W2 + (size_t)l * N_W2;

        // ---- attention ----
        k_f2b_ln<<<3169 + SS * BB, 256, 0, stream>>>(Wvg_l, Wout_l, W1_l, W2_l, wvg_bf,
                                                     x, hs_bf);
        gemm_big(hs_bf, HH, wqk_l, wvg_bf, HH, qkvg, 3072, SS * BB, 3072, HH,
                 bqk_l, bvg_l, nullptr, 1, stream);
        k_repack_cppc<<<dim3(16, 96), 256, 0, stream>>>(qkvg, ppall + (size_t)l * N_PP,
                                                        qT, kT, vT, cp, pc);
        k_attn_fused<<<dim3(SS / 64, BB * NHH), 256, 0, stream>>>(qT, kT, vT, cp, pc,
                                                                  bucket, maski, ctxr);
        k_gated_ln<<<SS * BB, 256, 0, stream>>>(ctxr, qkvg, ctx_bf);
        k_gemm_skinny<<<dim3(HH / 64, SS * BB / 64), 256, 0, stream>>>(
            ctx_bf, HH, wout_bf, HH, x, HH, SS * BB, HH, HH, bout_l, x);

        // ---- GeGLU FFN ----
        k_ln_bf<<<SS * BB, 256, 0, stream>>>(x, hs_bf);
        gemm_big(hs_bf, HH, w1_bf, nullptr, HH, ffh, 4096, SS * BB, 4096, HH,
                 nullptr, nullptr, nullptr, 1, stream);
        k_ffn_ln<<<SS * BB, 256, 0, stream>>>(ffh, h2_bf);
        // last layer writes the residual-added output straight into d_out
        float* outC = (l == LL - 1) ? (float*)d_out : x;
        k_gemm_skinny<<<dim3(HH / 64, SS * BB / 64), 256, 0, stream>>>(
            h2_bf, II, w2_bf, II, outC, HH, SS * BB, HH, II, nullptr, x);
    }
}

// Round 12
// 2826.256 us; speedup vs baseline: 1.0007x; 1.0007x over previous
//
#include <hip/hip_runtime.h>
#include <math.h>

#define SS 512
#define BB 8
#define NHH 12
#define DD 64
#define HH 768
#define II 2048
#define LL 12
#define SCALE_F 0.07216878364870323f  /* 1/sqrt(3*64) */

typedef __attribute__((ext_vector_type(8))) short bf16x8;
typedef __attribute__((ext_vector_type(4))) float f32x4;

// f32 -> bf16 (RNE, finite values)
__device__ __forceinline__ unsigned short f2b(float f) {
    union { float f; unsigned int u; } x; x.f = f;
    unsigned int r = x.u + 0x7fffu + ((x.u >> 16) & 1u);
    return (unsigned short)(r >> 16);
}
__device__ __forceinline__ float b2f(unsigned short u) {
    union { unsigned int u; float f; } x; x.u = ((unsigned int)u) << 16;
    return x.f;
}

// ---------------------------------------------------------------------------
// block reduction helpers (blockDim.x == 256)
// ---------------------------------------------------------------------------
__device__ __forceinline__ float2 blockReduceSum2(float a, float b) {
    __shared__ float2 sm[4];
    __shared__ float2 bc;
#pragma unroll
    for (int o = 32; o > 0; o >>= 1) {
        a += __shfl_down(a, o);
        b += __shfl_down(b, o);
    }
    int t = threadIdx.x;
    if ((t & 63) == 0) sm[t >> 6] = make_float2(a, b);
    __syncthreads();
    if (t == 0) {
        float xa = sm[0].x + sm[1].x + sm[2].x + sm[3].x;
        float xb = sm[0].y + sm[1].y + sm[2].y + sm[3].y;
        bc = make_float2(xa, xb);
    }
    __syncthreads();
    return bc;
}

__device__ __forceinline__ float gelu_erf(float v) {
    return 0.5f * v * (1.0f + erff(v * 0.70710678118654752f));
}
__device__ __forceinline__ float gelu_tanh(float v) {
    const float c = 0.7978845608028654f;
    return 0.5f * v * (1.0f + tanhf(c * (v + 0.044715f * v * v * v)));
}

// ---------------------------------------------------------------------------
// mask decode: handle bool-as-u8 or bool-as-int32 layouts
// ---------------------------------------------------------------------------
__global__ __launch_bounds__(256) void k_decode_mask(const unsigned char* __restrict__ raw,
                                                     int* __restrict__ mask, int n) {
    __shared__ int s_any;
    if (threadIdx.x == 0) s_any = 0;
    __syncthreads();
    int local = 0;
    for (int i = threadIdx.x; i < n; i += blockDim.x)
        if ((i & 3) && raw[i]) local = 1;
    if (local) atomicOr(&s_any, 1);
    __syncthreads();
    bool isU8 = (s_any != 0);
    const int* as_int = (const int*)raw;
    for (int i = threadIdx.x; i < n; i += blockDim.x)
        mask[i] = isU8 ? (raw[i] != 0) : (as_int[i] != 0);
}

// ---------------------------------------------------------------------------
// DeBERTa log-bucket table: rel in [-511,511] -> idx in [0,62]
// ---------------------------------------------------------------------------
__global__ __launch_bounds__(256) void k_bucket(int* __restrict__ tab) {
    int i = blockIdx.x * 256 + threadIdx.x;
    if (i >= 1023) return;
    int rel = i - 511;
    int a = rel < 0 ? -rel : rel;
    int abs_pos = (a < 16) ? 15 : (a < 511 ? a : 511);
    int bucket;
    if (abs_pos <= 16) {
        bucket = rel;
    } else {
        double lp = ceil(log((double)abs_pos / 16.0) / log(511.0 / 16.0) * 15.0);
        int l = (int)lp + 16;
        bucket = (rel > 0) ? l : -l;
    }
    int idx = bucket + 31;
    if (idx < 0) idx = 0;
    if (idx > 62) idx = 62;
    tab[i] = idx;
}

// ---------------------------------------------------------------------------
// generic f32 -> bf16 bulk conversion (8 elems/thread)
// ---------------------------------------------------------------------------
__global__ __launch_bounds__(256) void k_f2b(const float* __restrict__ in,
                                             unsigned short* __restrict__ out, int n8) {
    int i = blockIdx.x * 256 + threadIdx.x;
    if (i >= n8) return;
    float4 a = ((const float4*)in)[2 * (size_t)i];
    float4 b = ((const float4*)in)[2 * (size_t)i + 1];
    ushort4 lo, hi;
    lo.x = f2b(a.x); lo.y = f2b(a.y); lo.z = f2b(a.z); lo.w = f2b(a.w);
    hi.x = f2b(b.x); hi.y = f2b(b.y); hi.z = f2b(b.z); hi.w = f2b(b.w);
    ((ushort4*)out)[2 * (size_t)i] = lo;
    ((ushort4*)out)[2 * (size_t)i + 1] = hi;
}

// ---------------------------------------------------------------------------
// merged: per-layer weight conversion (blocks 0..3168) + LN of x (blocks 3169..7264)
// ---------------------------------------------------------------------------
__global__ __launch_bounds__(256) void k_f2b_ln(const float* __restrict__ wvg,
                                                const float* __restrict__ wout,
                                                const float* __restrict__ w1,
                                                const float* __restrict__ w2,
                                                unsigned short* __restrict__ wbf,
                                                const float* __restrict__ x,
                                                unsigned short* __restrict__ hs) {
    int bid = blockIdx.x;
    int t = threadIdx.x;
    if (bid < 3169) {
        int i = bid * 256 + t;
        if (i >= 811008) return;
        const float* src;
        int off;
        if (i < 221184) {
            if (i < 147456) { src = wvg;  off = i; }
            else            { src = wout; off = i - 147456; }
        } else if (i < 614400) { src = w1; off = i - 221184; }
        else                   { src = w2; off = i - 614400; }
        float4 a = ((const float4*)src)[2 * (size_t)off];
        float4 b = ((const float4*)src)[2 * (size_t)off + 1];
        ushort4 lo, hi;
        lo.x = f2b(a.x); lo.y = f2b(a.y); lo.z = f2b(a.z); lo.w = f2b(a.w);
        hi.x = f2b(b.x); hi.y = f2b(b.y); hi.z = f2b(b.z); hi.w = f2b(b.w);
        ((ushort4*)wbf)[2 * (size_t)i] = lo;
        ((ushort4*)wbf)[2 * (size_t)i + 1] = hi;
    } else {
        int row = bid - 3169;
        const float* r = x + (size_t)row * HH;
        float v0 = r[t], v1 = r[t + 256], v2 = r[t + 512];
        float s = v0 + v1 + v2;
        float ss = v0 * v0 + v1 * v1 + v2 * v2;
        float2 r2 = blockReduceSum2(s, ss);
        float mean = r2.x * (1.0f / HH);
        float var = r2.y * (1.0f / HH) - mean * mean;
        float rs = rsqrtf(var + 1e-7f);
        unsigned short* o = hs + (size_t)row * HH;
        o[t] = f2b((v0 - mean) * rs);
        o[t + 256] = f2b((v1 - mean) * rs);
        o[t + 512] = f2b((v2 - mean) * rs);
    }
}

// ---------------------------------------------------------------------------
// LayerNorm family; EPS = 1e-7, biased variance
// ---------------------------------------------------------------------------
__global__ __launch_bounds__(256) void k_ln_bf(const float* __restrict__ in,
                                               unsigned short* __restrict__ out) {
    int row = blockIdx.x, t = threadIdx.x;
    const float* r = in + (size_t)row * HH;
    float v0 = r[t], v1 = r[t + 256], v2 = r[t + 512];
    float s = v0 + v1 + v2;
    float ss = v0 * v0 + v1 * v1 + v2 * v2;
    float2 r2 = blockReduceSum2(s, ss);
    float mean = r2.x * (1.0f / HH);
    float var = r2.y * (1.0f / HH) - mean * mean;
    float rs = rsqrtf(var + 1e-7f);
    unsigned short* o = out + (size_t)row * HH;
    o[t] = f2b((v0 - mean) * rs);
    o[t + 256] = f2b((v1 - mean) * rs);
    o[t + 512] = f2b((v2 - mean) * rs);
}

__global__ __launch_bounds__(256) void k_embed_ln(const int* __restrict__ ids,
                                                  const float* __restrict__ emb,
                                                  float* __restrict__ out) {
    int row = blockIdx.x, t = threadIdx.x;
    const float* r = emb + (size_t)ids[row] * HH;
    float v0 = r[t], v1 = r[t + 256], v2 = r[t + 512];
    float s = v0 + v1 + v2;
    float ss = v0 * v0 + v1 * v1 + v2 * v2;
    float2 r2 = blockReduceSum2(s, ss);
    float mean = r2.x * (1.0f / HH);
    float var = r2.y * (1.0f / HH) - mean * mean;
    float rs = rsqrtf(var + 1e-7f);
    float* o = out + (size_t)row * HH;
    o[t] = (v0 - mean) * rs;
    o[t + 256] = (v1 - mean) * rs;
    o[t + 512] = (v2 - mean) * rs;
}

// rel LN -> bf16, padded to 128 rows (rows 63..127 zero)
__global__ __launch_bounds__(256) void k_rel_ln_bf(const float* __restrict__ rel_emb,
                                                   const float* __restrict__ g,
                                                   const float* __restrict__ b,
                                                   unsigned short* __restrict__ out) {
    int row = blockIdx.x, t = threadIdx.x;
    unsigned short* o = out + (size_t)row * HH;
    if (row >= 63) {
        o[t] = 0; o[t + 256] = 0; o[t + 512] = 0;
        return;
    }
    const float* r = rel_emb + (size_t)row * HH;
    float v0 = r[t], v1 = r[t + 256], v2 = r[t + 512];
    float s = v0 + v1 + v2;
    float ss = v0 * v0 + v1 * v1 + v2 * v2;
    float2 r2 = blockReduceSum2(s, ss);
    float mean = r2.x * (1.0f / HH);
    float var = r2.y * (1.0f / HH) - mean * mean;
    float rs = rsqrtf(var + 1e-7f);
    o[t] = f2b((v0 - mean) * rs * g[t] + b[t]);
    o[t + 256] = f2b((v1 - mean) * rs * g[t + 256] + b[t + 256]);
    o[t + 512] = f2b((v2 - mean) * rs * g[t + 512] + b[t + 512]);
}

// ctx_bf = bf16(LN(ctxr * gelu_exact(g))), g = qkvg[..., 2304:3072] (bf16)
__global__ __launch_bounds__(256) void k_gated_ln(const float* __restrict__ ctxr,
                                                  const unsigned short* __restrict__ qkvg,
                                                  unsigned short* __restrict__ out) {
    int row = blockIdx.x, t = threadIdx.x;
    const float* cr = ctxr + (size_t)row * HH;
    const unsigned short* gr = qkvg + (size_t)row * 3072 + 2304;
    float v[3];
    float s = 0.f, ss = 0.f;
#pragma unroll
    for (int e = 0; e < 3; ++e) {
        int i = t + e * 256;
        float x = cr[i] * gelu_erf(b2f(gr[i]));
        v[e] = x;
        s += x; ss += x * x;
    }
    float2 r2 = blockReduceSum2(s, ss);
    float mean = r2.x * (1.0f / HH);
    float var = r2.y * (1.0f / HH) - mean * mean;
    float rs = rsqrtf(var + 1e-7f);
    unsigned short* o = out + (size_t)row * HH;
#pragma unroll
    for (int e = 0; e < 3; ++e) o[t + e * 256] = f2b((v[e] - mean) * rs);
}

// h2_bf = bf16(LN(ffh[:, :I] * gelu_tanh(ffh[:, I:])))  (ffh bf16 [row][4096])
__global__ __launch_bounds__(256) void k_ffn_ln(const unsigned short* __restrict__ ffh,
                                                unsigned short* __restrict__ out) {
    int row = blockIdx.x, t = threadIdx.x;
    const unsigned short* ar = ffh + (size_t)row * 4096 + t * 8;
    const unsigned short* gr = ar + II;
    ushort4 a0 = *(const ushort4*)ar;
    ushort4 a1 = *(const ushort4*)(ar + 4);
    ushort4 g0 = *(const ushort4*)gr;
    ushort4 g1 = *(const ushort4*)(gr + 4);
    float av[8] = {b2f(a0.x), b2f(a0.y), b2f(a0.z), b2f(a0.w),
                   b2f(a1.x), b2f(a1.y), b2f(a1.z), b2f(a1.w)};
    float gv[8] = {b2f(g0.x), b2f(g0.y), b2f(g0.z), b2f(g0.w),
                   b2f(g1.x), b2f(g1.y), b2f(g1.z), b2f(g1.w)};
    float v[8];
    float s = 0.f, ss = 0.f;
#pragma unroll
    for (int e = 0; e < 8; ++e) {
        float x = av[e] * gelu_tanh(gv[e]);
        v[e] = x;
        s += x; ss += x * x;
    }
    float2 r2 = blockReduceSum2(s, ss);
    float mean = r2.x * (1.0f / II);
    float var = r2.y * (1.0f / II) - mean * mean;
    float rs = rsqrtf(var + 1e-7f);
    ushort4 o0, o1;
    o0.x = f2b((v[0] - mean) * rs); o0.y = f2b((v[1] - mean) * rs);
    o0.z = f2b((v[2] - mean) * rs); o0.w = f2b((v[3] - mean) * rs);
    o1.x = f2b((v[4] - mean) * rs); o1.y = f2b((v[5] - mean) * rs);
    o1.z = f2b((v[6] - mean) * rs); o1.w = f2b((v[7] - mean) * rs);
    unsigned short* o = out + (size_t)row * II + t * 8;
    *(ushort4*)o = o0;
    *(ushort4*)(o + 4) = o1;
}

// ---------------------------------------------------------------------------
// bf16 MFMA GEMM (m97 structure + bijective XCD swizzle + z-batch) —
// used only for the batched posproj at setup.
// ---------------------------------------------------------------------------
template <int OBF>
__global__ __launch_bounds__(256) void k_gemm_bf16(const unsigned short* __restrict__ A, int lda,
                                                   const unsigned short* __restrict__ W, int ldw,
                                                   void* __restrict__ Cv, int ldc,
                                                   int M, int N, int K,
                                                   const float* __restrict__ bias,
                                                   const float* __restrict__ bias2,
                                                   const float* __restrict__ res,
                                                   size_t wz, size_t cz, size_t bz) {
    __shared__ unsigned short As[128 * 32];
    __shared__ unsigned short Ws[128 * 32];
    int zz = blockIdx.z;
    W += (size_t)zz * wz;
    if (bias) bias += (size_t)zz * bz;
    int nwg = gridDim.x * gridDim.y;
    int orig = blockIdx.y * gridDim.x + blockIdx.x;
    int qq = nwg >> 3, rr = nwg & 7;
    int xcd = orig & 7, idx = orig >> 3;
    int wg = (xcd < rr ? xcd * (qq + 1) : rr * (qq + 1) + (xcd - rr) * qq) + idx;
    int bx = wg % gridDim.x, by = wg / gridDim.x;

    const int t = threadIdx.x;
    const int lane = t & 63, wid = t >> 6;
    const int row0 = by * 128, col0 = bx * 128;
    const int wr = (wid >> 1) * 64, wc = (wid & 1) * 64;
    const int rA = lane & 15, kA = (lane >> 4) * 8;

    f32x4 acc[4][4] = {};

    for (int k0 = 0; k0 < K; k0 += 32) {
#pragma unroll
        for (int j = 0; j < 2; ++j) {
            int c = t + j * 256;
            int r = c >> 2, ko = (c & 3) * 8;
            const unsigned short* srcA = A + (size_t)(row0 + r) * lda + k0 + ko;
            const unsigned short* srcB = W + (size_t)(col0 + r) * ldw + k0 + ko;
            unsigned short* dstA = As + (size_t)(j * 256 + wid * 64) * 8;
            unsigned short* dstB = Ws + (size_t)(j * 256 + wid * 64) * 8;
            __builtin_amdgcn_global_load_lds(
                (const __attribute__((address_space(1))) void*)srcA,
                (__attribute__((address_space(3))) void*)dstA, 16, 0, 0);
            __builtin_amdgcn_global_load_lds(
                (const __attribute__((address_space(1))) void*)srcB,
                (__attribute__((address_space(3))) void*)dstB, 16, 0, 0);
        }
        __syncthreads();
        bf16x8 af[4], bfr[4];
#pragma unroll
        for (int m = 0; m < 4; ++m)
            af[m] = *(const bf16x8*)&As[(wr + m * 16 + rA) * 32 + kA];
#pragma unroll
        for (int n = 0; n < 4; ++n)
            bfr[n] = *(const bf16x8*)&Ws[(wc + n * 16 + rA) * 32 + kA];
#pragma unroll
        for (int m = 0; m < 4; ++m)
#pragma unroll
            for (int n = 0; n < 4; ++n)
                acc[m][n] = __builtin_amdgcn_mfma_f32_16x16x32_bf16(af[m], bfr[n], acc[m][n], 0, 0, 0);
        __syncthreads();
    }

    float* Cf = (float*)Cv + (size_t)zz * cz;
    unsigned short* Cb = (unsigned short*)Cv + (size_t)zz * cz;
    const int cl = lane & 15, rg = (lane >> 4) * 4;
#pragma unroll
    for (int n = 0; n < 4; ++n) {
        int gc = col0 + wc + n * 16 + cl;
        float bv = 0.0f;
        if (bias) bv = (bias2 && gc >= 1536) ? bias2[gc - 1536] : bias[gc];
#pragma unroll
        for (int m = 0; m < 4; ++m) {
#pragma unroll
            for (int i = 0; i < 4; ++i) {
                int gr = row0 + wr + m * 16 + rg + i;
                float v = acc[m][n][i] + bv;
                if (OBF) {
                    Cb[(size_t)gr * ldc + gc] = f2b(v);
                } else {
                    if (res) v += res[(size_t)gr * ldc + gc];
                    Cf[(size_t)gr * ldc + gc] = v;
                }
            }
        }
    }
}

// ---------------------------------------------------------------------------
// Skinny bf16 MFMA GEMM for N=768 (Wout, W2), 2-slot pipelined
// ---------------------------------------------------------------------------
#define SKSLOT 16384  /* 16 KB per slot: A 8KB @0, B 8KB @8192 */

__device__ __forceinline__ void sk_stage(const unsigned short* __restrict__ Ab, int lda,
                                         const unsigned short* __restrict__ Wb, int ldw,
                                         unsigned char* slot, int t, int wid) {
    int rit = t >> 3;
    int kb = (t & 7) << 4;
#pragma unroll
    for (int c = 0; c < 2; ++c) {
        int row = c * 32 + rit;
        int gkb = kb ^ ((row & 7) << 4);
        const unsigned short* src = Ab + (size_t)row * lda + (gkb >> 1);
        unsigned char* dst = slot + c * 4096 + wid * 1024;
        __builtin_amdgcn_global_load_lds(
            (const __attribute__((address_space(1))) void*)src,
            (__attribute__((address_space(3))) void*)dst, 16, 0, 0);
    }
#pragma unroll
    for (int c = 0; c < 2; ++c) {
        int row = c * 32 + rit;
        int gkb = kb ^ ((row & 7) << 4);
        const unsigned short* src = Wb + (size_t)row * ldw + (gkb >> 1);
        unsigned char* dst = slot + 8192 + c * 4096 + wid * 1024;
        __builtin_amdgcn_global_load_lds(
            (const __attribute__((address_space(1))) void*)src,
            (__attribute__((address_space(3))) void*)dst, 16, 0, 0);
    }
}

__device__ __forceinline__ void sk_compute(const unsigned char* slot, int wr, int wc,
                                           int rA, int g16, f32x4 acc[2][2]) {
    const unsigned char* Ab = slot;
    const unsigned char* Bb = slot + 8192;
    bf16x8 a[2][2], b[2][2];
#pragma unroll
    for (int m = 0; m < 2; ++m) {
        int row = wr + m * 16 + rA;
        int sw = (row & 7) << 4;
#pragma unroll
        for (int s = 0; s < 2; ++s)
            a[m][s] = *(const bf16x8*)(Ab + row * 128 + ((s * 64 + g16 * 16) ^ sw));
    }
#pragma unroll
    for (int n = 0; n < 2; ++n) {
        int row = wc + n * 16 + rA;
        int sw = (row & 7) << 4;
#pragma unroll
        for (int s = 0; s < 2; ++s)
            b[n][s] = *(const bf16x8*)(Bb + row * 128 + ((s * 64 + g16 * 16) ^ sw));
    }
    __builtin_amdgcn_s_setprio(1);
#pragma unroll
    for (int m = 0; m < 2; ++m)
#pragma unroll
        for (int n = 0; n < 2; ++n) {
            acc[m][n] = __builtin_amdgcn_mfma_f32_16x16x32_bf16(a[m][0], b[n][0], acc[m][n], 0, 0, 0);
            acc[m][n] = __builtin_amdgcn_mfma_f32_16x16x32_bf16(a[m][1], b[n][1], acc[m][n], 0, 0, 0);
        }
    __builtin_amdgcn_s_setprio(0);
}

__global__ __launch_bounds__(256) void k_gemm_skinny(const unsigned short* __restrict__ A, int lda,
                                                     const unsigned short* __restrict__ W, int ldw,
                                                     float* __restrict__ C, int ldc,
                                                     int M, int N, int K,
                                                     const float* __restrict__ bias,
                                                     const float* __restrict__ res) {
    __shared__ unsigned char smem[2 * SKSLOT];
    int nwg = gridDim.x * gridDim.y;
    int orig = blockIdx.y * gridDim.x + blockIdx.x;
    int qq = nwg >> 3, rr = nwg & 7;
    int xcd = orig & 7, idx = orig >> 3;
    int wg = (xcd < rr ? xcd * (qq + 1) : rr * (qq + 1) + (xcd - rr) * qq) + idx;
    int bx = wg % gridDim.x, by = wg / gridDim.x;

    const int t = threadIdx.x;
    const int lane = t & 63, wid = t >> 6;
    const int row0 = by * 64, col0 = bx * 64;
    const int wr = (wid >> 1) * 32, wc = (wid & 1) * 32;
    const int rA = lane & 15, g16 = lane >> 4;
    const unsigned short* Abase = A + (size_t)row0 * lda;
    const unsigned short* Wbase = W + (size_t)col0 * ldw;

    const int nt = K >> 6;
    f32x4 acc[2][2] = {};

    sk_stage(Abase, lda, Wbase, ldw, smem, t, wid);

    for (int tt = 0; tt < nt; ++tt) {
        asm volatile("s_barrier" ::: "memory");
        if (tt + 1 < nt) {
            sk_stage(Abase + (size_t)(tt + 1) * 64, lda, Wbase + (size_t)(tt + 1) * 64,
                     ldw, smem + (size_t)((tt + 1) & 1) * SKSLOT, t, wid);
            asm volatile("s_waitcnt vmcnt(4)" ::: "memory");
        } else {
            asm volatile("s_waitcnt vmcnt(0)" ::: "memory");
        }
        asm volatile("s_barrier" ::: "memory");
        sk_compute(smem + (size_t)(tt & 1) * SKSLOT, wr, wc, rA, g16, acc);
    }

    const int cl = lane & 15, rg = (lane >> 4) * 4;
#pragma unroll
    for (int n = 0; n < 2; ++n) {
        int gc = col0 + wc + n * 16 + cl;
        float bv = bias ? bias[gc] : 0.0f;
#pragma unroll
        for (int m = 0; m < 2; ++m) {
#pragma unroll
            for (int i = 0; i < 4; ++i) {
                int gr = row0 + wr + m * 16 + rg + i;
                float v = acc[m][n][i] + bv;
                if (res) v += res[(size_t)gr * ldc + gc];
                C[(size_t)gr * ldc + gc] = v;
            }
        }
    }
}

// ---------------------------------------------------------------------------
// Pipelined bf16 MFMA GEMM for the large GEMMs (qkvg, W1)
// ---------------------------------------------------------------------------
#define GSLOT 49152  /* 48 KB: A 16KB @0, B 32KB @16384 */

__device__ __forceinline__ void g_stage(const unsigned short* __restrict__ Abase, int lda,
                                        const unsigned short* __restrict__ Wbase, int ldw,
                                        unsigned char* slot, int t, int wid) {
    int rit = t >> 3;
    int kb = (t & 7) << 4;
#pragma unroll
    for (int c = 0; c < 2; ++c) {
        int row = c * 64 + rit;
        int gkb = kb ^ ((row & 7) << 4);
        const unsigned short* src = Abase + (size_t)row * lda + (gkb >> 1);
        unsigned char* dst = slot + c * 8192 + wid * 1024;
        __builtin_amdgcn_global_load_lds(
            (const __attribute__((address_space(1))) void*)src,
            (__attribute__((address_space(3))) void*)dst, 16, 0, 0);
    }
#pragma unroll
    for (int c = 0; c < 4; ++c) {
        int row = c * 64 + rit;
        int gkb = kb ^ ((row & 7) << 4);
        const unsigned short* src = Wbase + (size_t)row * ldw + (gkb >> 1);
        unsigned char* dst = slot + 16384 + c * 8192 + wid * 1024;
        __builtin_amdgcn_global_load_lds(
            (const __attribute__((address_space(1))) void*)src,
            (__attribute__((address_space(3))) void*)dst, 16, 0, 0);
    }
}

__device__ __forceinline__ void g_compute(const unsigned char* slot, int wm, int wn,
                                          int rA, int g16, f32x4 acc[4][4]) {
    const unsigned char* Ab = slot;
    const unsigned char* Bb = slot + 16384;
    bf16x8 a[4][2], b[4][2];
#pragma unroll
    for (int m = 0; m < 4; ++m) {
        int row = wm * 64 + m * 16 + rA;
        int sw = (row & 7) << 4;
#pragma unroll
        for (int s = 0; s < 2; ++s)
            a[m][s] = *(const bf16x8*)(Ab + row * 128 + ((s * 64 + g16 * 16) ^ sw));
    }
#pragma unroll
    for (int n = 0; n < 4; ++n) {
        int row = wn * 64 + n * 16 + rA;
        int sw = (row & 7) << 4;
#pragma unroll
        for (int s = 0; s < 2; ++s)
            b[n][s] = *(const bf16x8*)(Bb + row * 128 + ((s * 64 + g16 * 16) ^ sw));
    }
    __builtin_amdgcn_s_setprio(1);
#pragma unroll
    for (int m = 0; m < 4; ++m)
#pragma unroll
        for (int n = 0; n < 4; ++n) {
            acc[m][n] = __builtin_amdgcn_mfma_f32_16x16x32_bf16(a[m][0], b[n][0], acc[m][n], 0, 0, 0);
            acc[m][n] = __builtin_amdgcn_mfma_f32_16x16x32_bf16(a[m][1], b[n][1], acc[m][n], 0, 0, 0);
        }
    __builtin_amdgcn_s_setprio(0);
}

template <int OBF>
__global__ __launch_bounds__(512, 1) void k_gemm_big(const unsigned short* __restrict__ A, int lda,
                                                     const unsigned short* __restrict__ W,
                                                     const unsigned short* __restrict__ Wb2, int ldw,
                                                     void* __restrict__ Cv, int ldc,
                                                     int M, int N, int K,
                                                     const float* __restrict__ bias,
                                                     const float* __restrict__ bias2,
                                                     const float* __restrict__ res) {
    extern __shared__ unsigned char smem[];
    int nwg = gridDim.x * gridDim.y;
    int orig = blockIdx.y * gridDim.x + blockIdx.x;
    int qq = nwg >> 3, rr = nwg & 7;
    int xcd = orig & 7, idx = orig >> 3;
    int wg = (xcd < rr ? xcd * (qq + 1) : rr * (qq + 1) + (xcd - rr) * qq) + idx;
    int bx = wg % gridDim.x, by = wg / gridDim.x;

    const int t = threadIdx.x;
    const int lane = t & 63, wid = t >> 6;
    const int wm = wid >> 2, wn = wid & 3;
    const int rA = lane & 15, g16 = lane >> 4;
    const int row0 = by * 128, col0 = bx * 256;
    const unsigned short* Abase = A + (size_t)row0 * lda;
    const unsigned short* Wbase = (Wb2 && col0 >= 1536)
                                      ? Wb2 + (size_t)(col0 - 1536) * ldw
                                      : W + (size_t)col0 * ldw;

    const int nt = K >> 6;
    f32x4 acc[4][4] = {};

    g_stage(Abase, lda, Wbase, ldw, smem, t, wid);
    g_stage(Abase + 64, lda, Wbase + 64, ldw, smem + GSLOT, t, wid);

#define GBAR() asm volatile("s_barrier" ::: "memory")
#define GITER(T, STG, VMSTR)                                                        \
    do {                                                                            \
        GBAR();                                                                     \
        if (STG)                                                                    \
            g_stage(Abase + (size_t)(T + 2) * 64, lda, Wbase + (size_t)(T + 2) * 64,\
                    ldw, smem + (size_t)((T + 2) % 3) * GSLOT, t, wid);             \
        asm volatile(VMSTR ::: "memory");                                           \
        GBAR();                                                                     \
        g_compute(smem + (size_t)((T) % 3) * GSLOT, wm, wn, rA, g16, acc);          \
    } while (0)

    int tt = 0;
    for (; tt < nt - 2; ++tt) GITER(tt, true, "s_waitcnt vmcnt(12)");
    GITER(tt, false, "s_waitcnt vmcnt(6)");
    ++tt;
    GITER(tt, false, "s_waitcnt vmcnt(0)");
#undef GITER
#undef GBAR

    float* Cf = (float*)Cv;
    unsigned short* Cb = (unsigned short*)Cv;
    const int cl = lane & 15, rg = (lane >> 4) * 4;
#pragma unroll
    for (int n = 0; n < 4; ++n) {
        int gc = col0 + wn * 64 + n * 16 + cl;
        float bv = 0.0f;
        if (bias) bv = (bias2 && gc >= 1536) ? bias2[gc - 1536] : bias[gc];
#pragma unroll
        for (int m = 0; m < 4; ++m) {
#pragma unroll
            for (int i = 0; i < 4; ++i) {
                int gr = row0 + wm * 64 + m * 16 + rg + i;
                float v = acc[m][n][i] + bv;
                if (OBF) {
                    Cb[(size_t)gr * ldc + gc] = f2b(v);
                } else {
                    if (res) v += res[(size_t)gr * ldc + gc];
                    Cf[(size_t)gr * ldc + gc] = v;
                }
            }
        }
    }
}

// ---------------------------------------------------------------------------
// merged: repack (blockIdx.x<8) + cp/pc MFMA (blockIdx.x>=8); grid (16, 96)
// ---------------------------------------------------------------------------
__global__ __launch_bounds__(256) void k_repack_cppc(const unsigned short* __restrict__ qkvg,
                                                     const unsigned short* __restrict__ pp,
                                                     unsigned short* __restrict__ qT,
                                                     unsigned short* __restrict__ kT,
                                                     unsigned short* __restrict__ vT,
                                                     float* __restrict__ cp,
                                                     float* __restrict__ pc) {
    __shared__ unsigned char shmem[12288];
    int t = threadIdx.x;
    if (blockIdx.x < 8) {
        unsigned short (*tile)[72] = (unsigned short(*)[72])shmem;
        int bh = blockIdx.y;
        int b = bh / NHH, h = bh % NHH;
        int s0 = blockIdx.x * 64;
#pragma unroll
        for (int j = 0; j < 2; ++j) {
            int idx = t + j * 256;
            int r = idx >> 3, dc = idx & 7;
            const unsigned short* src = qkvg + ((size_t)(s0 + r) * BB + b) * 3072 + h * DD + dc * 8;
            ushort4 a = *(const ushort4*)src;
            ushort4 c = *(const ushort4*)(src + 4);
            unsigned short* dq = qT + ((size_t)bh * SS + s0 + r) * DD + dc * 8;
            *(ushort4*)dq = a; *(ushort4*)(dq + 4) = c;
            const unsigned short* srck = src + HH;
            ushort4 a2 = *(const ushort4*)srck;
            ushort4 c2 = *(const ushort4*)(srck + 4);
            unsigned short* dk = kT + ((size_t)bh * SS + s0 + r) * DD + dc * 8;
            *(ushort4*)dk = a2; *(ushort4*)(dk + 4) = c2;
        }
#pragma unroll
        for (int j = 0; j < 4; ++j) {
            int idx = t + j * 256;
            int r = idx >> 4, c4 = idx & 15;
            ushort4 u = *(const ushort4*)(qkvg + ((size_t)(s0 + r) * BB + b) * 3072 + 1536 + h * DD + c4 * 4);
            *(ushort4*)&tile[r][c4 * 4] = u;
        }
        __syncthreads();
#pragma unroll
        for (int j = 0; j < 2; ++j) {
            int idx = t + j * 256;
            int d = idx >> 3, s8 = idx & 7;
            ushort4 a, c;
            a.x = tile[s8 * 8 + 0][d]; a.y = tile[s8 * 8 + 1][d];
            a.z = tile[s8 * 8 + 2][d]; a.w = tile[s8 * 8 + 3][d];
            c.x = tile[s8 * 8 + 4][d]; c.y = tile[s8 * 8 + 5][d];
            c.z = tile[s8 * 8 + 6][d]; c.w = tile[s8 * 8 + 7][d];
            unsigned short* dst = vT + ((size_t)bh * DD + d) * SS + s0 + s8 * 8;
            *(ushort4*)dst = a; *(ushort4*)(dst + 4) = c;
        }
    } else {
        int cid = (blockIdx.x - 8) * 96 + blockIdx.y;
        int z = cid >= 384;
        int rem = cid - (z ? 384 : 0);
        int h = rem >> 5;
        int mt = rem & 31;
        int aoff = z ? HH : 0;
        int toff = z ? 0 : HH;
        float* out = z ? pc : cp;
        unsigned short* As = (unsigned short*)shmem;
        unsigned short* Bs = (unsigned short*)(shmem + 8192);
        const int lane = t & 63, wid = t >> 6;
        const int rA = lane & 15, kA = (lane >> 4) * 8;

        f32x4 acc[2][4] = {};

        for (int k0 = 0; k0 < 64; k0 += 32) {
#pragma unroll
            for (int j = 0; j < 2; ++j) {
                int c = t + j * 256;
                int r = c >> 2, ko = (c & 3) * 8;
                const unsigned short* srcA = qkvg + (size_t)(mt * 128 + r) * 3072 + aoff + h * DD + k0 + ko;
                unsigned short* dstA = As + (size_t)(j * 256 + wid * 64) * 8;
                __builtin_amdgcn_global_load_lds(
                    (const __attribute__((address_space(1))) void*)srcA,
                    (__attribute__((address_space(3))) void*)dstA, 16, 0, 0);
            }
            {
                int r = t >> 2, ko = (t & 3) * 8;
                const unsigned short* srcB = pp + (size_t)r * 1536 + toff + h * DD + k0 + ko;
                unsigned short* dstB = Bs + (size_t)(wid * 64) * 8;
                __builtin_amdgcn_global_load_lds(
                    (const __attribute__((address_space(1))) void*)srcB,
                    (__attribute__((address_space(3))) void*)dstB, 16, 0, 0);
            }
            __syncthreads();
            bf16x8 af[2], bfr[4];
#pragma unroll
            for (int m = 0; m < 2; ++m)
                af[m] = *(const bf16x8*)&As[(wid * 32 + m * 16 + rA) * 32 + kA];
#pragma unroll
            for (int n = 0; n < 4; ++n)
                bfr[n] = *(const bf16x8*)&Bs[(n * 16 + rA) * 32 + kA];
#pragma unroll
            for (int m = 0; m < 2; ++m)
#pragma unroll
                for (int n = 0; n < 4; ++n)
                    acc[m][n] = __builtin_amdgcn_mfma_f32_16x16x32_bf16(af[m], bfr[n], acc[m][n], 0, 0, 0);
            __syncthreads();
        }

        const int cl = lane & 15, rg = (lane >> 4) * 4;
#pragma unroll
        for (int m = 0; m < 2; ++m)
#pragma unroll
            for (int n = 0; n < 4; ++n) {
                int gc = n * 16 + cl;
                if (gc < 63) {
#pragma unroll
                    for (int i = 0; i < 4; ++i) {
                        int gr = mt * 128 + wid * 32 + m * 16 + rg + i;
                        int sIdx = gr >> 3, bIdx = gr & 7;
                        out[(((size_t)(bIdx * NHH + h)) * SS + sIdx) * 63 + gc] = acc[m][n][i];
                    }
                }
            }
    }
}

// ---------------------------------------------------------------------------
// fused disentangled flash attention v4:
//   cps table bf16 (converted ONCE at block init, outside the K-loop);
//   pcs stays f32 (raw float4 staging, no hot-loop conversion).
//   LDS 37.5 KB -> 4 blocks/CU (vs 45.5 KB / 3). Hot-loop delta vs v2:
//   one b2f shift per cps gather only.
// ---------------------------------------------------------------------------
__global__ __launch_bounds__(256) void k_attn_fused(
    const unsigned short* __restrict__ qT, const unsigned short* __restrict__ kT,
    const unsigned short* __restrict__ vT, const float* __restrict__ cp,
    const float* __restrict__ pc, const int* __restrict__ bucket,
    const int* __restrict__ mask, float* __restrict__ ctxr) {
    __shared__ unsigned short cps[64 * 63];        // 8064 B (bf16, block-static)
    __shared__ float pcs[64 * 63];                 // 16128 B (f32, per K-tile)
    __shared__ unsigned short pb_all[4][16 * 72];  // 9216 B
    __shared__ int btab[1023];                     // 4092 B   => 37.5 KB total
    int t = threadIdx.x;
    int lane = t & 63, wid = t >> 6;
    int bh = blockIdx.y;
    int b = bh / NHH, h = bh % NHH;
    int qb0 = blockIdx.x * 64;
    int q0 = qb0 + wid * 16;
    int rA = lane & 15, g = lane >> 4, kA = g * 8;
    unsigned short* pb = pb_all[wid];
    const unsigned short* qTb = qT + (size_t)bh * SS * DD;
    const unsigned short* kTb = kT + (size_t)bh * SS * DD;
    const unsigned short* vTb = vT + (size_t)bh * DD * SS;
    const float* cpb = cp + (size_t)bh * SS * 63 + (size_t)qb0 * 63;
    const float* pcb = pc + (size_t)bh * SS * 63;
    const int* mkb = mask + b * SS;

    for (int i = t; i < 1023; i += 256) btab[i] = bucket[i];
    for (int i = t; i < 1008; i += 256) {
        float4 d = ((const float4*)cpb)[i];
        ushort4 u;
        u.x = f2b(d.x); u.y = f2b(d.y); u.z = f2b(d.z); u.w = f2b(d.w);
        ((ushort4*)cps)[i] = u;
    }

    bf16x8 aq[2];
#pragma unroll
    for (int dc = 0; dc < 2; ++dc)
        aq[dc] = *(const bf16x8*)&qTb[(size_t)(q0 + rA) * DD + dc * 32 + kA];

    f32x4 o[4] = {};
    float mrow[4], lrow[4];
#pragma unroll
    for (int i = 0; i < 4; ++i) { mrow[i] = -INFINITY; lrow[i] = 0.f; }

    for (int kt = 0; kt < 8; ++kt) {
        int k0 = kt * 64;
        __syncthreads();  // all waves done reading pcs (prev iter); covers cps+btab on kt=0
        {
            const float4* src = (const float4*)(pcb + (size_t)k0 * 63);
            for (int i = t; i < 1008; i += 256) ((float4*)pcs)[i] = src[i];
        }
        // ---- S = Q.K^T (independent of pcs; covers stage latency) ----
        f32x4 sa[4] = {};
#pragma unroll
        for (int n = 0; n < 4; ++n) {
            bf16x8 bk0 = *(const bf16x8*)&kTb[(size_t)(k0 + n * 16 + rA) * DD + kA];
            bf16x8 bk1 = *(const bf16x8*)&kTb[(size_t)(k0 + n * 16 + rA) * DD + 32 + kA];
            sa[n] = __builtin_amdgcn_mfma_f32_16x16x32_bf16(aq[0], bk0, sa[n], 0, 0, 0);
            sa[n] = __builtin_amdgcn_mfma_f32_16x16x32_bf16(aq[1], bk1, sa[n], 0, 0, 0);
        }
        int mk[4];
#pragma unroll
        for (int n = 0; n < 4; ++n) mk[n] = mkb[k0 + n * 16 + rA];
        __syncthreads();  // pcs visible

        // ---- bias + mask + online softmax (gathers in LDS) ----
        float pv[4][4];
#pragma unroll
        for (int i = 0; i < 4; ++i) {
            int qr = wid * 16 + g * 4 + i;
            int q = qb0 + qr;
            float sv[4];
            float tmax = -INFINITY;
#pragma unroll
            for (int n = 0; n < 4; ++n) {
                int kr = n * 16 + rA;
                int id = btab[q - (k0 + kr) + 511];
                float v = (sa[n][i] + b2f(cps[qr * 63 + id]) + pcs[kr * 63 + id]) * SCALE_F;
                v = mk[n] ? -1e9f : v;
                sv[n] = v;
                tmax = fmaxf(tmax, v);
            }
            tmax = fmaxf(tmax, __shfl_xor(tmax, 1, 16));
            tmax = fmaxf(tmax, __shfl_xor(tmax, 2, 16));
            tmax = fmaxf(tmax, __shfl_xor(tmax, 4, 16));
            tmax = fmaxf(tmax, __shfl_xor(tmax, 8, 16));
            float mold = mrow[i];
            float mnew = fmaxf(mold, tmax);
            float ls = 0.f;
#pragma unroll
            for (int n = 0; n < 4; ++n) {
                float p = __expf(sv[n] - mnew);
                pv[n][i] = p;
                ls += p;
            }
            ls += __shfl_xor(ls, 1, 16);
            ls += __shfl_xor(ls, 2, 16);
            ls += __shfl_xor(ls, 4, 16);
            ls += __shfl_xor(ls, 8, 16);
            if (mnew > mold) {
                float alpha = __expf(mold - mnew);
                lrow[i] = lrow[i] * alpha + ls;
                mrow[i] = mnew;
#pragma unroll
                for (int n = 0; n < 4; ++n) o[n][i] *= alpha;
            } else {
                lrow[i] += ls;
            }
        }
        // ---- P -> bf16 via wave-local LDS transpose ----
#pragma unroll
        for (int n = 0; n < 4; ++n)
#pragma unroll
            for (int i = 0; i < 4; ++i)
                pb[(g * 4 + i) * 72 + n * 16 + rA] = f2b(pv[n][i]);
        // ---- O += P.V ----
        bf16x8 ap[2];
#pragma unroll
        for (int kc = 0; kc < 2; ++kc)
            ap[kc] = *(const bf16x8*)&pb[rA * 72 + kc * 32 + kA];
#pragma unroll
        for (int n = 0; n < 4; ++n) {
            bf16x8 bv0 = *(const bf16x8*)&vTb[(size_t)(n * 16 + rA) * SS + k0 + kA];
            bf16x8 bv1 = *(const bf16x8*)&vTb[(size_t)(n * 16 + rA) * SS + k0 + 32 + kA];
            o[n] = __builtin_amdgcn_mfma_f32_16x16x32_bf16(ap[0], bv0, o[n], 0, 0, 0);
            o[n] = __builtin_amdgcn_mfma_f32_16x16x32_bf16(ap[1], bv1, o[n], 0, 0, 0);
        }
    }
#pragma unroll
    for (int i = 0; i < 4; ++i) {
        int q = q0 + g * 4 + i;
        float inv = 1.0f / lrow[i];
#pragma unroll
        for (int n = 0; n < 4; ++n)
            ctxr[((size_t)q * BB + b) * HH + h * DD + n * 16 + rA] = o[n][i] * inv;
    }
}

// ---------------------------------------------------------------------------
// host launcher
// ---------------------------------------------------------------------------
static inline void gemm_big(const unsigned short* A, int lda,
                            const unsigned short* W, const unsigned short* Wb2, int ldw,
                            void* C, int ldc, int M, int N, int K,
                            const float* bias, const float* bias2, const float* res,
                            int obf, hipStream_t st) {
    dim3 g(N / 256, M / 128);
    if (obf)
        k_gemm_big<1><<<g, 512, 3 * GSLOT, st>>>(A, lda, W, Wb2, ldw, C, ldc, M, N, K, bias, bias2, res);
    else
        k_gemm_big<0><<<g, 512, 3 * GSLOT, st>>>(A, lda, W, Wb2, ldw, C, ldc, M, N, K, bias, bias2, res);
}

extern "C" void kernel_launch(void* const* d_in, const int* in_sizes, int n_in,
                              void* d_out, int out_size, void* d_ws, size_t ws_size,
                              hipStream_t stream) {
    static int attr_done = 0;
    if (!attr_done) {
        hipFuncSetAttribute((const void*)&k_gemm_big<1>,
                            hipFuncAttributeMaxDynamicSharedMemorySize, 3 * GSLOT);
        hipFuncSetAttribute((const void*)&k_gemm_big<0>,
                            hipFuncAttributeMaxDynamicSharedMemorySize, 3 * GSLOT);
        attr_done = 1;
    }

    const int* ids = (const int*)d_in[0];
    const unsigned char* maskraw = (const unsigned char*)d_in[1];
    const float* word_emb = (const float*)d_in[2];
    const float* rel_emb = (const float*)d_in[3];
    const float* rel_g = (const float*)d_in[4];
    const float* rel_b = (const float*)d_in[5];
    const float* Wqk = (const float*)d_in[6];
    const float* bqk = (const float*)d_in[7];
    const float* Wvg = (const float*)d_in[8];
    const float* bvg = (const float*)d_in[9];
    const float* Wout = (const float*)d_in[10];
    const float* bout = (const float*)d_in[11];
    const float* W1 = (const float*)d_in[12];
    const float* W2 = (const float*)d_in[13];

    const size_t N_X = (size_t)SS * BB * HH;
    const size_t N_CP = (size_t)SS * BB * NHH * 63;
    const size_t N_H2 = (size_t)SS * BB * II;
    const size_t N_WQK = (size_t)2 * HH * HH;
    const size_t N_WOUT = (size_t)HH * HH;
    const size_t N_W1 = (size_t)2 * II * HH;
    const size_t N_W2 = (size_t)HH * II;
    const size_t N_HD = (size_t)BB * NHH * SS * DD;
    const size_t N_QKVG = (size_t)SS * BB * 3072;
    const size_t N_FFH = (size_t)SS * BB * 4096;
    const size_t N_PP = (size_t)128 * 1536;

    float* ws = (float*)d_ws;
    float* x = ws;
    float* ctxr = x + N_X;
    float* cp = ctxr + N_X;
    float* pc = cp + N_CP;
    unsigned short* us = (unsigned short*)(pc + N_CP);
    unsigned short* qkvg = us;
    unsigned short* hs_bf = qkvg + N_QKVG;
    unsigned short* ctx_bf = hs_bf + N_X;
    unsigned short* h2_bf = ctx_bf + N_X;
    unsigned short* ffh = h2_bf + N_H2;
    unsigned short* wqk_all = ffh + N_FFH;
    unsigned short* wvg_bf = wqk_all + 12 * N_WQK;
    unsigned short* wout_bf = wvg_bf + N_WQK;
    unsigned short* w1_bf = wout_bf + N_WOUT;
    unsigned short* w2_bf = w1_bf + N_W1;
    unsigned short* ppall = w2_bf + N_W2;
    unsigned short* rel_bf = ppall + 12 * N_PP;
    unsigned short* qT = rel_bf + 128 * HH;
    unsigned short* kT = qT + N_HD;
    unsigned short* vT = kT + N_HD;
    int* bucket = (int*)(vT + N_HD);
    int* maski = bucket + 1024;

    size_t need_bytes = ((size_t)(maski + BB * SS) - (size_t)d_ws);
    if (ws_size < need_bytes) return;  // ~205 MB required

    // ---- setup ----
    k_decode_mask<<<1, 256, 0, stream>>>(maskraw, maski, BB * SS);
    k_bucket<<<4, 256, 0, stream>>>(bucket);
    k_embed_ln<<<SS * BB, 256, 0, stream>>>(ids, word_emb, x);
    k_rel_ln_bf<<<128, 256, 0, stream>>>(rel_emb, rel_g, rel_b, rel_bf);
    k_f2b<<<(int)((12 * N_WQK / 8 + 255) / 256), 256, 0, stream>>>(Wqk, wqk_all,
                                                                   (int)(12 * N_WQK / 8));
    {
        dim3 gpp(1536 / 128, 1, 12);
        k_gemm_bf16<1><<<gpp, 256, 0, stream>>>(rel_bf, HH, wqk_all, HH, ppall, 1536,
                                                128, 1536, HH, bqk, nullptr, nullptr,
                                                N_WQK, N_PP, 2 * HH);
    }

    for (int l = 0; l < LL; ++l) {
        const unsigned short* wqk_l = wqk_all + (size_t)l * N_WQK;
        const float* bqk_l = bqk + (size_t)l * 2 * HH;
        const float* Wvg_l = Wvg + (size_t)l * N_WQK;
        const float* bvg_l = bvg + (size_t)l * 2 * HH;
        const float* Wout_l = Wout + (size_t)l * N_WOUT;
        const float* bout_l = bout + (size_t)l * HH;
        const float* W1_l = W1 + (size_t)l * N_W1;
        const float* W2_l = W2 + (size_t)l * N_W2;

        // ---- attention ----
        k_f2b_ln<<<3169 + SS * BB, 256, 0, stream>>>(Wvg_l, Wout_l, W1_l, W2_l, wvg_bf,
                                                     x, hs_bf);
        gemm_big(hs_bf, HH, wqk_l, wvg_bf, HH, qkvg, 3072, SS * BB, 3072, HH,
                 bqk_l, bvg_l, nullptr, 1, stream);
        k_repack_cppc<<<dim3(16, 96), 256, 0, stream>>>(qkvg, ppall + (size_t)l * N_PP,
                                                        qT, kT, vT, cp, pc);
        k_attn_fused<<<dim3(SS / 64, BB * NHH), 256, 0, stream>>>(qT, kT, vT, cp, pc,
                                                                  bucket, maski, ctxr);
        k_gated_ln<<<SS * BB, 256, 0, stream>>>(ctxr, qkvg, ctx_bf);
        k_gemm_skinny<<<dim3(HH / 64, SS * BB / 64), 256, 0, stream>>>(
            ctx_bf, HH, wout_bf, HH, x, HH, SS * BB, HH, HH, bout_l, x);

        // ---- GeGLU FFN ----
        k_ln_bf<<<SS * BB, 256, 0, stream>>>(x, hs_bf);
        gemm_big(hs_bf, HH, w1_bf, nullptr, HH, ffh, 4096, SS * BB, 4096, HH,
                 nullptr, nullptr, nullptr, 1, stream);
        k_ffn_ln<<<SS * BB, 256, 0, stream>>>(ffh, h2_bf);
        // last layer writes the residual-added output straight into d_out
        float* outC = (l == LL - 1) ? (float*)d_out : x;
        k_gemm_skinny<<<dim3(HH / 64, SS * BB / 64), 256, 0, stream>>>(
            h2_bf, II, w2_bf, II, outC, HH, SS * BB, HH, II, nullptr, x);
    }
}

// Round 13
// 2705.766 us; speedup vs baseline: 1.0452x; 1.0445x over previous
//
#include <hip/hip_runtime.h>
#include <math.h>

#define SS 512
#define BB 8
#define NHH 12
#define DD 64
#define HH 768
#define II 2048
#define LL 12
#define SCALE_F 0.07216878364870323f  /* 1/sqrt(3*64) */

typedef __attribute__((ext_vector_type(8))) short bf16x8;
typedef __attribute__((ext_vector_type(4))) float f32x4;

// f32 -> bf16 (RNE, finite values)
__device__ __forceinline__ unsigned short f2b(float f) {
    union { float f; unsigned int u; } x; x.f = f;
    unsigned int r = x.u + 0x7fffu + ((x.u >> 16) & 1u);
    return (unsigned short)(r >> 16);
}
__device__ __forceinline__ float b2f(unsigned short u) {
    union { unsigned int u; float f; } x; x.u = ((unsigned int)u) << 16;
    return x.f;
}

// ---------------------------------------------------------------------------
// block reduction helpers (blockDim.x == 256)
// ---------------------------------------------------------------------------
__device__ __forceinline__ float2 blockReduceSum2(float a, float b) {
    __shared__ float2 sm[4];
    __shared__ float2 bc;
#pragma unroll
    for (int o = 32; o > 0; o >>= 1) {
        a += __shfl_down(a, o);
        b += __shfl_down(b, o);
    }
    int t = threadIdx.x;
    if ((t & 63) == 0) sm[t >> 6] = make_float2(a, b);
    __syncthreads();
    if (t == 0) {
        float xa = sm[0].x + sm[1].x + sm[2].x + sm[3].x;
        float xb = sm[0].y + sm[1].y + sm[2].y + sm[3].y;
        bc = make_float2(xa, xb);
    }
    __syncthreads();
    return bc;
}

__device__ __forceinline__ float gelu_erf(float v) {
    return 0.5f * v * (1.0f + erff(v * 0.70710678118654752f));
}
__device__ __forceinline__ float gelu_tanh(float v) {
    const float c = 0.7978845608028654f;
    return 0.5f * v * (1.0f + tanhf(c * (v + 0.044715f * v * v * v)));
}

// ---------------------------------------------------------------------------
// mask decode: handle bool-as-u8 or bool-as-int32 layouts
// ---------------------------------------------------------------------------
__global__ __launch_bounds__(256) void k_decode_mask(const unsigned char* __restrict__ raw,
                                                     int* __restrict__ mask, int n) {
    __shared__ int s_any;
    if (threadIdx.x == 0) s_any = 0;
    __syncthreads();
    int local = 0;
    for (int i = threadIdx.x; i < n; i += blockDim.x)
        if ((i & 3) && raw[i]) local = 1;
    if (local) atomicOr(&s_any, 1);
    __syncthreads();
    bool isU8 = (s_any != 0);
    const int* as_int = (const int*)raw;
    for (int i = threadIdx.x; i < n; i += blockDim.x)
        mask[i] = isU8 ? (raw[i] != 0) : (as_int[i] != 0);
}

// ---------------------------------------------------------------------------
// DeBERTa log-bucket table: rel in [-511,511] -> idx in [0,62]
// ---------------------------------------------------------------------------
__global__ __launch_bounds__(256) void k_bucket(int* __restrict__ tab) {
    int i = blockIdx.x * 256 + threadIdx.x;
    if (i >= 1023) return;
    int rel = i - 511;
    int a = rel < 0 ? -rel : rel;
    int abs_pos = (a < 16) ? 15 : (a < 511 ? a : 511);
    int bucket;
    if (abs_pos <= 16) {
        bucket = rel;
    } else {
        double lp = ceil(log((double)abs_pos / 16.0) / log(511.0 / 16.0) * 15.0);
        int l = (int)lp + 16;
        bucket = (rel > 0) ? l : -l;
    }
    int idx = bucket + 31;
    if (idx < 0) idx = 0;
    if (idx > 62) idx = 62;
    tab[i] = idx;
}

// ---------------------------------------------------------------------------
// generic f32 -> bf16 bulk conversion (8 elems/thread)
// ---------------------------------------------------------------------------
__global__ __launch_bounds__(256) void k_f2b(const float* __restrict__ in,
                                             unsigned short* __restrict__ out, int n8) {
    int i = blockIdx.x * 256 + threadIdx.x;
    if (i >= n8) return;
    float4 a = ((const float4*)in)[2 * (size_t)i];
    float4 b = ((const float4*)in)[2 * (size_t)i + 1];
    ushort4 lo, hi;
    lo.x = f2b(a.x); lo.y = f2b(a.y); lo.z = f2b(a.z); lo.w = f2b(a.w);
    hi.x = f2b(b.x); hi.y = f2b(b.y); hi.z = f2b(b.z); hi.w = f2b(b.w);
    ((ushort4*)out)[2 * (size_t)i] = lo;
    ((ushort4*)out)[2 * (size_t)i + 1] = hi;
}

// ---------------------------------------------------------------------------
// merged: per-layer weight conversion (blocks 0..3168) + LN of x (blocks 3169..7264)
// ---------------------------------------------------------------------------
__global__ __launch_bounds__(256) void k_f2b_ln(const float* __restrict__ wvg,
                                                const float* __restrict__ wout,
                                                const float* __restrict__ w1,
                                                const float* __restrict__ w2,
                                                unsigned short* __restrict__ wbf,
                                                const float* __restrict__ x,
                                                unsigned short* __restrict__ hs) {
    int bid = blockIdx.x;
    int t = threadIdx.x;
    if (bid < 3169) {
        int i = bid * 256 + t;
        if (i >= 811008) return;
        const float* src;
        int off;
        if (i < 221184) {
            if (i < 147456) { src = wvg;  off = i; }
            else            { src = wout; off = i - 147456; }
        } else if (i < 614400) { src = w1; off = i - 221184; }
        else                   { src = w2; off = i - 614400; }
        float4 a = ((const float4*)src)[2 * (size_t)off];
        float4 b = ((const float4*)src)[2 * (size_t)off + 1];
        ushort4 lo, hi;
        lo.x = f2b(a.x); lo.y = f2b(a.y); lo.z = f2b(a.z); lo.w = f2b(a.w);
        hi.x = f2b(b.x); hi.y = f2b(b.y); hi.z = f2b(b.z); hi.w = f2b(b.w);
        ((ushort4*)wbf)[2 * (size_t)i] = lo;
        ((ushort4*)wbf)[2 * (size_t)i + 1] = hi;
    } else {
        int row = bid - 3169;
        const float* r = x + (size_t)row * HH;
        float v0 = r[t], v1 = r[t + 256], v2 = r[t + 512];
        float s = v0 + v1 + v2;
        float ss = v0 * v0 + v1 * v1 + v2 * v2;
        float2 r2 = blockReduceSum2(s, ss);
        float mean = r2.x * (1.0f / HH);
        float var = r2.y * (1.0f / HH) - mean * mean;
        float rs = rsqrtf(var + 1e-7f);
        unsigned short* o = hs + (size_t)row * HH;
        o[t] = f2b((v0 - mean) * rs);
        o[t + 256] = f2b((v1 - mean) * rs);
        o[t + 512] = f2b((v2 - mean) * rs);
    }
}

// ---------------------------------------------------------------------------
// LayerNorm family; EPS = 1e-7, biased variance
// ---------------------------------------------------------------------------
__global__ __launch_bounds__(256) void k_ln_bf(const float* __restrict__ in,
                                               unsigned short* __restrict__ out) {
    int row = blockIdx.x, t = threadIdx.x;
    const float* r = in + (size_t)row * HH;
    float v0 = r[t], v1 = r[t + 256], v2 = r[t + 512];
    float s = v0 + v1 + v2;
    float ss = v0 * v0 + v1 * v1 + v2 * v2;
    float2 r2 = blockReduceSum2(s, ss);
    float mean = r2.x * (1.0f / HH);
    float var = r2.y * (1.0f / HH) - mean * mean;
    float rs = rsqrtf(var + 1e-7f);
    unsigned short* o = out + (size_t)row * HH;
    o[t] = f2b((v0 - mean) * rs);
    o[t + 256] = f2b((v1 - mean) * rs);
    o[t + 512] = f2b((v2 - mean) * rs);
}

__global__ __launch_bounds__(256) void k_embed_ln(const int* __restrict__ ids,
                                                  const float* __restrict__ emb,
                                                  float* __restrict__ out) {
    int row = blockIdx.x, t = threadIdx.x;
    const float* r = emb + (size_t)ids[row] * HH;
    float v0 = r[t], v1 = r[t + 256], v2 = r[t + 512];
    float s = v0 + v1 + v2;
    float ss = v0 * v0 + v1 * v1 + v2 * v2;
    float2 r2 = blockReduceSum2(s, ss);
    float mean = r2.x * (1.0f / HH);
    float var = r2.y * (1.0f / HH) - mean * mean;
    float rs = rsqrtf(var + 1e-7f);
    float* o = out + (size_t)row * HH;
    o[t] = (v0 - mean) * rs;
    o[t + 256] = (v1 - mean) * rs;
    o[t + 512] = (v2 - mean) * rs;
}

// rel LN -> bf16, padded to 128 rows (rows 63..127 zero)
__global__ __launch_bounds__(256) void k_rel_ln_bf(const float* __restrict__ rel_emb,
                                                   const float* __restrict__ g,
                                                   const float* __restrict__ b,
                                                   unsigned short* __restrict__ out) {
    int row = blockIdx.x, t = threadIdx.x;
    unsigned short* o = out + (size_t)row * HH;
    if (row >= 63) {
        o[t] = 0; o[t + 256] = 0; o[t + 512] = 0;
        return;
    }
    const float* r = rel_emb + (size_t)row * HH;
    float v0 = r[t], v1 = r[t + 256], v2 = r[t + 512];
    float s = v0 + v1 + v2;
    float ss = v0 * v0 + v1 * v1 + v2 * v2;
    float2 r2 = blockReduceSum2(s, ss);
    float mean = r2.x * (1.0f / HH);
    float var = r2.y * (1.0f / HH) - mean * mean;
    float rs = rsqrtf(var + 1e-7f);
    o[t] = f2b((v0 - mean) * rs * g[t] + b[t]);
    o[t + 256] = f2b((v1 - mean) * rs * g[t + 256] + b[t + 256]);
    o[t + 512] = f2b((v2 - mean) * rs * g[t + 512] + b[t + 512]);
}

// ctx_bf = bf16(LN(ctxr * gelu_exact(g))), g = qkvg[..., 2304:3072] (bf16)
__global__ __launch_bounds__(256) void k_gated_ln(const float* __restrict__ ctxr,
                                                  const unsigned short* __restrict__ qkvg,
                                                  unsigned short* __restrict__ out) {
    int row = blockIdx.x, t = threadIdx.x;
    const float* cr = ctxr + (size_t)row * HH;
    const unsigned short* gr = qkvg + (size_t)row * 3072 + 2304;
    float v[3];
    float s = 0.f, ss = 0.f;
#pragma unroll
    for (int e = 0; e < 3; ++e) {
        int i = t + e * 256;
        float x = cr[i] * gelu_erf(b2f(gr[i]));
        v[e] = x;
        s += x; ss += x * x;
    }
    float2 r2 = blockReduceSum2(s, ss);
    float mean = r2.x * (1.0f / HH);
    float var = r2.y * (1.0f / HH) - mean * mean;
    float rs = rsqrtf(var + 1e-7f);
    unsigned short* o = out + (size_t)row * HH;
#pragma unroll
    for (int e = 0; e < 3; ++e) o[t + e * 256] = f2b((v[e] - mean) * rs);
}

// h2_bf = bf16(LN(ffh[:, :I] * gelu_tanh(ffh[:, I:])))  (ffh bf16 [row][4096])
__global__ __launch_bounds__(256) void k_ffn_ln(const unsigned short* __restrict__ ffh,
                                                unsigned short* __restrict__ out) {
    int row = blockIdx.x, t = threadIdx.x;
    const unsigned short* ar = ffh + (size_t)row * 4096 + t * 8;
    const unsigned short* gr = ar + II;
    ushort4 a0 = *(const ushort4*)ar;
    ushort4 a1 = *(const ushort4*)(ar + 4);
    ushort4 g0 = *(const ushort4*)gr;
    ushort4 g1 = *(const ushort4*)(gr + 4);
    float av[8] = {b2f(a0.x), b2f(a0.y), b2f(a0.z), b2f(a0.w),
                   b2f(a1.x), b2f(a1.y), b2f(a1.z), b2f(a1.w)};
    float gv[8] = {b2f(g0.x), b2f(g0.y), b2f(g0.z), b2f(g0.w),
                   b2f(g1.x), b2f(g1.y), b2f(g1.z), b2f(g1.w)};
    float v[8];
    float s = 0.f, ss = 0.f;
#pragma unroll
    for (int e = 0; e < 8; ++e) {
        float x = av[e] * gelu_tanh(gv[e]);
        v[e] = x;
        s += x; ss += x * x;
    }
    float2 r2 = blockReduceSum2(s, ss);
    float mean = r2.x * (1.0f / II);
    float var = r2.y * (1.0f / II) - mean * mean;
    float rs = rsqrtf(var + 1e-7f);
    ushort4 o0, o1;
    o0.x = f2b((v[0] - mean) * rs); o0.y = f2b((v[1] - mean) * rs);
    o0.z = f2b((v[2] - mean) * rs); o0.w = f2b((v[3] - mean) * rs);
    o1.x = f2b((v[4] - mean) * rs); o1.y = f2b((v[5] - mean) * rs);
    o1.z = f2b((v[6] - mean) * rs); o1.w = f2b((v[7] - mean) * rs);
    unsigned short* o = out + (size_t)row * II + t * 8;
    *(ushort4*)o = o0;
    *(ushort4*)(o + 4) = o1;
}

// ---------------------------------------------------------------------------
// bf16 MFMA GEMM (m97 structure + bijective XCD swizzle + z-batch) —
// used only for the batched posproj at setup.
// ---------------------------------------------------------------------------
template <int OBF>
__global__ __launch_bounds__(256) void k_gemm_bf16(const unsigned short* __restrict__ A, int lda,
                                                   const unsigned short* __restrict__ W, int ldw,
                                                   void* __restrict__ Cv, int ldc,
                                                   int M, int N, int K,
                                                   const float* __restrict__ bias,
                                                   const float* __restrict__ bias2,
                                                   const float* __restrict__ res,
                                                   size_t wz, size_t cz, size_t bz) {
    __shared__ unsigned short As[128 * 32];
    __shared__ unsigned short Ws[128 * 32];
    int zz = blockIdx.z;
    W += (size_t)zz * wz;
    if (bias) bias += (size_t)zz * bz;
    int nwg = gridDim.x * gridDim.y;
    int orig = blockIdx.y * gridDim.x + blockIdx.x;
    int qq = nwg >> 3, rr = nwg & 7;
    int xcd = orig & 7, idx = orig >> 3;
    int wg = (xcd < rr ? xcd * (qq + 1) : rr * (qq + 1) + (xcd - rr) * qq) + idx;
    int bx = wg % gridDim.x, by = wg / gridDim.x;

    const int t = threadIdx.x;
    const int lane = t & 63, wid = t >> 6;
    const int row0 = by * 128, col0 = bx * 128;
    const int wr = (wid >> 1) * 64, wc = (wid & 1) * 64;
    const int rA = lane & 15, kA = (lane >> 4) * 8;

    f32x4 acc[4][4] = {};

    for (int k0 = 0; k0 < K; k0 += 32) {
#pragma unroll
        for (int j = 0; j < 2; ++j) {
            int c = t + j * 256;
            int r = c >> 2, ko = (c & 3) * 8;
            const unsigned short* srcA = A + (size_t)(row0 + r) * lda + k0 + ko;
            const unsigned short* srcB = W + (size_t)(col0 + r) * ldw + k0 + ko;
            unsigned short* dstA = As + (size_t)(j * 256 + wid * 64) * 8;
            unsigned short* dstB = Ws + (size_t)(j * 256 + wid * 64) * 8;
            __builtin_amdgcn_global_load_lds(
                (const __attribute__((address_space(1))) void*)srcA,
                (__attribute__((address_space(3))) void*)dstA, 16, 0, 0);
            __builtin_amdgcn_global_load_lds(
                (const __attribute__((address_space(1))) void*)srcB,
                (__attribute__((address_space(3))) void*)dstB, 16, 0, 0);
        }
        __syncthreads();
        bf16x8 af[4], bfr[4];
#pragma unroll
        for (int m = 0; m < 4; ++m)
            af[m] = *(const bf16x8*)&As[(wr + m * 16 + rA) * 32 + kA];
#pragma unroll
        for (int n = 0; n < 4; ++n)
            bfr[n] = *(const bf16x8*)&Ws[(wc + n * 16 + rA) * 32 + kA];
#pragma unroll
        for (int m = 0; m < 4; ++m)
#pragma unroll
            for (int n = 0; n < 4; ++n)
                acc[m][n] = __builtin_amdgcn_mfma_f32_16x16x32_bf16(af[m], bfr[n], acc[m][n], 0, 0, 0);
        __syncthreads();
    }

    float* Cf = (float*)Cv + (size_t)zz * cz;
    unsigned short* Cb = (unsigned short*)Cv + (size_t)zz * cz;
    const int cl = lane & 15, rg = (lane >> 4) * 4;
#pragma unroll
    for (int n = 0; n < 4; ++n) {
        int gc = col0 + wc + n * 16 + cl;
        float bv = 0.0f;
        if (bias) bv = (bias2 && gc >= 1536) ? bias2[gc - 1536] : bias[gc];
#pragma unroll
        for (int m = 0; m < 4; ++m) {
#pragma unroll
            for (int i = 0; i < 4; ++i) {
                int gr = row0 + wr + m * 16 + rg + i;
                float v = acc[m][n][i] + bv;
                if (OBF) {
                    Cb[(size_t)gr * ldc + gc] = f2b(v);
                } else {
                    if (res) v += res[(size_t)gr * ldc + gc];
                    Cf[(size_t)gr * ldc + gc] = v;
                }
            }
        }
    }
}

// ---------------------------------------------------------------------------
// Skinny bf16 MFMA GEMM for N=768 (Wout, W2), 2-slot pipelined
// ---------------------------------------------------------------------------
#define SKSLOT 16384  /* 16 KB per slot: A 8KB @0, B 8KB @8192 */

__device__ __forceinline__ void sk_stage(const unsigned short* __restrict__ Ab, int lda,
                                         const unsigned short* __restrict__ Wb, int ldw,
                                         unsigned char* slot, int t, int wid) {
    int rit = t >> 3;
    int kb = (t & 7) << 4;
#pragma unroll
    for (int c = 0; c < 2; ++c) {
        int row = c * 32 + rit;
        int gkb = kb ^ ((row & 7) << 4);
        const unsigned short* src = Ab + (size_t)row * lda + (gkb >> 1);
        unsigned char* dst = slot + c * 4096 + wid * 1024;
        __builtin_amdgcn_global_load_lds(
            (const __attribute__((address_space(1))) void*)src,
            (__attribute__((address_space(3))) void*)dst, 16, 0, 0);
    }
#pragma unroll
    for (int c = 0; c < 2; ++c) {
        int row = c * 32 + rit;
        int gkb = kb ^ ((row & 7) << 4);
        const unsigned short* src = Wb + (size_t)row * ldw + (gkb >> 1);
        unsigned char* dst = slot + 8192 + c * 4096 + wid * 1024;
        __builtin_amdgcn_global_load_lds(
            (const __attribute__((address_space(1))) void*)src,
            (__attribute__((address_space(3))) void*)dst, 16, 0, 0);
    }
}

__device__ __forceinline__ void sk_compute(const unsigned char* slot, int wr, int wc,
                                           int rA, int g16, f32x4 acc[2][2]) {
    const unsigned char* Ab = slot;
    const unsigned char* Bb = slot + 8192;
    bf16x8 a[2][2], b[2][2];
#pragma unroll
    for (int m = 0; m < 2; ++m) {
        int row = wr + m * 16 + rA;
        int sw = (row & 7) << 4;
#pragma unroll
        for (int s = 0; s < 2; ++s)
            a[m][s] = *(const bf16x8*)(Ab + row * 128 + ((s * 64 + g16 * 16) ^ sw));
    }
#pragma unroll
    for (int n = 0; n < 2; ++n) {
        int row = wc + n * 16 + rA;
        int sw = (row & 7) << 4;
#pragma unroll
        for (int s = 0; s < 2; ++s)
            b[n][s] = *(const bf16x8*)(Bb + row * 128 + ((s * 64 + g16 * 16) ^ sw));
    }
    __builtin_amdgcn_s_setprio(1);
#pragma unroll
    for (int m = 0; m < 2; ++m)
#pragma unroll
        for (int n = 0; n < 2; ++n) {
            acc[m][n] = __builtin_amdgcn_mfma_f32_16x16x32_bf16(a[m][0], b[n][0], acc[m][n], 0, 0, 0);
            acc[m][n] = __builtin_amdgcn_mfma_f32_16x16x32_bf16(a[m][1], b[n][1], acc[m][n], 0, 0, 0);
        }
    __builtin_amdgcn_s_setprio(0);
}

__global__ __launch_bounds__(256) void k_gemm_skinny(const unsigned short* __restrict__ A, int lda,
                                                     const unsigned short* __restrict__ W, int ldw,
                                                     float* __restrict__ C, int ldc,
                                                     int M, int N, int K,
                                                     const float* __restrict__ bias,
                                                     const float* __restrict__ res) {
    __shared__ unsigned char smem[2 * SKSLOT];
    int nwg = gridDim.x * gridDim.y;
    int orig = blockIdx.y * gridDim.x + blockIdx.x;
    int qq = nwg >> 3, rr = nwg & 7;
    int xcd = orig & 7, idx = orig >> 3;
    int wg = (xcd < rr ? xcd * (qq + 1) : rr * (qq + 1) + (xcd - rr) * qq) + idx;
    int bx = wg % gridDim.x, by = wg / gridDim.x;

    const int t = threadIdx.x;
    const int lane = t & 63, wid = t >> 6;
    const int row0 = by * 64, col0 = bx * 64;
    const int wr = (wid >> 1) * 32, wc = (wid & 1) * 32;
    const int rA = lane & 15, g16 = lane >> 4;
    const unsigned short* Abase = A + (size_t)row0 * lda;
    const unsigned short* Wbase = W + (size_t)col0 * ldw;

    const int nt = K >> 6;
    f32x4 acc[2][2] = {};

    sk_stage(Abase, lda, Wbase, ldw, smem, t, wid);

    for (int tt = 0; tt < nt; ++tt) {
        asm volatile("s_barrier" ::: "memory");
        if (tt + 1 < nt) {
            sk_stage(Abase + (size_t)(tt + 1) * 64, lda, Wbase + (size_t)(tt + 1) * 64,
                     ldw, smem + (size_t)((tt + 1) & 1) * SKSLOT, t, wid);
            asm volatile("s_waitcnt vmcnt(4)" ::: "memory");
        } else {
            asm volatile("s_waitcnt vmcnt(0)" ::: "memory");
        }
        asm volatile("s_barrier" ::: "memory");
        sk_compute(smem + (size_t)(tt & 1) * SKSLOT, wr, wc, rA, g16, acc);
    }

    const int cl = lane & 15, rg = (lane >> 4) * 4;
#pragma unroll
    for (int n = 0; n < 2; ++n) {
        int gc = col0 + wc + n * 16 + cl;
        float bv = bias ? bias[gc] : 0.0f;
#pragma unroll
        for (int m = 0; m < 2; ++m) {
#pragma unroll
            for (int i = 0; i < 4; ++i) {
                int gr = row0 + wr + m * 16 + rg + i;
                float v = acc[m][n][i] + bv;
                if (res) v += res[(size_t)gr * ldc + gc];
                C[(size_t)gr * ldc + gc] = v;
            }
        }
    }
}

// ---------------------------------------------------------------------------
// Pipelined bf16 MFMA GEMM for the large GEMMs (qkvg, W1)
// ---------------------------------------------------------------------------
#define GSLOT 49152  /* 48 KB: A 16KB @0, B 32KB @16384 */

__device__ __forceinline__ void g_stage(const unsigned short* __restrict__ Abase, int lda,
                                        const unsigned short* __restrict__ Wbase, int ldw,
                                        unsigned char* slot, int t, int wid) {
    int rit = t >> 3;
    int kb = (t & 7) << 4;
#pragma unroll
    for (int c = 0; c < 2; ++c) {
        int row = c * 64 + rit;
        int gkb = kb ^ ((row & 7) << 4);
        const unsigned short* src = Abase + (size_t)row * lda + (gkb >> 1);
        unsigned char* dst = slot + c * 8192 + wid * 1024;
        __builtin_amdgcn_global_load_lds(
            (const __attribute__((address_space(1))) void*)src,
            (__attribute__((address_space(3))) void*)dst, 16, 0, 0);
    }
#pragma unroll
    for (int c = 0; c < 4; ++c) {
        int row = c * 64 + rit;
        int gkb = kb ^ ((row & 7) << 4);
        const unsigned short* src = Wbase + (size_t)row * ldw + (gkb >> 1);
        unsigned char* dst = slot + 16384 + c * 8192 + wid * 1024;
        __builtin_amdgcn_global_load_lds(
            (const __attribute__((address_space(1))) void*)src,
            (__attribute__((address_space(3))) void*)dst, 16, 0, 0);
    }
}

__device__ __forceinline__ void g_compute(const unsigned char* slot, int wm, int wn,
                                          int rA, int g16, f32x4 acc[4][4]) {
    const unsigned char* Ab = slot;
    const unsigned char* Bb = slot + 16384;
    bf16x8 a[4][2], b[4][2];
#pragma unroll
    for (int m = 0; m < 4; ++m) {
        int row = wm * 64 + m * 16 + rA;
        int sw = (row & 7) << 4;
#pragma unroll
        for (int s = 0; s < 2; ++s)
            a[m][s] = *(const bf16x8*)(Ab + row * 128 + ((s * 64 + g16 * 16) ^ sw));
    }
#pragma unroll
    for (int n = 0; n < 4; ++n) {
        int row = wn * 64 + n * 16 + rA;
        int sw = (row & 7) << 4;
#pragma unroll
        for (int s = 0; s < 2; ++s)
            b[n][s] = *(const bf16x8*)(Bb + row * 128 + ((s * 64 + g16 * 16) ^ sw));
    }
    __builtin_amdgcn_s_setprio(1);
#pragma unroll
    for (int m = 0; m < 4; ++m)
#pragma unroll
        for (int n = 0; n < 4; ++n) {
            acc[m][n] = __builtin_amdgcn_mfma_f32_16x16x32_bf16(a[m][0], b[n][0], acc[m][n], 0, 0, 0);
            acc[m][n] = __builtin_amdgcn_mfma_f32_16x16x32_bf16(a[m][1], b[n][1], acc[m][n], 0, 0, 0);
        }
    __builtin_amdgcn_s_setprio(0);
}

template <int OBF>
__global__ __launch_bounds__(512, 1) void k_gemm_big(const unsigned short* __restrict__ A, int lda,
                                                     const unsigned short* __restrict__ W,
                                                     const unsigned short* __restrict__ Wb2, int ldw,
                                                     void* __restrict__ Cv, int ldc,
                                                     int M, int N, int K,
                                                     const float* __restrict__ bias,
                                                     const float* __restrict__ bias2,
                                                     const float* __restrict__ res) {
    extern __shared__ unsigned char smem[];
    int nwg = gridDim.x * gridDim.y;
    int orig = blockIdx.y * gridDim.x + blockIdx.x;
    int qq = nwg >> 3, rr = nwg & 7;
    int xcd = orig & 7, idx = orig >> 3;
    int wg = (xcd < rr ? xcd * (qq + 1) : rr * (qq + 1) + (xcd - rr) * qq) + idx;
    int bx = wg % gridDim.x, by = wg / gridDim.x;

    const int t = threadIdx.x;
    const int lane = t & 63, wid = t >> 6;
    const int wm = wid >> 2, wn = wid & 3;
    const int rA = lane & 15, g16 = lane >> 4;
    const int row0 = by * 128, col0 = bx * 256;
    const unsigned short* Abase = A + (size_t)row0 * lda;
    const unsigned short* Wbase = (Wb2 && col0 >= 1536)
                                      ? Wb2 + (size_t)(col0 - 1536) * ldw
                                      : W + (size_t)col0 * ldw;

    const int nt = K >> 6;
    f32x4 acc[4][4] = {};

    g_stage(Abase, lda, Wbase, ldw, smem, t, wid);
    g_stage(Abase + 64, lda, Wbase + 64, ldw, smem + GSLOT, t, wid);

#define GBAR() asm volatile("s_barrier" ::: "memory")
#define GITER(T, STG, VMSTR)                                                        \
    do {                                                                            \
        GBAR();                                                                     \
        if (STG)                                                                    \
            g_stage(Abase + (size_t)(T + 2) * 64, lda, Wbase + (size_t)(T + 2) * 64,\
                    ldw, smem + (size_t)((T + 2) % 3) * GSLOT, t, wid);             \
        asm volatile(VMSTR ::: "memory");                                           \
        GBAR();                                                                     \
        g_compute(smem + (size_t)((T) % 3) * GSLOT, wm, wn, rA, g16, acc);          \
    } while (0)

    int tt = 0;
    for (; tt < nt - 2; ++tt) GITER(tt, true, "s_waitcnt vmcnt(12)");
    GITER(tt, false, "s_waitcnt vmcnt(6)");
    ++tt;
    GITER(tt, false, "s_waitcnt vmcnt(0)");
#undef GITER
#undef GBAR

    float* Cf = (float*)Cv;
    unsigned short* Cb = (unsigned short*)Cv;
    const int cl = lane & 15, rg = (lane >> 4) * 4;
#pragma unroll
    for (int n = 0; n < 4; ++n) {
        int gc = col0 + wn * 64 + n * 16 + cl;
        float bv = 0.0f;
        if (bias) bv = (bias2 && gc >= 1536) ? bias2[gc - 1536] : bias[gc];
#pragma unroll
        for (int m = 0; m < 4; ++m) {
#pragma unroll
            for (int i = 0; i < 4; ++i) {
                int gr = row0 + wm * 64 + m * 16 + rg + i;
                float v = acc[m][n][i] + bv;
                if (OBF) {
                    Cb[(size_t)gr * ldc + gc] = f2b(v);
                } else {
                    if (res) v += res[(size_t)gr * ldc + gc];
                    Cf[(size_t)gr * ldc + gc] = v;
                }
            }
        }
    }
}

// ---------------------------------------------------------------------------
// merged: repack (blockIdx.x<8) + cp/pc MFMA (blockIdx.x>=8); grid (16, 96)
// ---------------------------------------------------------------------------
__global__ __launch_bounds__(256) void k_repack_cppc(const unsigned short* __restrict__ qkvg,
                                                     const unsigned short* __restrict__ pp,
                                                     unsigned short* __restrict__ qT,
                                                     unsigned short* __restrict__ kT,
                                                     unsigned short* __restrict__ vT,
                                                     float* __restrict__ cp,
                                                     float* __restrict__ pc) {
    __shared__ unsigned char shmem[12288];
    int t = threadIdx.x;
    if (blockIdx.x < 8) {
        unsigned short (*tile)[72] = (unsigned short(*)[72])shmem;
        int bh = blockIdx.y;
        int b = bh / NHH, h = bh % NHH;
        int s0 = blockIdx.x * 64;
#pragma unroll
        for (int j = 0; j < 2; ++j) {
            int idx = t + j * 256;
            int r = idx >> 3, dc = idx & 7;
            const unsigned short* src = qkvg + ((size_t)(s0 + r) * BB + b) * 3072 + h * DD + dc * 8;
            ushort4 a = *(const ushort4*)src;
            ushort4 c = *(const ushort4*)(src + 4);
            unsigned short* dq = qT + ((size_t)bh * SS + s0 + r) * DD + dc * 8;
            *(ushort4*)dq = a; *(ushort4*)(dq + 4) = c;
            const unsigned short* srck = src + HH;
            ushort4 a2 = *(const ushort4*)srck;
            ushort4 c2 = *(const ushort4*)(srck + 4);
            unsigned short* dk = kT + ((size_t)bh * SS + s0 + r) * DD + dc * 8;
            *(ushort4*)dk = a2; *(ushort4*)(dk + 4) = c2;
        }
#pragma unroll
        for (int j = 0; j < 4; ++j) {
            int idx = t + j * 256;
            int r = idx >> 4, c4 = idx & 15;
            ushort4 u = *(const ushort4*)(qkvg + ((size_t)(s0 + r) * BB + b) * 3072 + 1536 + h * DD + c4 * 4);
            *(ushort4*)&tile[r][c4 * 4] = u;
        }
        __syncthreads();
#pragma unroll
        for (int j = 0; j < 2; ++j) {
            int idx = t + j * 256;
            int d = idx >> 3, s8 = idx & 7;
            ushort4 a, c;
            a.x = tile[s8 * 8 + 0][d]; a.y = tile[s8 * 8 + 1][d];
            a.z = tile[s8 * 8 + 2][d]; a.w = tile[s8 * 8 + 3][d];
            c.x = tile[s8 * 8 + 4][d]; c.y = tile[s8 * 8 + 5][d];
            c.z = tile[s8 * 8 + 6][d]; c.w = tile[s8 * 8 + 7][d];
            unsigned short* dst = vT + ((size_t)bh * DD + d) * SS + s0 + s8 * 8;
            *(ushort4*)dst = a; *(ushort4*)(dst + 4) = c;
        }
    } else {
        int cid = (blockIdx.x - 8) * 96 + blockIdx.y;
        int z = cid >= 384;
        int rem = cid - (z ? 384 : 0);
        int h = rem >> 5;
        int mt = rem & 31;
        int aoff = z ? HH : 0;
        int toff = z ? 0 : HH;
        float* out = z ? pc : cp;
        unsigned short* As = (unsigned short*)shmem;
        unsigned short* Bs = (unsigned short*)(shmem + 8192);
        const int lane = t & 63, wid = t >> 6;
        const int rA = lane & 15, kA = (lane >> 4) * 8;

        f32x4 acc[2][4] = {};

        for (int k0 = 0; k0 < 64; k0 += 32) {
#pragma unroll
            for (int j = 0; j < 2; ++j) {
                int c = t + j * 256;
                int r = c >> 2, ko = (c & 3) * 8;
                const unsigned short* srcA = qkvg + (size_t)(mt * 128 + r) * 3072 + aoff + h * DD + k0 + ko;
                unsigned short* dstA = As + (size_t)(j * 256 + wid * 64) * 8;
                __builtin_amdgcn_global_load_lds(
                    (const __attribute__((address_space(1))) void*)srcA,
                    (__attribute__((address_space(3))) void*)dstA, 16, 0, 0);
            }
            {
                int r = t >> 2, ko = (t & 3) * 8;
                const unsigned short* srcB = pp + (size_t)r * 1536 + toff + h * DD + k0 + ko;
                unsigned short* dstB = Bs + (size_t)(wid * 64) * 8;
                __builtin_amdgcn_global_load_lds(
                    (const __attribute__((address_space(1))) void*)srcB,
                    (__attribute__((address_space(3))) void*)dstB, 16, 0, 0);
            }
            __syncthreads();
            bf16x8 af[2], bfr[4];
#pragma unroll
            for (int m = 0; m < 2; ++m)
                af[m] = *(const bf16x8*)&As[(wid * 32 + m * 16 + rA) * 32 + kA];
#pragma unroll
            for (int n = 0; n < 4; ++n)
                bfr[n] = *(const bf16x8*)&Bs[(n * 16 + rA) * 32 + kA];
#pragma unroll
            for (int m = 0; m < 2; ++m)
#pragma unroll
                for (int n = 0; n < 4; ++n)
                    acc[m][n] = __builtin_amdgcn_mfma_f32_16x16x32_bf16(af[m], bfr[n], acc[m][n], 0, 0, 0);
            __syncthreads();
        }

        const int cl = lane & 15, rg = (lane >> 4) * 4;
#pragma unroll
        for (int m = 0; m < 2; ++m)
#pragma unroll
            for (int n = 0; n < 4; ++n) {
                int gc = n * 16 + cl;
                if (gc < 63) {
#pragma unroll
                    for (int i = 0; i < 4; ++i) {
                        int gr = mt * 128 + wid * 32 + m * 16 + rg + i;
                        int sIdx = gr >> 3, bIdx = gr & 7;
                        out[(((size_t)(bIdx * NHH + h)) * SS + sIdx) * 63 + gc] = acc[m][n][i];
                    }
                }
            }
    }
}

// ---------------------------------------------------------------------------
// fused disentangled flash attention v2 (round-10 proven config: f32 cps+pcs)
// ---------------------------------------------------------------------------
__global__ __launch_bounds__(256) void k_attn_fused(
    const unsigned short* __restrict__ qT, const unsigned short* __restrict__ kT,
    const unsigned short* __restrict__ vT, const float* __restrict__ cp,
    const float* __restrict__ pc, const int* __restrict__ bucket,
    const int* __restrict__ mask, float* __restrict__ ctxr) {
    __shared__ float cps[64 * 63];
    __shared__ float pcs[64 * 63];
    __shared__ unsigned short pb_all[4][16 * 72];
    __shared__ int btab[1023];
    int t = threadIdx.x;
    int lane = t & 63, wid = t >> 6;
    int bh = blockIdx.y;
    int b = bh / NHH, h = bh % NHH;
    int qb0 = blockIdx.x * 64;
    int q0 = qb0 + wid * 16;
    int rA = lane & 15, g = lane >> 4, kA = g * 8;
    unsigned short* pb = pb_all[wid];
    const unsigned short* qTb = qT + (size_t)bh * SS * DD;
    const unsigned short* kTb = kT + (size_t)bh * SS * DD;
    const unsigned short* vTb = vT + (size_t)bh * DD * SS;
    const float* cpb = cp + (size_t)bh * SS * 63 + (size_t)qb0 * 63;
    const float* pcb = pc + (size_t)bh * SS * 63;
    const int* mkb = mask + b * SS;

    for (int i = t; i < 1023; i += 256) btab[i] = bucket[i];
    for (int i = t; i < 1008; i += 256) ((float4*)cps)[i] = ((const float4*)cpb)[i];

    bf16x8 aq[2];
#pragma unroll
    for (int dc = 0; dc < 2; ++dc)
        aq[dc] = *(const bf16x8*)&qTb[(size_t)(q0 + rA) * DD + dc * 32 + kA];

    f32x4 o[4] = {};
    float mrow[4], lrow[4];
#pragma unroll
    for (int i = 0; i < 4; ++i) { mrow[i] = -INFINITY; lrow[i] = 0.f; }

    for (int kt = 0; kt < 8; ++kt) {
        int k0 = kt * 64;
        __syncthreads();
        {
            const float4* src = (const float4*)(pcb + (size_t)k0 * 63);
            for (int i = t; i < 1008; i += 256) ((float4*)pcs)[i] = src[i];
        }
        f32x4 sa[4] = {};
#pragma unroll
        for (int n = 0; n < 4; ++n) {
            bf16x8 bk0 = *(const bf16x8*)&kTb[(size_t)(k0 + n * 16 + rA) * DD + kA];
            bf16x8 bk1 = *(const bf16x8*)&kTb[(size_t)(k0 + n * 16 + rA) * DD + 32 + kA];
            sa[n] = __builtin_amdgcn_mfma_f32_16x16x32_bf16(aq[0], bk0, sa[n], 0, 0, 0);
            sa[n] = __builtin_amdgcn_mfma_f32_16x16x32_bf16(aq[1], bk1, sa[n], 0, 0, 0);
        }
        int mk[4];
#pragma unroll
        for (int n = 0; n < 4; ++n) mk[n] = mkb[k0 + n * 16 + rA];
        __syncthreads();

        float pv[4][4];
#pragma unroll
        for (int i = 0; i < 4; ++i) {
            int qr = wid * 16 + g * 4 + i;
            int q = qb0 + qr;
            float sv[4];
            float tmax = -INFINITY;
#pragma unroll
            for (int n = 0; n < 4; ++n) {
                int kr = n * 16 + rA;
                int id = btab[q - (k0 + kr) + 511];
                float v = (sa[n][i] + cps[qr * 63 + id] + pcs[kr * 63 + id]) * SCALE_F;
                v = mk[n] ? -1e9f : v;
                sv[n] = v;
                tmax = fmaxf(tmax, v);
            }
            tmax = fmaxf(tmax, __shfl_xor(tmax, 1, 16));
            tmax = fmaxf(tmax, __shfl_xor(tmax, 2, 16));
            tmax = fmaxf(tmax, __shfl_xor(tmax, 4, 16));
            tmax = fmaxf(tmax, __shfl_xor(tmax, 8, 16));
            float mold = mrow[i];
            float mnew = fmaxf(mold, tmax);
            float ls = 0.f;
#pragma unroll
            for (int n = 0; n < 4; ++n) {
                float p = __expf(sv[n] - mnew);
                pv[n][i] = p;
                ls += p;
            }
            ls += __shfl_xor(ls, 1, 16);
            ls += __shfl_xor(ls, 2, 16);
            ls += __shfl_xor(ls, 4, 16);
            ls += __shfl_xor(ls, 8, 16);
            if (mnew > mold) {
                float alpha = __expf(mold - mnew);
                lrow[i] = lrow[i] * alpha + ls;
                mrow[i] = mnew;
#pragma unroll
                for (int n = 0; n < 4; ++n) o[n][i] *= alpha;
            } else {
                lrow[i] += ls;
            }
        }
#pragma unroll
        for (int n = 0; n < 4; ++n)
#pragma unroll
            for (int i = 0; i < 4; ++i)
                pb[(g * 4 + i) * 72 + n * 16 + rA] = f2b(pv[n][i]);
        bf16x8 ap[2];
#pragma unroll
        for (int kc = 0; kc < 2; ++kc)
            ap[kc] = *(const bf16x8*)&pb[rA * 72 + kc * 32 + kA];
#pragma unroll
        for (int n = 0; n < 4; ++n) {
            bf16x8 bv0 = *(const bf16x8*)&vTb[(size_t)(n * 16 + rA) * SS + k0 + kA];
            bf16x8 bv1 = *(const bf16x8*)&vTb[(size_t)(n * 16 + rA) * SS + k0 + 32 + kA];
            o[n] = __builtin_amdgcn_mfma_f32_16x16x32_bf16(ap[0], bv0, o[n], 0, 0, 0);
            o[n] = __builtin_amdgcn_mfma_f32_16x16x32_bf16(ap[1], bv1, o[n], 0, 0, 0);
        }
    }
#pragma unroll
    for (int i = 0; i < 4; ++i) {
        int q = q0 + g * 4 + i;
        float inv = 1.0f / lrow[i];
#pragma unroll
        for (int n = 0; n < 4; ++n)
            ctxr[((size_t)q * BB + b) * HH + h * DD + n * 16 + rA] = o[n][i] * inv;
    }
}

// ---------------------------------------------------------------------------
// host launcher
// ---------------------------------------------------------------------------
static inline void gemm_big(const unsigned short* A, int lda,
                            const unsigned short* W, const unsigned short* Wb2, int ldw,
                            void* C, int ldc, int M, int N, int K,
                            const float* bias, const float* bias2, const float* res,
                            int obf, hipStream_t st) {
    dim3 g(N / 256, M / 128);
    if (obf)
        k_gemm_big<1><<<g, 512, 3 * GSLOT, st>>>(A, lda, W, Wb2, ldw, C, ldc, M, N, K, bias, bias2, res);
    else
        k_gemm_big<0><<<g, 512, 3 * GSLOT, st>>>(A, lda, W, Wb2, ldw, C, ldc, M, N, K, bias, bias2, res);
}

extern "C" void kernel_launch(void* const* d_in, const int* in_sizes, int n_in,
                              void* d_out, int out_size, void* d_ws, size_t ws_size,
                              hipStream_t stream) {
    static int attr_done = 0;
    if (!attr_done) {
        hipFuncSetAttribute((const void*)&k_gemm_big<1>,
                            hipFuncAttributeMaxDynamicSharedMemorySize, 3 * GSLOT);
        hipFuncSetAttribute((const void*)&k_gemm_big<0>,
                            hipFuncAttributeMaxDynamicSharedMemorySize, 3 * GSLOT);
        attr_done = 1;
    }

    const int* ids = (const int*)d_in[0];
    const unsigned char* maskraw = (const unsigned char*)d_in[1];
    const float* word_emb = (const float*)d_in[2];
    const float* rel_emb = (const float*)d_in[3];
    const float* rel_g = (const float*)d_in[4];
    const float* rel_b = (const float*)d_in[5];
    const float* Wqk = (const float*)d_in[6];
    const float* bqk = (const float*)d_in[7];
    const float* Wvg = (const float*)d_in[8];
    const float* bvg = (const float*)d_in[9];
    const float* Wout = (const float*)d_in[10];
    const float* bout = (const float*)d_in[11];
    const float* W1 = (const float*)d_in[12];
    const float* W2 = (const float*)d_in[13];

    const size_t N_X = (size_t)SS * BB * HH;
    const size_t N_CP = (size_t)SS * BB * NHH * 63;
    const size_t N_H2 = (size_t)SS * BB * II;
    const size_t N_WQK = (size_t)2 * HH * HH;
    const size_t N_WOUT = (size_t)HH * HH;
    const size_t N_W1 = (size_t)2 * II * HH;
    const size_t N_W2 = (size_t)HH * II;
    const size_t N_HD = (size_t)BB * NHH * SS * DD;
    const size_t N_QKVG = (size_t)SS * BB * 3072;
    const size_t N_FFH = (size_t)SS * BB * 4096;
    const size_t N_PP = (size_t)128 * 1536;

    float* ws = (float*)d_ws;
    float* x = ws;
    float* ctxr = x + N_X;
    float* cp = ctxr + N_X;
    float* pc = cp + N_CP;
    unsigned short* us = (unsigned short*)(pc + N_CP);
    unsigned short* qkvg = us;
    unsigned short* hs_bf = qkvg + N_QKVG;
    unsigned short* ctx_bf = hs_bf + N_X;
    unsigned short* h2_bf = ctx_bf + N_X;
    unsigned short* ffh = h2_bf + N_H2;
    unsigned short* wqk_all = ffh + N_FFH;
    unsigned short* wvg_bf = wqk_all + 12 * N_WQK;
    unsigned short* wout_bf = wvg_bf + N_WQK;
    unsigned short* w1_bf = wout_bf + N_WOUT;
    unsigned short* w2_bf = w1_bf + N_W1;
    unsigned short* ppall = w2_bf + N_W2;
    unsigned short* rel_bf = ppall + 12 * N_PP;
    unsigned short* qT = rel_bf + 128 * HH;
    unsigned short* kT = qT + N_HD;
    unsigned short* vT = kT + N_HD;
    int* bucket = (int*)(vT + N_HD);
    int* maski = bucket + 1024;

    size_t need_bytes = ((size_t)(maski + BB * SS) - (size_t)d_ws);
    if (ws_size < need_bytes) return;  // ~205 MB required

    // ---- setup ----
    k_decode_mask<<<1, 256, 0, stream>>>(maskraw, maski, BB * SS);
    k_bucket<<<4, 256, 0, stream>>>(bucket);
    k_embed_ln<<<SS * BB, 256, 0, stream>>>(ids, word_emb, x);
    k_rel_ln_bf<<<128, 256, 0, stream>>>(rel_emb, rel_g, rel_b, rel_bf);
    k_f2b<<<(int)((12 * N_WQK / 8 + 255) / 256), 256, 0, stream>>>(Wqk, wqk_all,
                                                                   (int)(12 * N_WQK / 8));
    {
        dim3 gpp(1536 / 128, 1, 12);
        k_gemm_bf16<1><<<gpp, 256, 0, stream>>>(rel_bf, HH, wqk_all, HH, ppall, 1536,
                                                128, 1536, HH, bqk, nullptr, nullptr,
                                                N_WQK, N_PP, 2 * HH);
    }

    for (int l = 0; l < LL; ++l) {
        const unsigned short* wqk_l = wqk_all + (size_t)l * N_WQK;
        const float* bqk_l = bqk + (size_t)l * 2 * HH;
        const float* Wvg_l = Wvg + (size_t)l * N_WQK;
        const float* bvg_l = bvg + (size_t)l * 2 * HH;
        const float* Wout_l = Wout + (size_t)l * N_WOUT;
        const float* bout_l = bout + (size_t)l * HH;
        const float* W1_l = W1 + (size_t)l * N_W1;
        const float* W2_l = W2 + (size_t)l * N_W2;

        // ---- attention ----
        k_f2b_ln<<<3169 + SS * BB, 256, 0, stream>>>(Wvg_l, Wout_l, W1_l, W2_l, wvg_bf,
                                                     x, hs_bf);
        gemm_big(hs_bf, HH, wqk_l, wvg_bf, HH, qkvg, 3072, SS * BB, 3072, HH,
                 bqk_l, bvg_l, nullptr, 1, stream);
        k_repack_cppc<<<dim3(16, 96), 256, 0, stream>>>(qkvg, ppall + (size_t)l * N_PP,
                                                        qT, kT, vT, cp, pc);
        k_attn_fused<<<dim3(SS / 64, BB * NHH), 256, 0, stream>>>(qT, kT, vT, cp, pc,
                                                                  bucket, maski, ctxr);
        k_gated_ln<<<SS * BB, 256, 0, stream>>>(ctxr, qkvg, ctx_bf);
        k_gemm_skinny<<<dim3(HH / 64, SS * BB / 64), 256, 0, stream>>>(
            ctx_bf, HH, wout_bf, HH, x, HH, SS * BB, HH, HH, bout_l, x);

        // ---- GeGLU FFN ----
        k_ln_bf<<<SS * BB, 256, 0, stream>>>(x, hs_bf);
        gemm_big(hs_bf, HH, w1_bf, nullptr, HH, ffh, 4096, SS * BB, 4096, HH,
                 nullptr, nullptr, nullptr, 1, stream);
        k_ffn_ln<<<SS * BB, 256, 0, stream>>>(ffh, h2_bf);
        // last layer writes the residual-added output straight into d_out
        float* outC = (l == LL - 1) ? (float*)d_out : x;
        k_gemm_skinny<<<dim3(HH / 64, SS * BB / 64), 256, 0, stream>>>(
            h2_bf, II, w2_bf, II, outC, HH, SS * BB, HH, II, nullptr, x);
    }
}

// Round 14
// 2660.495 us; speedup vs baseline: 1.0630x; 1.0170x over previous
//
#include <hip/hip_runtime.h>
#include <math.h>

#define SS 512
#define BB 8
#define NHH 12
#define DD 64
#define HH 768
#define II 2048
#define LL 12
#define SCALE_F 0.07216878364870323f  /* 1/sqrt(3*64) */

typedef __attribute__((ext_vector_type(8))) short bf16x8;
typedef __attribute__((ext_vector_type(4))) float f32x4;

// f32 -> bf16 (RNE, finite values)
__device__ __forceinline__ unsigned short f2b(float f) {
    union { float f; unsigned int u; } x; x.f = f;
    unsigned int r = x.u + 0x7fffu + ((x.u >> 16) & 1u);
    return (unsigned short)(r >> 16);
}
__device__ __forceinline__ float b2f(unsigned short u) {
    union { unsigned int u; float f; } x; x.u = ((unsigned int)u) << 16;
    return x.f;
}

// ---------------------------------------------------------------------------
// block reduction helpers (blockDim.x == 256)
// ---------------------------------------------------------------------------
__device__ __forceinline__ float2 blockReduceSum2(float a, float b) {
    __shared__ float2 sm[4];
    __shared__ float2 bc;
#pragma unroll
    for (int o = 32; o > 0; o >>= 1) {
        a += __shfl_down(a, o);
        b += __shfl_down(b, o);
    }
    int t = threadIdx.x;
    if ((t & 63) == 0) sm[t >> 6] = make_float2(a, b);
    __syncthreads();
    if (t == 0) {
        float xa = sm[0].x + sm[1].x + sm[2].x + sm[3].x;
        float xb = sm[0].y + sm[1].y + sm[2].y + sm[3].y;
        bc = make_float2(xa, xb);
    }
    __syncthreads();
    return bc;
}

__device__ __forceinline__ float gelu_erf(float v) {
    return 0.5f * v * (1.0f + erff(v * 0.70710678118654752f));
}
__device__ __forceinline__ float gelu_tanh(float v) {
    const float c = 0.7978845608028654f;
    return 0.5f * v * (1.0f + tanhf(c * (v + 0.044715f * v * v * v)));
}

// ---------------------------------------------------------------------------
// mask decode: handle bool-as-u8 or bool-as-int32 layouts
// ---------------------------------------------------------------------------
__global__ __launch_bounds__(256) void k_decode_mask(const unsigned char* __restrict__ raw,
                                                     int* __restrict__ mask, int n) {
    __shared__ int s_any;
    if (threadIdx.x == 0) s_any = 0;
    __syncthreads();
    int local = 0;
    for (int i = threadIdx.x; i < n; i += blockDim.x)
        if ((i & 3) && raw[i]) local = 1;
    if (local) atomicOr(&s_any, 1);
    __syncthreads();
    bool isU8 = (s_any != 0);
    const int* as_int = (const int*)raw;
    for (int i = threadIdx.x; i < n; i += blockDim.x)
        mask[i] = isU8 ? (raw[i] != 0) : (as_int[i] != 0);
}

// ---------------------------------------------------------------------------
// DeBERTa log-bucket table: rel in [-511,511] -> idx in [0,62]
// ---------------------------------------------------------------------------
__global__ __launch_bounds__(256) void k_bucket(int* __restrict__ tab) {
    int i = blockIdx.x * 256 + threadIdx.x;
    if (i >= 1023) return;
    int rel = i - 511;
    int a = rel < 0 ? -rel : rel;
    int abs_pos = (a < 16) ? 15 : (a < 511 ? a : 511);
    int bucket;
    if (abs_pos <= 16) {
        bucket = rel;
    } else {
        double lp = ceil(log((double)abs_pos / 16.0) / log(511.0 / 16.0) * 15.0);
        int l = (int)lp + 16;
        bucket = (rel > 0) ? l : -l;
    }
    int idx = bucket + 31;
    if (idx < 0) idx = 0;
    if (idx > 62) idx = 62;
    tab[i] = idx;
}

// ---------------------------------------------------------------------------
// generic f32 -> bf16 bulk conversion (8 elems/thread)
// ---------------------------------------------------------------------------
__global__ __launch_bounds__(256) void k_f2b(const float* __restrict__ in,
                                             unsigned short* __restrict__ out, int n8) {
    int i = blockIdx.x * 256 + threadIdx.x;
    if (i >= n8) return;
    float4 a = ((const float4*)in)[2 * (size_t)i];
    float4 b = ((const float4*)in)[2 * (size_t)i + 1];
    ushort4 lo, hi;
    lo.x = f2b(a.x); lo.y = f2b(a.y); lo.z = f2b(a.z); lo.w = f2b(a.w);
    hi.x = f2b(b.x); hi.y = f2b(b.y); hi.z = f2b(b.z); hi.w = f2b(b.w);
    ((ushort4*)out)[2 * (size_t)i] = lo;
    ((ushort4*)out)[2 * (size_t)i + 1] = hi;
}

// ---------------------------------------------------------------------------
// merged: per-layer weight conversion (blocks 0..3168) + LN of x (blocks 3169..7264)
// ---------------------------------------------------------------------------
__global__ __launch_bounds__(256) void k_f2b_ln(const float* __restrict__ wvg,
                                                const float* __restrict__ wout,
                                                const float* __restrict__ w1,
                                                const float* __restrict__ w2,
                                                unsigned short* __restrict__ wbf,
                                                const float* __restrict__ x,
                                                unsigned short* __restrict__ hs) {
    int bid = blockIdx.x;
    int t = threadIdx.x;
    if (bid < 3169) {
        int i = bid * 256 + t;
        if (i >= 811008) return;
        const float* src;
        int off;
        if (i < 221184) {
            if (i < 147456) { src = wvg;  off = i; }
            else            { src = wout; off = i - 147456; }
        } else if (i < 614400) { src = w1; off = i - 221184; }
        else                   { src = w2; off = i - 614400; }
        float4 a = ((const float4*)src)[2 * (size_t)off];
        float4 b = ((const float4*)src)[2 * (size_t)off + 1];
        ushort4 lo, hi;
        lo.x = f2b(a.x); lo.y = f2b(a.y); lo.z = f2b(a.z); lo.w = f2b(a.w);
        hi.x = f2b(b.x); hi.y = f2b(b.y); hi.z = f2b(b.z); hi.w = f2b(b.w);
        ((ushort4*)wbf)[2 * (size_t)i] = lo;
        ((ushort4*)wbf)[2 * (size_t)i + 1] = hi;
    } else {
        int row = bid - 3169;
        const float* r = x + (size_t)row * HH;
        float v0 = r[t], v1 = r[t + 256], v2 = r[t + 512];
        float s = v0 + v1 + v2;
        float ss = v0 * v0 + v1 * v1 + v2 * v2;
        float2 r2 = blockReduceSum2(s, ss);
        float mean = r2.x * (1.0f / HH);
        float var = r2.y * (1.0f / HH) - mean * mean;
        float rs = rsqrtf(var + 1e-7f);
        unsigned short* o = hs + (size_t)row * HH;
        o[t] = f2b((v0 - mean) * rs);
        o[t + 256] = f2b((v1 - mean) * rs);
        o[t + 512] = f2b((v2 - mean) * rs);
    }
}

// ---------------------------------------------------------------------------
// LayerNorm family; EPS = 1e-7, biased variance
// ---------------------------------------------------------------------------
__global__ __launch_bounds__(256) void k_ln_bf(const float* __restrict__ in,
                                               unsigned short* __restrict__ out) {
    int row = blockIdx.x, t = threadIdx.x;
    const float* r = in + (size_t)row * HH;
    float v0 = r[t], v1 = r[t + 256], v2 = r[t + 512];
    float s = v0 + v1 + v2;
    float ss = v0 * v0 + v1 * v1 + v2 * v2;
    float2 r2 = blockReduceSum2(s, ss);
    float mean = r2.x * (1.0f / HH);
    float var = r2.y * (1.0f / HH) - mean * mean;
    float rs = rsqrtf(var + 1e-7f);
    unsigned short* o = out + (size_t)row * HH;
    o[t] = f2b((v0 - mean) * rs);
    o[t + 256] = f2b((v1 - mean) * rs);
    o[t + 512] = f2b((v2 - mean) * rs);
}

__global__ __launch_bounds__(256) void k_embed_ln(const int* __restrict__ ids,
                                                  const float* __restrict__ emb,
                                                  float* __restrict__ out) {
    int row = blockIdx.x, t = threadIdx.x;
    const float* r = emb + (size_t)ids[row] * HH;
    float v0 = r[t], v1 = r[t + 256], v2 = r[t + 512];
    float s = v0 + v1 + v2;
    float ss = v0 * v0 + v1 * v1 + v2 * v2;
    float2 r2 = blockReduceSum2(s, ss);
    float mean = r2.x * (1.0f / HH);
    float var = r2.y * (1.0f / HH) - mean * mean;
    float rs = rsqrtf(var + 1e-7f);
    float* o = out + (size_t)row * HH;
    o[t] = (v0 - mean) * rs;
    o[t + 256] = (v1 - mean) * rs;
    o[t + 512] = (v2 - mean) * rs;
}

// rel LN -> bf16, padded to 128 rows (rows 63..127 zero)
__global__ __launch_bounds__(256) void k_rel_ln_bf(const float* __restrict__ rel_emb,
                                                   const float* __restrict__ g,
                                                   const float* __restrict__ b,
                                                   unsigned short* __restrict__ out) {
    int row = blockIdx.x, t = threadIdx.x;
    unsigned short* o = out + (size_t)row * HH;
    if (row >= 63) {
        o[t] = 0; o[t + 256] = 0; o[t + 512] = 0;
        return;
    }
    const float* r = rel_emb + (size_t)row * HH;
    float v0 = r[t], v1 = r[t + 256], v2 = r[t + 512];
    float s = v0 + v1 + v2;
    float ss = v0 * v0 + v1 * v1 + v2 * v2;
    float2 r2 = blockReduceSum2(s, ss);
    float mean = r2.x * (1.0f / HH);
    float var = r2.y * (1.0f / HH) - mean * mean;
    float rs = rsqrtf(var + 1e-7f);
    o[t] = f2b((v0 - mean) * rs * g[t] + b[t]);
    o[t + 256] = f2b((v1 - mean) * rs * g[t + 256] + b[t + 256]);
    o[t + 512] = f2b((v2 - mean) * rs * g[t + 512] + b[t + 512]);
}

// ctx_bf = bf16(LN(ctxr * gelu_exact(g))), g = qkvg[..., 2304:3072] (bf16)
__global__ __launch_bounds__(256) void k_gated_ln(const float* __restrict__ ctxr,
                                                  const unsigned short* __restrict__ qkvg,
                                                  unsigned short* __restrict__ out) {
    int row = blockIdx.x, t = threadIdx.x;
    const float* cr = ctxr + (size_t)row * HH;
    const unsigned short* gr = qkvg + (size_t)row * 3072 + 2304;
    float v[3];
    float s = 0.f, ss = 0.f;
#pragma unroll
    for (int e = 0; e < 3; ++e) {
        int i = t + e * 256;
        float x = cr[i] * gelu_erf(b2f(gr[i]));
        v[e] = x;
        s += x; ss += x * x;
    }
    float2 r2 = blockReduceSum2(s, ss);
    float mean = r2.x * (1.0f / HH);
    float var = r2.y * (1.0f / HH) - mean * mean;
    float rs = rsqrtf(var + 1e-7f);
    unsigned short* o = out + (size_t)row * HH;
#pragma unroll
    for (int e = 0; e < 3; ++e) o[t + e * 256] = f2b((v[e] - mean) * rs);
}

// h2_bf = bf16(LN(ffh[:, :I] * gelu_tanh(ffh[:, I:])))  (ffh bf16 [row][4096])
__global__ __launch_bounds__(256) void k_ffn_ln(const unsigned short* __restrict__ ffh,
                                                unsigned short* __restrict__ out) {
    int row = blockIdx.x, t = threadIdx.x;
    const unsigned short* ar = ffh + (size_t)row * 4096 + t * 8;
    const unsigned short* gr = ar + II;
    ushort4 a0 = *(const ushort4*)ar;
    ushort4 a1 = *(const ushort4*)(ar + 4);
    ushort4 g0 = *(const ushort4*)gr;
    ushort4 g1 = *(const ushort4*)(gr + 4);
    float av[8] = {b2f(a0.x), b2f(a0.y), b2f(a0.z), b2f(a0.w),
                   b2f(a1.x), b2f(a1.y), b2f(a1.z), b2f(a1.w)};
    float gv[8] = {b2f(g0.x), b2f(g0.y), b2f(g0.z), b2f(g0.w),
                   b2f(g1.x), b2f(g1.y), b2f(g1.z), b2f(g1.w)};
    float v[8];
    float s = 0.f, ss = 0.f;
#pragma unroll
    for (int e = 0; e < 8; ++e) {
        float x = av[e] * gelu_tanh(gv[e]);
        v[e] = x;
        s += x; ss += x * x;
    }
    float2 r2 = blockReduceSum2(s, ss);
    float mean = r2.x * (1.0f / II);
    float var = r2.y * (1.0f / II) - mean * mean;
    float rs = rsqrtf(var + 1e-7f);
    ushort4 o0, o1;
    o0.x = f2b((v[0] - mean) * rs); o0.y = f2b((v[1] - mean) * rs);
    o0.z = f2b((v[2] - mean) * rs); o0.w = f2b((v[3] - mean) * rs);
    o1.x = f2b((v[4] - mean) * rs); o1.y = f2b((v[5] - mean) * rs);
    o1.z = f2b((v[6] - mean) * rs); o1.w = f2b((v[7] - mean) * rs);
    unsigned short* o = out + (size_t)row * II + t * 8;
    *(ushort4*)o = o0;
    *(ushort4*)(o + 4) = o1;
}

// ---------------------------------------------------------------------------
// bf16 MFMA GEMM (m97 structure + bijective XCD swizzle + z-batch) —
// used only for the batched posproj at setup.
// ---------------------------------------------------------------------------
template <int OBF>
__global__ __launch_bounds__(256) void k_gemm_bf16(const unsigned short* __restrict__ A, int lda,
                                                   const unsigned short* __restrict__ W, int ldw,
                                                   void* __restrict__ Cv, int ldc,
                                                   int M, int N, int K,
                                                   const float* __restrict__ bias,
                                                   const float* __restrict__ bias2,
                                                   const float* __restrict__ res,
                                                   size_t wz, size_t cz, size_t bz) {
    __shared__ unsigned short As[128 * 32];
    __shared__ unsigned short Ws[128 * 32];
    int zz = blockIdx.z;
    W += (size_t)zz * wz;
    if (bias) bias += (size_t)zz * bz;
    int nwg = gridDim.x * gridDim.y;
    int orig = blockIdx.y * gridDim.x + blockIdx.x;
    int qq = nwg >> 3, rr = nwg & 7;
    int xcd = orig & 7, idx = orig >> 3;
    int wg = (xcd < rr ? xcd * (qq + 1) : rr * (qq + 1) + (xcd - rr) * qq) + idx;
    int bx = wg % gridDim.x, by = wg / gridDim.x;

    const int t = threadIdx.x;
    const int lane = t & 63, wid = t >> 6;
    const int row0 = by * 128, col0 = bx * 128;
    const int wr = (wid >> 1) * 64, wc = (wid & 1) * 64;
    const int rA = lane & 15, kA = (lane >> 4) * 8;

    f32x4 acc[4][4] = {};

    for (int k0 = 0; k0 < K; k0 += 32) {
#pragma unroll
        for (int j = 0; j < 2; ++j) {
            int c = t + j * 256;
            int r = c >> 2, ko = (c & 3) * 8;
            const unsigned short* srcA = A + (size_t)(row0 + r) * lda + k0 + ko;
            const unsigned short* srcB = W + (size_t)(col0 + r) * ldw + k0 + ko;
            unsigned short* dstA = As + (size_t)(j * 256 + wid * 64) * 8;
            unsigned short* dstB = Ws + (size_t)(j * 256 + wid * 64) * 8;
            __builtin_amdgcn_global_load_lds(
                (const __attribute__((address_space(1))) void*)srcA,
                (__attribute__((address_space(3))) void*)dstA, 16, 0, 0);
            __builtin_amdgcn_global_load_lds(
                (const __attribute__((address_space(1))) void*)srcB,
                (__attribute__((address_space(3))) void*)dstB, 16, 0, 0);
        }
        __syncthreads();
        bf16x8 af[4], bfr[4];
#pragma unroll
        for (int m = 0; m < 4; ++m)
            af[m] = *(const bf16x8*)&As[(wr + m * 16 + rA) * 32 + kA];
#pragma unroll
        for (int n = 0; n < 4; ++n)
            bfr[n] = *(const bf16x8*)&Ws[(wc + n * 16 + rA) * 32 + kA];
#pragma unroll
        for (int m = 0; m < 4; ++m)
#pragma unroll
            for (int n = 0; n < 4; ++n)
                acc[m][n] = __builtin_amdgcn_mfma_f32_16x16x32_bf16(af[m], bfr[n], acc[m][n], 0, 0, 0);
        __syncthreads();
    }

    float* Cf = (float*)Cv + (size_t)zz * cz;
    unsigned short* Cb = (unsigned short*)Cv + (size_t)zz * cz;
    const int cl = lane & 15, rg = (lane >> 4) * 4;
#pragma unroll
    for (int n = 0; n < 4; ++n) {
        int gc = col0 + wc + n * 16 + cl;
        float bv = 0.0f;
        if (bias) bv = (bias2 && gc >= 1536) ? bias2[gc - 1536] : bias[gc];
#pragma unroll
        for (int m = 0; m < 4; ++m) {
#pragma unroll
            for (int i = 0; i < 4; ++i) {
                int gr = row0 + wr + m * 16 + rg + i;
                float v = acc[m][n][i] + bv;
                if (OBF) {
                    Cb[(size_t)gr * ldc + gc] = f2b(v);
                } else {
                    if (res) v += res[(size_t)gr * ldc + gc];
                    Cf[(size_t)gr * ldc + gc] = v;
                }
            }
        }
    }
}

// ---------------------------------------------------------------------------
// Skinny bf16 MFMA GEMM for N=768 (Wout, W2), 2-slot pipelined
// ---------------------------------------------------------------------------
#define SKSLOT 16384  /* 16 KB per slot: A 8KB @0, B 8KB @8192 */

__device__ __forceinline__ void sk_stage(const unsigned short* __restrict__ Ab, int lda,
                                         const unsigned short* __restrict__ Wb, int ldw,
                                         unsigned char* slot, int t, int wid) {
    int rit = t >> 3;
    int kb = (t & 7) << 4;
#pragma unroll
    for (int c = 0; c < 2; ++c) {
        int row = c * 32 + rit;
        int gkb = kb ^ ((row & 7) << 4);
        const unsigned short* src = Ab + (size_t)row * lda + (gkb >> 1);
        unsigned char* dst = slot + c * 4096 + wid * 1024;
        __builtin_amdgcn_global_load_lds(
            (const __attribute__((address_space(1))) void*)src,
            (__attribute__((address_space(3))) void*)dst, 16, 0, 0);
    }
#pragma unroll
    for (int c = 0; c < 2; ++c) {
        int row = c * 32 + rit;
        int gkb = kb ^ ((row & 7) << 4);
        const unsigned short* src = Wb + (size_t)row * ldw + (gkb >> 1);
        unsigned char* dst = slot + 8192 + c * 4096 + wid * 1024;
        __builtin_amdgcn_global_load_lds(
            (const __attribute__((address_space(1))) void*)src,
            (__attribute__((address_space(3))) void*)dst, 16, 0, 0);
    }
}

__device__ __forceinline__ void sk_compute(const unsigned char* slot, int wr, int wc,
                                           int rA, int g16, f32x4 acc[2][2]) {
    const unsigned char* Ab = slot;
    const unsigned char* Bb = slot + 8192;
    bf16x8 a[2][2], b[2][2];
#pragma unroll
    for (int m = 0; m < 2; ++m) {
        int row = wr + m * 16 + rA;
        int sw = (row & 7) << 4;
#pragma unroll
        for (int s = 0; s < 2; ++s)
            a[m][s] = *(const bf16x8*)(Ab + row * 128 + ((s * 64 + g16 * 16) ^ sw));
    }
#pragma unroll
    for (int n = 0; n < 2; ++n) {
        int row = wc + n * 16 + rA;
        int sw = (row & 7) << 4;
#pragma unroll
        for (int s = 0; s < 2; ++s)
            b[n][s] = *(const bf16x8*)(Bb + row * 128 + ((s * 64 + g16 * 16) ^ sw));
    }
    __builtin_amdgcn_s_setprio(1);
#pragma unroll
    for (int m = 0; m < 2; ++m)
#pragma unroll
        for (int n = 0; n < 2; ++n) {
            acc[m][n] = __builtin_amdgcn_mfma_f32_16x16x32_bf16(a[m][0], b[n][0], acc[m][n], 0, 0, 0);
            acc[m][n] = __builtin_amdgcn_mfma_f32_16x16x32_bf16(a[m][1], b[n][1], acc[m][n], 0, 0, 0);
        }
    __builtin_amdgcn_s_setprio(0);
}

__global__ __launch_bounds__(256) void k_gemm_skinny(const unsigned short* __restrict__ A, int lda,
                                                     const unsigned short* __restrict__ W, int ldw,
                                                     float* __restrict__ C, int ldc,
                                                     int M, int N, int K,
                                                     const float* __restrict__ bias,
                                                     const float* __restrict__ res) {
    __shared__ unsigned char smem[2 * SKSLOT];
    int nwg = gridDim.x * gridDim.y;
    int orig = blockIdx.y * gridDim.x + blockIdx.x;
    int qq = nwg >> 3, rr = nwg & 7;
    int xcd = orig & 7, idx = orig >> 3;
    int wg = (xcd < rr ? xcd * (qq + 1) : rr * (qq + 1) + (xcd - rr) * qq) + idx;
    int bx = wg % gridDim.x, by = wg / gridDim.x;

    const int t = threadIdx.x;
    const int lane = t & 63, wid = t >> 6;
    const int row0 = by * 64, col0 = bx * 64;
    const int wr = (wid >> 1) * 32, wc = (wid & 1) * 32;
    const int rA = lane & 15, g16 = lane >> 4;
    const unsigned short* Abase = A + (size_t)row0 * lda;
    const unsigned short* Wbase = W + (size_t)col0 * ldw;

    const int nt = K >> 6;
    f32x4 acc[2][2] = {};

    sk_stage(Abase, lda, Wbase, ldw, smem, t, wid);

    for (int tt = 0; tt < nt; ++tt) {
        asm volatile("s_barrier" ::: "memory");
        if (tt + 1 < nt) {
            sk_stage(Abase + (size_t)(tt + 1) * 64, lda, Wbase + (size_t)(tt + 1) * 64,
                     ldw, smem + (size_t)((tt + 1) & 1) * SKSLOT, t, wid);
            asm volatile("s_waitcnt vmcnt(4)" ::: "memory");
        } else {
            asm volatile("s_waitcnt vmcnt(0)" ::: "memory");
        }
        asm volatile("s_barrier" ::: "memory");
        sk_compute(smem + (size_t)(tt & 1) * SKSLOT, wr, wc, rA, g16, acc);
    }

    const int cl = lane & 15, rg = (lane >> 4) * 4;
#pragma unroll
    for (int n = 0; n < 2; ++n) {
        int gc = col0 + wc + n * 16 + cl;
        float bv = bias ? bias[gc] : 0.0f;
#pragma unroll
        for (int m = 0; m < 2; ++m) {
#pragma unroll
            for (int i = 0; i < 4; ++i) {
                int gr = row0 + wr + m * 16 + rg + i;
                float v = acc[m][n][i] + bv;
                if (res) v += res[(size_t)gr * ldc + gc];
                C[(size_t)gr * ldc + gc] = v;
            }
        }
    }
}

// ---------------------------------------------------------------------------
// Mid bf16 MFMA GEMM (qkvg, W1): BM=128, BN=128, BK=64, 512 threads
// (8 waves 2x4, 64x32 out per wave), 2 LDS slots of 32 KB -> 64 KB total
// => 2 blocks/CU (16 waves/CU) vs gemm_big's 1. Same proven 2-slot schedule:
// stage t+1 || compute t, vmcnt(4) (4 load-insts/wave/stage), raw barriers,
// XOR-swizzle both-sides, setprio. bf16 out + bias[/bias2 at col>=1536].
// Requires M%128==0, N%128==0, K%64==0, K/64>=2.
// ---------------------------------------------------------------------------
#define MDSLOT 32768  /* 32 KB per slot: A 16KB @0, B 16KB @16384 */

__device__ __forceinline__ void md_stage(const unsigned short* __restrict__ Ab, int lda,
                                         const unsigned short* __restrict__ Wb, int ldw,
                                         unsigned char* slot, int t, int wid) {
    int rit = t >> 3;             // 0..63
    int kb = (t & 7) << 4;        // byte offset of 16B chunk within 128B row
#pragma unroll
    for (int c = 0; c < 2; ++c) { // A: 128 rows
        int row = c * 64 + rit;
        int gkb = kb ^ ((row & 7) << 4);
        const unsigned short* src = Ab + (size_t)row * lda + (gkb >> 1);
        unsigned char* dst = slot + c * 8192 + wid * 1024;
        __builtin_amdgcn_global_load_lds(
            (const __attribute__((address_space(1))) void*)src,
            (__attribute__((address_space(3))) void*)dst, 16, 0, 0);
    }
#pragma unroll
    for (int c = 0; c < 2; ++c) { // B: 128 rows
        int row = c * 64 + rit;
        int gkb = kb ^ ((row & 7) << 4);
        const unsigned short* src = Wb + (size_t)row * ldw + (gkb >> 1);
        unsigned char* dst = slot + 16384 + c * 8192 + wid * 1024;
        __builtin_amdgcn_global_load_lds(
            (const __attribute__((address_space(1))) void*)src,
            (__attribute__((address_space(3))) void*)dst, 16, 0, 0);
    }
}

__device__ __forceinline__ void md_compute(const unsigned char* slot, int wm, int wn,
                                           int rA, int g16, f32x4 acc[4][2]) {
    const unsigned char* Ab = slot;
    const unsigned char* Bb = slot + 16384;
    bf16x8 a[4][2], b[2][2];
#pragma unroll
    for (int m = 0; m < 4; ++m) {
        int row = wm * 64 + m * 16 + rA;
        int sw = (row & 7) << 4;
#pragma unroll
        for (int s = 0; s < 2; ++s)
            a[m][s] = *(const bf16x8*)(Ab + row * 128 + ((s * 64 + g16 * 16) ^ sw));
    }
#pragma unroll
    for (int n = 0; n < 2; ++n) {
        int row = wn * 32 + n * 16 + rA;
        int sw = (row & 7) << 4;
#pragma unroll
        for (int s = 0; s < 2; ++s)
            b[n][s] = *(const bf16x8*)(Bb + row * 128 + ((s * 64 + g16 * 16) ^ sw));
    }
    __builtin_amdgcn_s_setprio(1);
#pragma unroll
    for (int m = 0; m < 4; ++m)
#pragma unroll
        for (int n = 0; n < 2; ++n) {
            acc[m][n] = __builtin_amdgcn_mfma_f32_16x16x32_bf16(a[m][0], b[n][0], acc[m][n], 0, 0, 0);
            acc[m][n] = __builtin_amdgcn_mfma_f32_16x16x32_bf16(a[m][1], b[n][1], acc[m][n], 0, 0, 0);
        }
    __builtin_amdgcn_s_setprio(0);
}

__global__ __launch_bounds__(512) void k_gemm_mid(const unsigned short* __restrict__ A, int lda,
                                                  const unsigned short* __restrict__ W,
                                                  const unsigned short* __restrict__ Wb2, int ldw,
                                                  unsigned short* __restrict__ Cb, int ldc,
                                                  int M, int N, int K,
                                                  const float* __restrict__ bias,
                                                  const float* __restrict__ bias2) {
    extern __shared__ unsigned char smem[];
    int nwg = gridDim.x * gridDim.y;
    int orig = blockIdx.y * gridDim.x + blockIdx.x;
    int qq = nwg >> 3, rr = nwg & 7;
    int xcd = orig & 7, idx = orig >> 3;
    int wg = (xcd < rr ? xcd * (qq + 1) : rr * (qq + 1) + (xcd - rr) * qq) + idx;
    int bx = wg % gridDim.x, by = wg / gridDim.x;

    const int t = threadIdx.x;
    const int lane = t & 63, wid = t >> 6;
    const int wm = wid >> 2, wn = wid & 3;      // 2 x 4 wave grid (64x32 per wave)
    const int rA = lane & 15, g16 = lane >> 4;
    const int row0 = by * 128, col0 = bx * 128;
    const unsigned short* Abase = A + (size_t)row0 * lda;
    const unsigned short* Wbase = (Wb2 && col0 >= 1536)
                                      ? Wb2 + (size_t)(col0 - 1536) * ldw
                                      : W + (size_t)col0 * ldw;

    const int nt = K >> 6;
    f32x4 acc[4][2] = {};

    md_stage(Abase, lda, Wbase, ldw, smem, t, wid);

    for (int tt = 0; tt < nt; ++tt) {
        asm volatile("s_barrier" ::: "memory");  // all waves done reading slot (tt+1)&1
        if (tt + 1 < nt) {
            md_stage(Abase + (size_t)(tt + 1) * 64, lda, Wbase + (size_t)(tt + 1) * 64,
                     ldw, smem + (size_t)((tt + 1) & 1) * MDSLOT, t, wid);
            asm volatile("s_waitcnt vmcnt(4)" ::: "memory");  // tile tt landed (per-wave)
        } else {
            asm volatile("s_waitcnt vmcnt(0)" ::: "memory");
        }
        asm volatile("s_barrier" ::: "memory");               // tile tt visible to all waves
        md_compute(smem + (size_t)(tt & 1) * MDSLOT, wm, wn, rA, g16, acc);
    }

    const int cl = lane & 15, rg = (lane >> 4) * 4;
#pragma unroll
    for (int n = 0; n < 2; ++n) {
        int gc = col0 + wn * 32 + n * 16 + cl;
        float bv = 0.0f;
        if (bias) bv = (bias2 && gc >= 1536) ? bias2[gc - 1536] : bias[gc];
#pragma unroll
        for (int m = 0; m < 4; ++m) {
#pragma unroll
            for (int i = 0; i < 4; ++i) {
                int gr = row0 + wm * 64 + m * 16 + rg + i;
                Cb[(size_t)gr * ldc + gc] = f2b(acc[m][n][i] + bv);
            }
        }
    }
}

// ---------------------------------------------------------------------------
// merged: repack (blockIdx.x<8) + cp/pc MFMA (blockIdx.x>=8); grid (16, 96)
// ---------------------------------------------------------------------------
__global__ __launch_bounds__(256) void k_repack_cppc(const unsigned short* __restrict__ qkvg,
                                                     const unsigned short* __restrict__ pp,
                                                     unsigned short* __restrict__ qT,
                                                     unsigned short* __restrict__ kT,
                                                     unsigned short* __restrict__ vT,
                                                     float* __restrict__ cp,
                                                     float* __restrict__ pc) {
    __shared__ unsigned char shmem[12288];
    int t = threadIdx.x;
    if (blockIdx.x < 8) {
        unsigned short (*tile)[72] = (unsigned short(*)[72])shmem;
        int bh = blockIdx.y;
        int b = bh / NHH, h = bh % NHH;
        int s0 = blockIdx.x * 64;
#pragma unroll
        for (int j = 0; j < 2; ++j) {
            int idx = t + j * 256;
            int r = idx >> 3, dc = idx & 7;
            const unsigned short* src = qkvg + ((size_t)(s0 + r) * BB + b) * 3072 + h * DD + dc * 8;
            ushort4 a = *(const ushort4*)src;
            ushort4 c = *(const ushort4*)(src + 4);
            unsigned short* dq = qT + ((size_t)bh * SS + s0 + r) * DD + dc * 8;
            *(ushort4*)dq = a; *(ushort4*)(dq + 4) = c;
            const unsigned short* srck = src + HH;
            ushort4 a2 = *(const ushort4*)srck;
            ushort4 c2 = *(const ushort4*)(srck + 4);
            unsigned short* dk = kT + ((size_t)bh * SS + s0 + r) * DD + dc * 8;
            *(ushort4*)dk = a2; *(ushort4*)(dk + 4) = c2;
        }
#pragma unroll
        for (int j = 0; j < 4; ++j) {
            int idx = t + j * 256;
            int r = idx >> 4, c4 = idx & 15;
            ushort4 u = *(const ushort4*)(qkvg + ((size_t)(s0 + r) * BB + b) * 3072 + 1536 + h * DD + c4 * 4);
            *(ushort4*)&tile[r][c4 * 4] = u;
        }
        __syncthreads();
#pragma unroll
        for (int j = 0; j < 2; ++j) {
            int idx = t + j * 256;
            int d = idx >> 3, s8 = idx & 7;
            ushort4 a, c;
            a.x = tile[s8 * 8 + 0][d]; a.y = tile[s8 * 8 + 1][d];
            a.z = tile[s8 * 8 + 2][d]; a.w = tile[s8 * 8 + 3][d];
            c.x = tile[s8 * 8 + 4][d]; c.y = tile[s8 * 8 + 5][d];
            c.z = tile[s8 * 8 + 6][d]; c.w = tile[s8 * 8 + 7][d];
            unsigned short* dst = vT + ((size_t)bh * DD + d) * SS + s0 + s8 * 8;
            *(ushort4*)dst = a; *(ushort4*)(dst + 4) = c;
        }
    } else {
        int cid = (blockIdx.x - 8) * 96 + blockIdx.y;
        int z = cid >= 384;
        int rem = cid - (z ? 384 : 0);
        int h = rem >> 5;
        int mt = rem & 31;
        int aoff = z ? HH : 0;
        int toff = z ? 0 : HH;
        float* out = z ? pc : cp;
        unsigned short* As = (unsigned short*)shmem;
        unsigned short* Bs = (unsigned short*)(shmem + 8192);
        const int lane = t & 63, wid = t >> 6;
        const int rA = lane & 15, kA = (lane >> 4) * 8;

        f32x4 acc[2][4] = {};

        for (int k0 = 0; k0 < 64; k0 += 32) {
#pragma unroll
            for (int j = 0; j < 2; ++j) {
                int c = t + j * 256;
                int r = c >> 2, ko = (c & 3) * 8;
                const unsigned short* srcA = qkvg + (size_t)(mt * 128 + r) * 3072 + aoff + h * DD + k0 + ko;
                unsigned short* dstA = As + (size_t)(j * 256 + wid * 64) * 8;
                __builtin_amdgcn_global_load_lds(
                    (const __attribute__((address_space(1))) void*)srcA,
                    (__attribute__((address_space(3))) void*)dstA, 16, 0, 0);
            }
            {
                int r = t >> 2, ko = (t & 3) * 8;
                const unsigned short* srcB = pp + (size_t)r * 1536 + toff + h * DD + k0 + ko;
                unsigned short* dstB = Bs + (size_t)(wid * 64) * 8;
                __builtin_amdgcn_global_load_lds(
                    (const __attribute__((address_space(1))) void*)srcB,
                    (__attribute__((address_space(3))) void*)dstB, 16, 0, 0);
            }
            __syncthreads();
            bf16x8 af[2], bfr[4];
#pragma unroll
            for (int m = 0; m < 2; ++m)
                af[m] = *(const bf16x8*)&As[(wid * 32 + m * 16 + rA) * 32 + kA];
#pragma unroll
            for (int n = 0; n < 4; ++n)
                bfr[n] = *(const bf16x8*)&Bs[(n * 16 + rA) * 32 + kA];
#pragma unroll
            for (int m = 0; m < 2; ++m)
#pragma unroll
                for (int n = 0; n < 4; ++n)
                    acc[m][n] = __builtin_amdgcn_mfma_f32_16x16x32_bf16(af[m], bfr[n], acc[m][n], 0, 0, 0);
            __syncthreads();
        }

        const int cl = lane & 15, rg = (lane >> 4) * 4;
#pragma unroll
        for (int m = 0; m < 2; ++m)
#pragma unroll
            for (int n = 0; n < 4; ++n) {
                int gc = n * 16 + cl;
                if (gc < 63) {
#pragma unroll
                    for (int i = 0; i < 4; ++i) {
                        int gr = mt * 128 + wid * 32 + m * 16 + rg + i;
                        int sIdx = gr >> 3, bIdx = gr & 7;
                        out[(((size_t)(bIdx * NHH + h)) * SS + sIdx) * 63 + gc] = acc[m][n][i];
                    }
                }
            }
    }
}

// ---------------------------------------------------------------------------
// fused disentangled flash attention v2 (round-10/13 proven config)
// ---------------------------------------------------------------------------
__global__ __launch_bounds__(256) void k_attn_fused(
    const unsigned short* __restrict__ qT, const unsigned short* __restrict__ kT,
    const unsigned short* __restrict__ vT, const float* __restrict__ cp,
    const float* __restrict__ pc, const int* __restrict__ bucket,
    const int* __restrict__ mask, float* __restrict__ ctxr) {
    __shared__ float cps[64 * 63];
    __shared__ float pcs[64 * 63];
    __shared__ unsigned short pb_all[4][16 * 72];
    __shared__ int btab[1023];
    int t = threadIdx.x;
    int lane = t & 63, wid = t >> 6;
    int bh = blockIdx.y;
    int b = bh / NHH, h = bh % NHH;
    int qb0 = blockIdx.x * 64;
    int q0 = qb0 + wid * 16;
    int rA = lane & 15, g = lane >> 4, kA = g * 8;
    unsigned short* pb = pb_all[wid];
    const unsigned short* qTb = qT + (size_t)bh * SS * DD;
    const unsigned short* kTb = kT + (size_t)bh * SS * DD;
    const unsigned short* vTb = vT + (size_t)bh * DD * SS;
    const float* cpb = cp + (size_t)bh * SS * 63 + (size_t)qb0 * 63;
    const float* pcb = pc + (size_t)bh * SS * 63;
    const int* mkb = mask + b * SS;

    for (int i = t; i < 1023; i += 256) btab[i] = bucket[i];
    for (int i = t; i < 1008; i += 256) ((float4*)cps)[i] = ((const float4*)cpb)[i];

    bf16x8 aq[2];
#pragma unroll
    for (int dc = 0; dc < 2; ++dc)
        aq[dc] = *(const bf16x8*)&qTb[(size_t)(q0 + rA) * DD + dc * 32 + kA];

    f32x4 o[4] = {};
    float mrow[4], lrow[4];
#pragma unroll
    for (int i = 0; i < 4; ++i) { mrow[i] = -INFINITY; lrow[i] = 0.f; }

    for (int kt = 0; kt < 8; ++kt) {
        int k0 = kt * 64;
        __syncthreads();
        {
            const float4* src = (const float4*)(pcb + (size_t)k0 * 63);
            for (int i = t; i < 1008; i += 256) ((float4*)pcs)[i] = src[i];
        }
        f32x4 sa[4] = {};
#pragma unroll
        for (int n = 0; n < 4; ++n) {
            bf16x8 bk0 = *(const bf16x8*)&kTb[(size_t)(k0 + n * 16 + rA) * DD + kA];
            bf16x8 bk1 = *(const bf16x8*)&kTb[(size_t)(k0 + n * 16 + rA) * DD + 32 + kA];
            sa[n] = __builtin_amdgcn_mfma_f32_16x16x32_bf16(aq[0], bk0, sa[n], 0, 0, 0);
            sa[n] = __builtin_amdgcn_mfma_f32_16x16x32_bf16(aq[1], bk1, sa[n], 0, 0, 0);
        }
        int mk[4];
#pragma unroll
        for (int n = 0; n < 4; ++n) mk[n] = mkb[k0 + n * 16 + rA];
        __syncthreads();

        float pv[4][4];
#pragma unroll
        for (int i = 0; i < 4; ++i) {
            int qr = wid * 16 + g * 4 + i;
            int q = qb0 + qr;
            float sv[4];
            float tmax = -INFINITY;
#pragma unroll
            for (int n = 0; n < 4; ++n) {
                int kr = n * 16 + rA;
                int id = btab[q - (k0 + kr) + 511];
                float v = (sa[n][i] + cps[qr * 63 + id] + pcs[kr * 63 + id]) * SCALE_F;
                v = mk[n] ? -1e9f : v;
                sv[n] = v;
                tmax = fmaxf(tmax, v);
            }
            tmax = fmaxf(tmax, __shfl_xor(tmax, 1, 16));
            tmax = fmaxf(tmax, __shfl_xor(tmax, 2, 16));
            tmax = fmaxf(tmax, __shfl_xor(tmax, 4, 16));
            tmax = fmaxf(tmax, __shfl_xor(tmax, 8, 16));
            float mold = mrow[i];
            float mnew = fmaxf(mold, tmax);
            float ls = 0.f;
#pragma unroll
            for (int n = 0; n < 4; ++n) {
                float p = __expf(sv[n] - mnew);
                pv[n][i] = p;
                ls += p;
            }
            ls += __shfl_xor(ls, 1, 16);
            ls += __shfl_xor(ls, 2, 16);
            ls += __shfl_xor(ls, 4, 16);
            ls += __shfl_xor(ls, 8, 16);
            if (mnew > mold) {
                float alpha = __expf(mold - mnew);
                lrow[i] = lrow[i] * alpha + ls;
                mrow[i] = mnew;
#pragma unroll
                for (int n = 0; n < 4; ++n) o[n][i] *= alpha;
            } else {
                lrow[i] += ls;
            }
        }
#pragma unroll
        for (int n = 0; n < 4; ++n)
#pragma unroll
            for (int i = 0; i < 4; ++i)
                pb[(g * 4 + i) * 72 + n * 16 + rA] = f2b(pv[n][i]);
        bf16x8 ap[2];
#pragma unroll
        for (int kc = 0; kc < 2; ++kc)
            ap[kc] = *(const bf16x8*)&pb[rA * 72 + kc * 32 + kA];
#pragma unroll
        for (int n = 0; n < 4; ++n) {
            bf16x8 bv0 = *(const bf16x8*)&vTb[(size_t)(n * 16 + rA) * SS + k0 + kA];
            bf16x8 bv1 = *(const bf16x8*)&vTb[(size_t)(n * 16 + rA) * SS + k0 + 32 + kA];
            o[n] = __builtin_amdgcn_mfma_f32_16x16x32_bf16(ap[0], bv0, o[n], 0, 0, 0);
            o[n] = __builtin_amdgcn_mfma_f32_16x16x32_bf16(ap[1], bv1, o[n], 0, 0, 0);
        }
    }
#pragma unroll
    for (int i = 0; i < 4; ++i) {
        int q = q0 + g * 4 + i;
        float inv = 1.0f / lrow[i];
#pragma unroll
        for (int n = 0; n < 4; ++n)
            ctxr[((size_t)q * BB + b) * HH + h * DD + n * 16 + rA] = o[n][i] * inv;
    }
}

// ---------------------------------------------------------------------------
// host launcher
// ---------------------------------------------------------------------------
static inline void gemm_mid(const unsigned short* A, int lda,
                            const unsigned short* W, const unsigned short* Wb2, int ldw,
                            unsigned short* C, int ldc, int M, int N, int K,
                            const float* bias, const float* bias2, hipStream_t st) {
    dim3 g(N / 128, M / 128);
    k_gemm_mid<<<g, 512, 2 * MDSLOT, st>>>(A, lda, W, Wb2, ldw, C, ldc, M, N, K, bias, bias2);
}

extern "C" void kernel_launch(void* const* d_in, const int* in_sizes, int n_in,
                              void* d_out, int out_size, void* d_ws, size_t ws_size,
                              hipStream_t stream) {
    static int attr_done = 0;
    if (!attr_done) {
        hipFuncSetAttribute((const void*)&k_gemm_mid,
                            hipFuncAttributeMaxDynamicSharedMemorySize, 2 * MDSLOT);
        attr_done = 1;
    }

    const int* ids = (const int*)d_in[0];
    const unsigned char* maskraw = (const unsigned char*)d_in[1];
    const float* word_emb = (const float*)d_in[2];
    const float* rel_emb = (const float*)d_in[3];
    const float* rel_g = (const float*)d_in[4];
    const float* rel_b = (const float*)d_in[5];
    const float* Wqk = (const float*)d_in[6];
    const float* bqk = (const float*)d_in[7];
    const float* Wvg = (const float*)d_in[8];
    const float* bvg = (const float*)d_in[9];
    const float* Wout = (const float*)d_in[10];
    const float* bout = (const float*)d_in[11];
    const float* W1 = (const float*)d_in[12];
    const float* W2 = (const float*)d_in[13];

    const size_t N_X = (size_t)SS * BB * HH;
    const size_t N_CP = (size_t)SS * BB * NHH * 63;
    const size_t N_H2 = (size_t)SS * BB * II;
    const size_t N_WQK = (size_t)2 * HH * HH;
    const size_t N_WOUT = (size_t)HH * HH;
    const size_t N_W1 = (size_t)2 * II * HH;
    const size_t N_W2 = (size_t)HH * II;
    const size_t N_HD = (size_t)BB * NHH * SS * DD;
    const size_t N_QKVG = (size_t)SS * BB * 3072;
    const size_t N_FFH = (size_t)SS * BB * 4096;
    const size_t N_PP = (size_t)128 * 1536;

    float* ws = (float*)d_ws;
    float* x = ws;
    float* ctxr = x + N_X;
    float* cp = ctxr + N_X;
    float* pc = cp + N_CP;
    unsigned short* us = (unsigned short*)(pc + N_CP);
    unsigned short* qkvg = us;
    unsigned short* hs_bf = qkvg + N_QKVG;
    unsigned short* ctx_bf = hs_bf + N_X;
    unsigned short* h2_bf = ctx_bf + N_X;
    unsigned short* ffh = h2_bf + N_H2;
    unsigned short* wqk_all = ffh + N_FFH;
    unsigned short* wvg_bf = wqk_all + 12 * N_WQK;
    unsigned short* wout_bf = wvg_bf + N_WQK;
    unsigned short* w1_bf = wout_bf + N_WOUT;
    unsigned short* w2_bf = w1_bf + N_W1;
    unsigned short* ppall = w2_bf + N_W2;
    unsigned short* rel_bf = ppall + 12 * N_PP;
    unsigned short* qT = rel_bf + 128 * HH;
    unsigned short* kT = qT + N_HD;
    unsigned short* vT = kT + N_HD;
    int* bucket = (int*)(vT + N_HD);
    int* maski = bucket + 1024;

    size_t need_bytes = ((size_t)(maski + BB * SS) - (size_t)d_ws);
    if (ws_size < need_bytes) return;  // ~205 MB required

    // ---- setup ----
    k_decode_mask<<<1, 256, 0, stream>>>(maskraw, maski, BB * SS);
    k_bucket<<<4, 256, 0, stream>>>(bucket);
    k_embed_ln<<<SS * BB, 256, 0, stream>>>(ids, word_emb, x);
    k_rel_ln_bf<<<128, 256, 0, stream>>>(rel_emb, rel_g, rel_b, rel_bf);
    k_f2b<<<(int)((12 * N_WQK / 8 + 255) / 256), 256, 0, stream>>>(Wqk, wqk_all,
                                                                   (int)(12 * N_WQK / 8));
    {
        dim3 gpp(1536 / 128, 1, 12);
        k_gemm_bf16<1><<<gpp, 256, 0, stream>>>(rel_bf, HH, wqk_all, HH, ppall, 1536,
                                                128, 1536, HH, bqk, nullptr, nullptr,
                                                N_WQK, N_PP, 2 * HH);
    }

    for (int l = 0; l < LL; ++l) {
        const unsigned short* wqk_l = wqk_all + (size_t)l * N_WQK;
        const float* bqk_l = bqk + (size_t)l * 2 * HH;
        const float* Wvg_l = Wvg + (size_t)l * N_WQK;
        const float* bvg_l = bvg + (size_t)l * 2 * HH;
        const float* Wout_l = Wout + (size_t)l * N_WOUT;
        const float* bout_l = bout + (size_t)l * HH;
        const float* W1_l = W1 + (size_t)l * N_W1;
        const float* W2_l = W2 + (size_t)l * N_W2;

        // ---- attention ----
        k_f2b_ln<<<3169 + SS * BB, 256, 0, stream>>>(Wvg_l, Wout_l, W1_l, W2_l, wvg_bf,
                                                     x, hs_bf);
        gemm_mid(hs_bf, HH, wqk_l, wvg_bf, HH, qkvg, 3072, SS * BB, 3072, HH,
                 bqk_l, bvg_l, stream);
        k_repack_cppc<<<dim3(16, 96), 256, 0, stream>>>(qkvg, ppall + (size_t)l * N_PP,
                                                        qT, kT, vT, cp, pc);
        k_attn_fused<<<dim3(SS / 64, BB * NHH), 256, 0, stream>>>(qT, kT, vT, cp, pc,
                                                                  bucket, maski, ctxr);
        k_gated_ln<<<SS * BB, 256, 0, stream>>>(ctxr, qkvg, ctx_bf);
        k_gemm_skinny<<<dim3(HH / 64, SS * BB / 64), 256, 0, stream>>>(
            ctx_bf, HH, wout_bf, HH, x, HH, SS * BB, HH, HH, bout_l, x);

        // ---- GeGLU FFN ----
        k_ln_bf<<<SS * BB, 256, 0, stream>>>(x, hs_bf);
        gemm_mid(hs_bf, HH, w1_bf, nullptr, HH, ffh, 4096, SS * BB, 4096, HH,
                 nullptr, nullptr, stream);
        k_ffn_ln<<<SS * BB, 256, 0, stream>>>(ffh, h2_bf);
        // last layer writes the residual-added output straight into d_out
        float* outC = (l == LL - 1) ? (float*)d_out : x;
        k_gemm_skinny<<<dim3(HH / 64, SS * BB / 64), 256, 0, stream>>>(
            h2_bf, II, w2_bf, II, outC, HH, SS * BB, HH, II, nullptr, x);
    }
}

// Round 15
// 2638.852 us; speedup vs baseline: 1.0717x; 1.0082x over previous
//
#include <hip/hip_runtime.h>
#include <math.h>

#define SS 512
#define BB 8
#define NHH 12
#define DD 64
#define HH 768
#define II 2048
#define LL 12
#define SCALE_F 0.07216878364870323f  /* 1/sqrt(3*64) */

typedef __attribute__((ext_vector_type(8))) short bf16x8;
typedef __attribute__((ext_vector_type(4))) float f32x4;

// f32 -> bf16 (RNE, finite values)
__device__ __forceinline__ unsigned short f2b(float f) {
    union { float f; unsigned int u; } x; x.f = f;
    unsigned int r = x.u + 0x7fffu + ((x.u >> 16) & 1u);
    return (unsigned short)(r >> 16);
}
__device__ __forceinline__ float b2f(unsigned short u) {
    union { unsigned int u; float f; } x; x.u = ((unsigned int)u) << 16;
    return x.f;
}

// ---------------------------------------------------------------------------
// block reduction helpers (blockDim.x == 256)
// ---------------------------------------------------------------------------
__device__ __forceinline__ float2 blockReduceSum2(float a, float b) {
    __shared__ float2 sm[4];
    __shared__ float2 bc;
#pragma unroll
    for (int o = 32; o > 0; o >>= 1) {
        a += __shfl_down(a, o);
        b += __shfl_down(b, o);
    }
    int t = threadIdx.x;
    if ((t & 63) == 0) sm[t >> 6] = make_float2(a, b);
    __syncthreads();
    if (t == 0) {
        float xa = sm[0].x + sm[1].x + sm[2].x + sm[3].x;
        float xb = sm[0].y + sm[1].y + sm[2].y + sm[3].y;
        bc = make_float2(xa, xb);
    }
    __syncthreads();
    return bc;
}

__device__ __forceinline__ float gelu_erf(float v) {
    return 0.5f * v * (1.0f + erff(v * 0.70710678118654752f));
}
__device__ __forceinline__ float gelu_tanh(float v) {
    const float c = 0.7978845608028654f;
    return 0.5f * v * (1.0f + tanhf(c * (v + 0.044715f * v * v * v)));
}

// ---------------------------------------------------------------------------
// mask decode: handle bool-as-u8 or bool-as-int32 layouts
// ---------------------------------------------------------------------------
__global__ __launch_bounds__(256) void k_decode_mask(const unsigned char* __restrict__ raw,
                                                     int* __restrict__ mask, int n) {
    __shared__ int s_any;
    if (threadIdx.x == 0) s_any = 0;
    __syncthreads();
    int local = 0;
    for (int i = threadIdx.x; i < n; i += blockDim.x)
        if ((i & 3) && raw[i]) local = 1;
    if (local) atomicOr(&s_any, 1);
    __syncthreads();
    bool isU8 = (s_any != 0);
    const int* as_int = (const int*)raw;
    for (int i = threadIdx.x; i < n; i += blockDim.x)
        mask[i] = isU8 ? (raw[i] != 0) : (as_int[i] != 0);
}

// ---------------------------------------------------------------------------
// DeBERTa log-bucket table: rel in [-511,511] -> idx in [0,62]
// ---------------------------------------------------------------------------
__global__ __launch_bounds__(256) void k_bucket(int* __restrict__ tab) {
    int i = blockIdx.x * 256 + threadIdx.x;
    if (i >= 1023) return;
    int rel = i - 511;
    int a = rel < 0 ? -rel : rel;
    int abs_pos = (a < 16) ? 15 : (a < 511 ? a : 511);
    int bucket;
    if (abs_pos <= 16) {
        bucket = rel;
    } else {
        double lp = ceil(log((double)abs_pos / 16.0) / log(511.0 / 16.0) * 15.0);
        int l = (int)lp + 16;
        bucket = (rel > 0) ? l : -l;
    }
    int idx = bucket + 31;
    if (idx < 0) idx = 0;
    if (idx > 62) idx = 62;
    tab[i] = idx;
}

// ---------------------------------------------------------------------------
// generic f32 -> bf16 bulk conversion (8 elems/thread)
// ---------------------------------------------------------------------------
__global__ __launch_bounds__(256) void k_f2b(const float* __restrict__ in,
                                             unsigned short* __restrict__ out, int n8) {
    int i = blockIdx.x * 256 + threadIdx.x;
    if (i >= n8) return;
    float4 a = ((const float4*)in)[2 * (size_t)i];
    float4 b = ((const float4*)in)[2 * (size_t)i + 1];
    ushort4 lo, hi;
    lo.x = f2b(a.x); lo.y = f2b(a.y); lo.z = f2b(a.z); lo.w = f2b(a.w);
    hi.x = f2b(b.x); hi.y = f2b(b.y); hi.z = f2b(b.z); hi.w = f2b(b.w);
    ((ushort4*)out)[2 * (size_t)i] = lo;
    ((ushort4*)out)[2 * (size_t)i + 1] = hi;
}

// ---------------------------------------------------------------------------
// merged: per-layer weight conversion (blocks 0..3168) + LN of x (blocks 3169..7264)
// ---------------------------------------------------------------------------
__global__ __launch_bounds__(256) void k_f2b_ln(const float* __restrict__ wvg,
                                                const float* __restrict__ wout,
                                                const float* __restrict__ w1,
                                                const float* __restrict__ w2,
                                                unsigned short* __restrict__ wbf,
                                                const float* __restrict__ x,
                                                unsigned short* __restrict__ hs) {
    int bid = blockIdx.x;
    int t = threadIdx.x;
    if (bid < 3169) {
        int i = bid * 256 + t;
        if (i >= 811008) return;
        const float* src;
        int off;
        if (i < 221184) {
            if (i < 147456) { src = wvg;  off = i; }
            else            { src = wout; off = i - 147456; }
        } else if (i < 614400) { src = w1; off = i - 221184; }
        else                   { src = w2; off = i - 614400; }
        float4 a = ((const float4*)src)[2 * (size_t)off];
        float4 b = ((const float4*)src)[2 * (size_t)off + 1];
        ushort4 lo, hi;
        lo.x = f2b(a.x); lo.y = f2b(a.y); lo.z = f2b(a.z); lo.w = f2b(a.w);
        hi.x = f2b(b.x); hi.y = f2b(b.y); hi.z = f2b(b.z); hi.w = f2b(b.w);
        ((ushort4*)wbf)[2 * (size_t)i] = lo;
        ((ushort4*)wbf)[2 * (size_t)i + 1] = hi;
    } else {
        int row = bid - 3169;
        const float* r = x + (size_t)row * HH;
        float v0 = r[t], v1 = r[t + 256], v2 = r[t + 512];
        float s = v0 + v1 + v2;
        float ss = v0 * v0 + v1 * v1 + v2 * v2;
        float2 r2 = blockReduceSum2(s, ss);
        float mean = r2.x * (1.0f / HH);
        float var = r2.y * (1.0f / HH) - mean * mean;
        float rs = rsqrtf(var + 1e-7f);
        unsigned short* o = hs + (size_t)row * HH;
        o[t] = f2b((v0 - mean) * rs);
        o[t + 256] = f2b((v1 - mean) * rs);
        o[t + 512] = f2b((v2 - mean) * rs);
    }
}

// ---------------------------------------------------------------------------
// LayerNorm family; EPS = 1e-7, biased variance
// ---------------------------------------------------------------------------
__global__ __launch_bounds__(256) void k_ln_bf(const float* __restrict__ in,
                                               unsigned short* __restrict__ out) {
    int row = blockIdx.x, t = threadIdx.x;
    const float* r = in + (size_t)row * HH;
    float v0 = r[t], v1 = r[t + 256], v2 = r[t + 512];
    float s = v0 + v1 + v2;
    float ss = v0 * v0 + v1 * v1 + v2 * v2;
    float2 r2 = blockReduceSum2(s, ss);
    float mean = r2.x * (1.0f / HH);
    float var = r2.y * (1.0f / HH) - mean * mean;
    float rs = rsqrtf(var + 1e-7f);
    unsigned short* o = out + (size_t)row * HH;
    o[t] = f2b((v0 - mean) * rs);
    o[t + 256] = f2b((v1 - mean) * rs);
    o[t + 512] = f2b((v2 - mean) * rs);
}

__global__ __launch_bounds__(256) void k_embed_ln(const int* __restrict__ ids,
                                                  const float* __restrict__ emb,
                                                  float* __restrict__ out) {
    int row = blockIdx.x, t = threadIdx.x;
    const float* r = emb + (size_t)ids[row] * HH;
    float v0 = r[t], v1 = r[t + 256], v2 = r[t + 512];
    float s = v0 + v1 + v2;
    float ss = v0 * v0 + v1 * v1 + v2 * v2;
    float2 r2 = blockReduceSum2(s, ss);
    float mean = r2.x * (1.0f / HH);
    float var = r2.y * (1.0f / HH) - mean * mean;
    float rs = rsqrtf(var + 1e-7f);
    float* o = out + (size_t)row * HH;
    o[t] = (v0 - mean) * rs;
    o[t + 256] = (v1 - mean) * rs;
    o[t + 512] = (v2 - mean) * rs;
}

// rel LN -> bf16, padded to 128 rows (rows 63..127 zero)
__global__ __launch_bounds__(256) void k_rel_ln_bf(const float* __restrict__ rel_emb,
                                                   const float* __restrict__ g,
                                                   const float* __restrict__ b,
                                                   unsigned short* __restrict__ out) {
    int row = blockIdx.x, t = threadIdx.x;
    unsigned short* o = out + (size_t)row * HH;
    if (row >= 63) {
        o[t] = 0; o[t + 256] = 0; o[t + 512] = 0;
        return;
    }
    const float* r = rel_emb + (size_t)row * HH;
    float v0 = r[t], v1 = r[t + 256], v2 = r[t + 512];
    float s = v0 + v1 + v2;
    float ss = v0 * v0 + v1 * v1 + v2 * v2;
    float2 r2 = blockReduceSum2(s, ss);
    float mean = r2.x * (1.0f / HH);
    float var = r2.y * (1.0f / HH) - mean * mean;
    float rs = rsqrtf(var + 1e-7f);
    o[t] = f2b((v0 - mean) * rs * g[t] + b[t]);
    o[t + 256] = f2b((v1 - mean) * rs * g[t + 256] + b[t + 256]);
    o[t + 512] = f2b((v2 - mean) * rs * g[t + 512] + b[t + 512]);
}

// ctx_bf = bf16(LN(ctxr * gelu_exact(g))), g = qkvg[..., 2304:3072] (bf16)
__global__ __launch_bounds__(256) void k_gated_ln(const float* __restrict__ ctxr,
                                                  const unsigned short* __restrict__ qkvg,
                                                  unsigned short* __restrict__ out) {
    int row = blockIdx.x, t = threadIdx.x;
    const float* cr = ctxr + (size_t)row * HH;
    const unsigned short* gr = qkvg + (size_t)row * 3072 + 2304;
    float v[3];
    float s = 0.f, ss = 0.f;
#pragma unroll
    for (int e = 0; e < 3; ++e) {
        int i = t + e * 256;
        float x = cr[i] * gelu_erf(b2f(gr[i]));
        v[e] = x;
        s += x; ss += x * x;
    }
    float2 r2 = blockReduceSum2(s, ss);
    float mean = r2.x * (1.0f / HH);
    float var = r2.y * (1.0f / HH) - mean * mean;
    float rs = rsqrtf(var + 1e-7f);
    unsigned short* o = out + (size_t)row * HH;
#pragma unroll
    for (int e = 0; e < 3; ++e) o[t + e * 256] = f2b((v[e] - mean) * rs);
}

// h2_bf = bf16(LN(ffh[:, :I] * gelu_tanh(ffh[:, I:])))  (ffh bf16 [row][4096])
__global__ __launch_bounds__(256) void k_ffn_ln(const unsigned short* __restrict__ ffh,
                                                unsigned short* __restrict__ out) {
    int row = blockIdx.x, t = threadIdx.x;
    const unsigned short* ar = ffh + (size_t)row * 4096 + t * 8;
    const unsigned short* gr = ar + II;
    ushort4 a0 = *(const ushort4*)ar;
    ushort4 a1 = *(const ushort4*)(ar + 4);
    ushort4 g0 = *(const ushort4*)gr;
    ushort4 g1 = *(const ushort4*)(gr + 4);
    float av[8] = {b2f(a0.x), b2f(a0.y), b2f(a0.z), b2f(a0.w),
                   b2f(a1.x), b2f(a1.y), b2f(a1.z), b2f(a1.w)};
    float gv[8] = {b2f(g0.x), b2f(g0.y), b2f(g0.z), b2f(g0.w),
                   b2f(g1.x), b2f(g1.y), b2f(g1.z), b2f(g1.w)};
    float v[8];
    float s = 0.f, ss = 0.f;
#pragma unroll
    for (int e = 0; e < 8; ++e) {
        float x = av[e] * gelu_tanh(gv[e]);
        v[e] = x;
        s += x; ss += x * x;
    }
    float2 r2 = blockReduceSum2(s, ss);
    float mean = r2.x * (1.0f / II);
    float var = r2.y * (1.0f / II) - mean * mean;
    float rs = rsqrtf(var + 1e-7f);
    ushort4 o0, o1;
    o0.x = f2b((v[0] - mean) * rs); o0.y = f2b((v[1] - mean) * rs);
    o0.z = f2b((v[2] - mean) * rs); o0.w = f2b((v[3] - mean) * rs);
    o1.x = f2b((v[4] - mean) * rs); o1.y = f2b((v[5] - mean) * rs);
    o1.z = f2b((v[6] - mean) * rs); o1.w = f2b((v[7] - mean) * rs);
    unsigned short* o = out + (size_t)row * II + t * 8;
    *(ushort4*)o = o0;
    *(ushort4*)(o + 4) = o1;
}

// ---------------------------------------------------------------------------
// bf16 MFMA GEMM (m97 structure + bijective XCD swizzle + z-batch) —
// used only for the batched posproj at setup.
// ---------------------------------------------------------------------------
template <int OBF>
__global__ __launch_bounds__(256) void k_gemm_bf16(const unsigned short* __restrict__ A, int lda,
                                                   const unsigned short* __restrict__ W, int ldw,
                                                   void* __restrict__ Cv, int ldc,
                                                   int M, int N, int K,
                                                   const float* __restrict__ bias,
                                                   const float* __restrict__ bias2,
                                                   const float* __restrict__ res,
                                                   size_t wz, size_t cz, size_t bz) {
    __shared__ unsigned short As[128 * 32];
    __shared__ unsigned short Ws[128 * 32];
    int zz = blockIdx.z;
    W += (size_t)zz * wz;
    if (bias) bias += (size_t)zz * bz;
    int nwg = gridDim.x * gridDim.y;
    int orig = blockIdx.y * gridDim.x + blockIdx.x;
    int qq = nwg >> 3, rr = nwg & 7;
    int xcd = orig & 7, idx = orig >> 3;
    int wg = (xcd < rr ? xcd * (qq + 1) : rr * (qq + 1) + (xcd - rr) * qq) + idx;
    int bx = wg % gridDim.x, by = wg / gridDim.x;

    const int t = threadIdx.x;
    const int lane = t & 63, wid = t >> 6;
    const int row0 = by * 128, col0 = bx * 128;
    const int wr = (wid >> 1) * 64, wc = (wid & 1) * 64;
    const int rA = lane & 15, kA = (lane >> 4) * 8;

    f32x4 acc[4][4] = {};

    for (int k0 = 0; k0 < K; k0 += 32) {
#pragma unroll
        for (int j = 0; j < 2; ++j) {
            int c = t + j * 256;
            int r = c >> 2, ko = (c & 3) * 8;
            const unsigned short* srcA = A + (size_t)(row0 + r) * lda + k0 + ko;
            const unsigned short* srcB = W + (size_t)(col0 + r) * ldw + k0 + ko;
            unsigned short* dstA = As + (size_t)(j * 256 + wid * 64) * 8;
            unsigned short* dstB = Ws + (size_t)(j * 256 + wid * 64) * 8;
            __builtin_amdgcn_global_load_lds(
                (const __attribute__((address_space(1))) void*)srcA,
                (__attribute__((address_space(3))) void*)dstA, 16, 0, 0);
            __builtin_amdgcn_global_load_lds(
                (const __attribute__((address_space(1))) void*)srcB,
                (__attribute__((address_space(3))) void*)dstB, 16, 0, 0);
        }
        __syncthreads();
        bf16x8 af[4], bfr[4];
#pragma unroll
        for (int m = 0; m < 4; ++m)
            af[m] = *(const bf16x8*)&As[(wr + m * 16 + rA) * 32 + kA];
#pragma unroll
        for (int n = 0; n < 4; ++n)
            bfr[n] = *(const bf16x8*)&Ws[(wc + n * 16 + rA) * 32 + kA];
#pragma unroll
        for (int m = 0; m < 4; ++m)
#pragma unroll
            for (int n = 0; n < 4; ++n)
                acc[m][n] = __builtin_amdgcn_mfma_f32_16x16x32_bf16(af[m], bfr[n], acc[m][n], 0, 0, 0);
        __syncthreads();
    }

    float* Cf = (float*)Cv + (size_t)zz * cz;
    unsigned short* Cb = (unsigned short*)Cv + (size_t)zz * cz;
    const int cl = lane & 15, rg = (lane >> 4) * 4;
#pragma unroll
    for (int n = 0; n < 4; ++n) {
        int gc = col0 + wc + n * 16 + cl;
        float bv = 0.0f;
        if (bias) bv = (bias2 && gc >= 1536) ? bias2[gc - 1536] : bias[gc];
#pragma unroll
        for (int m = 0; m < 4; ++m) {
#pragma unroll
            for (int i = 0; i < 4; ++i) {
                int gr = row0 + wr + m * 16 + rg + i;
                float v = acc[m][n][i] + bv;
                if (OBF) {
                    Cb[(size_t)gr * ldc + gc] = f2b(v);
                } else {
                    if (res) v += res[(size_t)gr * ldc + gc];
                    Cf[(size_t)gr * ldc + gc] = v;
                }
            }
        }
    }
}

// ---------------------------------------------------------------------------
// Skinny bf16 MFMA GEMM for N=768 (Wout, W2), 2-slot pipelined
// ---------------------------------------------------------------------------
#define SKSLOT 16384  /* 16 KB per slot: A 8KB @0, B 8KB @8192 */

__device__ __forceinline__ void sk_stage(const unsigned short* __restrict__ Ab, int lda,
                                         const unsigned short* __restrict__ Wb, int ldw,
                                         unsigned char* slot, int t, int wid) {
    int rit = t >> 3;
    int kb = (t & 7) << 4;
#pragma unroll
    for (int c = 0; c < 2; ++c) {
        int row = c * 32 + rit;
        int gkb = kb ^ ((row & 7) << 4);
        const unsigned short* src = Ab + (size_t)row * lda + (gkb >> 1);
        unsigned char* dst = slot + c * 4096 + wid * 1024;
        __builtin_amdgcn_global_load_lds(
            (const __attribute__((address_space(1))) void*)src,
            (__attribute__((address_space(3))) void*)dst, 16, 0, 0);
    }
#pragma unroll
    for (int c = 0; c < 2; ++c) {
        int row = c * 32 + rit;
        int gkb = kb ^ ((row & 7) << 4);
        const unsigned short* src = Wb + (size_t)row * ldw + (gkb >> 1);
        unsigned char* dst = slot + 8192 + c * 4096 + wid * 1024;
        __builtin_amdgcn_global_load_lds(
            (const __attribute__((address_space(1))) void*)src,
            (__attribute__((address_space(3))) void*)dst, 16, 0, 0);
    }
}

__device__ __forceinline__ void sk_compute(const unsigned char* slot, int wr, int wc,
                                           int rA, int g16, f32x4 acc[2][2]) {
    const unsigned char* Ab = slot;
    const unsigned char* Bb = slot + 8192;
    bf16x8 a[2][2], b[2][2];
#pragma unroll
    for (int m = 0; m < 2; ++m) {
        int row = wr + m * 16 + rA;
        int sw = (row & 7) << 4;
#pragma unroll
        for (int s = 0; s < 2; ++s)
            a[m][s] = *(const bf16x8*)(Ab + row * 128 + ((s * 64 + g16 * 16) ^ sw));
    }
#pragma unroll
    for (int n = 0; n < 2; ++n) {
        int row = wc + n * 16 + rA;
        int sw = (row & 7) << 4;
#pragma unroll
        for (int s = 0; s < 2; ++s)
            b[n][s] = *(const bf16x8*)(Bb + row * 128 + ((s * 64 + g16 * 16) ^ sw));
    }
    __builtin_amdgcn_s_setprio(1);
#pragma unroll
    for (int m = 0; m < 2; ++m)
#pragma unroll
        for (int n = 0; n < 2; ++n) {
            acc[m][n] = __builtin_amdgcn_mfma_f32_16x16x32_bf16(a[m][0], b[n][0], acc[m][n], 0, 0, 0);
            acc[m][n] = __builtin_amdgcn_mfma_f32_16x16x32_bf16(a[m][1], b[n][1], acc[m][n], 0, 0, 0);
        }
    __builtin_amdgcn_s_setprio(0);
}

__global__ __launch_bounds__(256) void k_gemm_skinny(const unsigned short* __restrict__ A, int lda,
                                                     const unsigned short* __restrict__ W, int ldw,
                                                     float* __restrict__ C, int ldc,
                                                     int M, int N, int K,
                                                     const float* __restrict__ bias,
                                                     const float* __restrict__ res) {
    __shared__ unsigned char smem[2 * SKSLOT];
    int nwg = gridDim.x * gridDim.y;
    int orig = blockIdx.y * gridDim.x + blockIdx.x;
    int qq = nwg >> 3, rr = nwg & 7;
    int xcd = orig & 7, idx = orig >> 3;
    int wg = (xcd < rr ? xcd * (qq + 1) : rr * (qq + 1) + (xcd - rr) * qq) + idx;
    int bx = wg % gridDim.x, by = wg / gridDim.x;

    const int t = threadIdx.x;
    const int lane = t & 63, wid = t >> 6;
    const int row0 = by * 64, col0 = bx * 64;
    const int wr = (wid >> 1) * 32, wc = (wid & 1) * 32;
    const int rA = lane & 15, g16 = lane >> 4;
    const unsigned short* Abase = A + (size_t)row0 * lda;
    const unsigned short* Wbase = W + (size_t)col0 * ldw;

    const int nt = K >> 6;
    f32x4 acc[2][2] = {};

    sk_stage(Abase, lda, Wbase, ldw, smem, t, wid);

    for (int tt = 0; tt < nt; ++tt) {
        asm volatile("s_barrier" ::: "memory");
        if (tt + 1 < nt) {
            sk_stage(Abase + (size_t)(tt + 1) * 64, lda, Wbase + (size_t)(tt + 1) * 64,
                     ldw, smem + (size_t)((tt + 1) & 1) * SKSLOT, t, wid);
            asm volatile("s_waitcnt vmcnt(4)" ::: "memory");
        } else {
            asm volatile("s_waitcnt vmcnt(0)" ::: "memory");
        }
        asm volatile("s_barrier" ::: "memory");
        sk_compute(smem + (size_t)(tt & 1) * SKSLOT, wr, wc, rA, g16, acc);
    }

    const int cl = lane & 15, rg = (lane >> 4) * 4;
#pragma unroll
    for (int n = 0; n < 2; ++n) {
        int gc = col0 + wc + n * 16 + cl;
        float bv = bias ? bias[gc] : 0.0f;
#pragma unroll
        for (int m = 0; m < 2; ++m) {
#pragma unroll
            for (int i = 0; i < 4; ++i) {
                int gr = row0 + wr + m * 16 + rg + i;
                float v = acc[m][n][i] + bv;
                if (res) v += res[(size_t)gr * ldc + gc];
                C[(size_t)gr * ldc + gc] = v;
            }
        }
    }
}

// ---------------------------------------------------------------------------
// Mid bf16 MFMA GEMM (qkvg, W1): BM=128, BN=128, BK=64, 512 threads
// (8 waves 2x4, 64x32 out per wave), 2 LDS slots of 32 KB, 2 blocks/CU.
// SCATTER=1 (qkvg): q cols [0,768) -> qT[b,h,s,d], k cols [768,1536) ->
// kT[b,h,s,d] (pure epilogue remap, same values, same 32B-stripe coalescing);
// v,g cols >= 1536 written to Cb normally.
// ---------------------------------------------------------------------------
#define MDSLOT 32768  /* 32 KB per slot: A 16KB @0, B 16KB @16384 */

__device__ __forceinline__ void md_stage(const unsigned short* __restrict__ Ab, int lda,
                                         const unsigned short* __restrict__ Wb, int ldw,
                                         unsigned char* slot, int t, int wid) {
    int rit = t >> 3;             // 0..63
    int kb = (t & 7) << 4;
#pragma unroll
    for (int c = 0; c < 2; ++c) { // A: 128 rows
        int row = c * 64 + rit;
        int gkb = kb ^ ((row & 7) << 4);
        const unsigned short* src = Ab + (size_t)row * lda + (gkb >> 1);
        unsigned char* dst = slot + c * 8192 + wid * 1024;
        __builtin_amdgcn_global_load_lds(
            (const __attribute__((address_space(1))) void*)src,
            (__attribute__((address_space(3))) void*)dst, 16, 0, 0);
    }
#pragma unroll
    for (int c = 0; c < 2; ++c) { // B: 128 rows
        int row = c * 64 + rit;
        int gkb = kb ^ ((row & 7) << 4);
        const unsigned short* src = Wb + (size_t)row * ldw + (gkb >> 1);
        unsigned char* dst = slot + 16384 + c * 8192 + wid * 1024;
        __builtin_amdgcn_global_load_lds(
            (const __attribute__((address_space(1))) void*)src,
            (__attribute__((address_space(3))) void*)dst, 16, 0, 0);
    }
}

__device__ __forceinline__ void md_compute(const unsigned char* slot, int wm, int wn,
                                           int rA, int g16, f32x4 acc[4][2]) {
    const unsigned char* Ab = slot;
    const unsigned char* Bb = slot + 16384;
    bf16x8 a[4][2], b[2][2];
#pragma unroll
    for (int m = 0; m < 4; ++m) {
        int row = wm * 64 + m * 16 + rA;
        int sw = (row & 7) << 4;
#pragma unroll
        for (int s = 0; s < 2; ++s)
            a[m][s] = *(const bf16x8*)(Ab + row * 128 + ((s * 64 + g16 * 16) ^ sw));
    }
#pragma unroll
    for (int n = 0; n < 2; ++n) {
        int row = wn * 32 + n * 16 + rA;
        int sw = (row & 7) << 4;
#pragma unroll
        for (int s = 0; s < 2; ++s)
            b[n][s] = *(const bf16x8*)(Bb + row * 128 + ((s * 64 + g16 * 16) ^ sw));
    }
    __builtin_amdgcn_s_setprio(1);
#pragma unroll
    for (int m = 0; m < 4; ++m)
#pragma unroll
        for (int n = 0; n < 2; ++n) {
            acc[m][n] = __builtin_amdgcn_mfma_f32_16x16x32_bf16(a[m][0], b[n][0], acc[m][n], 0, 0, 0);
            acc[m][n] = __builtin_amdgcn_mfma_f32_16x16x32_bf16(a[m][1], b[n][1], acc[m][n], 0, 0, 0);
        }
    __builtin_amdgcn_s_setprio(0);
}

template <int SCATTER>
__global__ __launch_bounds__(512) void k_gemm_mid(const unsigned short* __restrict__ A, int lda,
                                                  const unsigned short* __restrict__ W,
                                                  const unsigned short* __restrict__ Wb2, int ldw,
                                                  unsigned short* __restrict__ Cb, int ldc,
                                                  int M, int N, int K,
                                                  const float* __restrict__ bias,
                                                  const float* __restrict__ bias2,
                                                  unsigned short* __restrict__ qT,
                                                  unsigned short* __restrict__ kT) {
    extern __shared__ unsigned char smem[];
    int nwg = gridDim.x * gridDim.y;
    int orig = blockIdx.y * gridDim.x + blockIdx.x;
    int qq = nwg >> 3, rr = nwg & 7;
    int xcd = orig & 7, idx = orig >> 3;
    int wg = (xcd < rr ? xcd * (qq + 1) : rr * (qq + 1) + (xcd - rr) * qq) + idx;
    int bx = wg % gridDim.x, by = wg / gridDim.x;

    const int t = threadIdx.x;
    const int lane = t & 63, wid = t >> 6;
    const int wm = wid >> 2, wn = wid & 3;
    const int rA = lane & 15, g16 = lane >> 4;
    const int row0 = by * 128, col0 = bx * 128;
    const unsigned short* Abase = A + (size_t)row0 * lda;
    const unsigned short* Wbase = (Wb2 && col0 >= 1536)
                                      ? Wb2 + (size_t)(col0 - 1536) * ldw
                                      : W + (size_t)col0 * ldw;

    const int nt = K >> 6;
    f32x4 acc[4][2] = {};

    md_stage(Abase, lda, Wbase, ldw, smem, t, wid);

    for (int tt = 0; tt < nt; ++tt) {
        asm volatile("s_barrier" ::: "memory");
        if (tt + 1 < nt) {
            md_stage(Abase + (size_t)(tt + 1) * 64, lda, Wbase + (size_t)(tt + 1) * 64,
                     ldw, smem + (size_t)((tt + 1) & 1) * MDSLOT, t, wid);
            asm volatile("s_waitcnt vmcnt(4)" ::: "memory");
        } else {
            asm volatile("s_waitcnt vmcnt(0)" ::: "memory");
        }
        asm volatile("s_barrier" ::: "memory");
        md_compute(smem + (size_t)(tt & 1) * MDSLOT, wm, wn, rA, g16, acc);
    }

    const int cl = lane & 15, rg = (lane >> 4) * 4;
#pragma unroll
    for (int n = 0; n < 2; ++n) {
        int gc = col0 + wn * 32 + n * 16 + cl;
        float bv = 0.0f;
        if (bias) bv = (bias2 && gc >= 1536) ? bias2[gc - 1536] : bias[gc];
        if (SCATTER && gc < 1536) {
            // q/k scatter: gc -> (h,d); gr -> (s,b). Same f2b values as normal path.
            int isk = gc >= HH;
            unsigned short* dst = isk ? kT : qT;
            int h = (isk ? gc - HH : gc) >> 6;
            int d = gc & 63;
#pragma unroll
            for (int m = 0; m < 4; ++m) {
#pragma unroll
                for (int i = 0; i < 4; ++i) {
                    int gr = row0 + wm * 64 + m * 16 + rg + i;
                    int s = gr >> 3, b = gr & 7;
                    dst[(((size_t)(b * NHH + h)) * SS + s) * DD + d] = f2b(acc[m][n][i] + bv);
                }
            }
        } else {
#pragma unroll
            for (int m = 0; m < 4; ++m) {
#pragma unroll
                for (int i = 0; i < 4; ++i) {
                    int gr = row0 + wm * 64 + m * 16 + rg + i;
                    Cb[(size_t)gr * ldc + gc] = f2b(acc[m][n][i] + bv);
                }
            }
        }
    }
}

// ---------------------------------------------------------------------------
// merged: v-transpose repack (blockIdx.x<8) + cp/pc MFMA (blockIdx.x>=8)
// grid (16, 96). q/k now scattered by gemm_mid; cp/pc A-operand stages from
// qT/kT (per-lane global source remap; LDS layout unchanged).
// ---------------------------------------------------------------------------
__global__ __launch_bounds__(256) void k_repack_cppc(const unsigned short* __restrict__ qkvg,
                                                     const unsigned short* __restrict__ pp,
                                                     const unsigned short* __restrict__ qT,
                                                     const unsigned short* __restrict__ kT,
                                                     unsigned short* __restrict__ vT,
                                                     float* __restrict__ cp,
                                                     float* __restrict__ pc) {
    __shared__ unsigned char shmem[12288];
    int t = threadIdx.x;
    if (blockIdx.x < 8) {
        // ---- v -> vT via LDS transpose (q/k copies removed) ----
        unsigned short (*tile)[72] = (unsigned short(*)[72])shmem;
        int bh = blockIdx.y;
        int b = bh / NHH, h = bh % NHH;
        int s0 = blockIdx.x * 64;
#pragma unroll
        for (int j = 0; j < 4; ++j) {
            int idx = t + j * 256;
            int r = idx >> 4, c4 = idx & 15;
            ushort4 u = *(const ushort4*)(qkvg + ((size_t)(s0 + r) * BB + b) * 3072 + 1536 + h * DD + c4 * 4);
            *(ushort4*)&tile[r][c4 * 4] = u;
        }
        __syncthreads();
#pragma unroll
        for (int j = 0; j < 2; ++j) {
            int idx = t + j * 256;
            int d = idx >> 3, s8 = idx & 7;
            ushort4 a, c;
            a.x = tile[s8 * 8 + 0][d]; a.y = tile[s8 * 8 + 1][d];
            a.z = tile[s8 * 8 + 2][d]; a.w = tile[s8 * 8 + 3][d];
            c.x = tile[s8 * 8 + 4][d]; c.y = tile[s8 * 8 + 5][d];
            c.z = tile[s8 * 8 + 6][d]; c.w = tile[s8 * 8 + 7][d];
            unsigned short* dst = vT + ((size_t)bh * DD + d) * SS + s0 + s8 * 8;
            *(ushort4*)dst = a; *(ushort4*)(dst + 4) = c;
        }
    } else {
        int cid = (blockIdx.x - 8) * 96 + blockIdx.y;
        int z = cid >= 384;
        int rem = cid - (z ? 384 : 0);
        int h = rem >> 5;
        int mt = rem & 31;
        int toff = z ? 0 : HH;
        float* out = z ? pc : cp;
        const unsigned short* srcbase = z ? kT : qT;  // k rows for pc, q rows for cp
        unsigned short* As = (unsigned short*)shmem;
        unsigned short* Bs = (unsigned short*)(shmem + 8192);
        const int lane = t & 63, wid = t >> 6;
        const int rA = lane & 15, kA = (lane >> 4) * 8;

        f32x4 acc[2][4] = {};

        for (int k0 = 0; k0 < 64; k0 += 32) {
#pragma unroll
            for (int j = 0; j < 2; ++j) {
                int c = t + j * 256;
                int r = c >> 2, ko = (c & 3) * 8;
                int row = mt * 128 + r;              // row = s*B + b
                int s = row >> 3, b = row & 7;
                const unsigned short* srcA =
                    srcbase + (((size_t)(b * NHH + h)) * SS + s) * DD + k0 + ko;
                unsigned short* dstA = As + (size_t)(j * 256 + wid * 64) * 8;
                __builtin_amdgcn_global_load_lds(
                    (const __attribute__((address_space(1))) void*)srcA,
                    (__attribute__((address_space(3))) void*)dstA, 16, 0, 0);
            }
            {
                int r = t >> 2, ko = (t & 3) * 8;
                const unsigned short* srcB = pp + (size_t)r * 1536 + toff + h * DD + k0 + ko;
                unsigned short* dstB = Bs + (size_t)(wid * 64) * 8;
                __builtin_amdgcn_global_load_lds(
                    (const __attribute__((address_space(1))) void*)srcB,
                    (__attribute__((address_space(3))) void*)dstB, 16, 0, 0);
            }
            __syncthreads();
            bf16x8 af[2], bfr[4];
#pragma unroll
            for (int m = 0; m < 2; ++m)
                af[m] = *(const bf16x8*)&As[(wid * 32 + m * 16 + rA) * 32 + kA];
#pragma unroll
            for (int n = 0; n < 4; ++n)
                bfr[n] = *(const bf16x8*)&Bs[(n * 16 + rA) * 32 + kA];
#pragma unroll
            for (int m = 0; m < 2; ++m)
#pragma unroll
                for (int n = 0; n < 4; ++n)
                    acc[m][n] = __builtin_amdgcn_mfma_f32_16x16x32_bf16(af[m], bfr[n], acc[m][n], 0, 0, 0);
            __syncthreads();
        }

        const int cl = lane & 15, rg = (lane >> 4) * 4;
#pragma unroll
        for (int m = 0; m < 2; ++m)
#pragma unroll
            for (int n = 0; n < 4; ++n) {
                int gc = n * 16 + cl;
                if (gc < 63) {
#pragma unroll
                    for (int i = 0; i < 4; ++i) {
                        int gr = mt * 128 + wid * 32 + m * 16 + rg + i;
                        int sIdx = gr >> 3, bIdx = gr & 7;
                        out[(((size_t)(bIdx * NHH + h)) * SS + sIdx) * 63 + gc] = acc[m][n][i];
                    }
                }
            }
    }
}

// ---------------------------------------------------------------------------
// fused disentangled flash attention v2 (round-10/13 proven config)
// ---------------------------------------------------------------------------
__global__ __launch_bounds__(256) void k_attn_fused(
    const unsigned short* __restrict__ qT, const unsigned short* __restrict__ kT,
    const unsigned short* __restrict__ vT, const float* __restrict__ cp,
    const float* __restrict__ pc, const int* __restrict__ bucket,
    const int* __restrict__ mask, float* __restrict__ ctxr) {
    __shared__ float cps[64 * 63];
    __shared__ float pcs[64 * 63];
    __shared__ unsigned short pb_all[4][16 * 72];
    __shared__ int btab[1023];
    int t = threadIdx.x;
    int lane = t & 63, wid = t >> 6;
    int bh = blockIdx.y;
    int b = bh / NHH, h = bh % NHH;
    int qb0 = blockIdx.x * 64;
    int q0 = qb0 + wid * 16;
    int rA = lane & 15, g = lane >> 4, kA = g * 8;
    unsigned short* pb = pb_all[wid];
    const unsigned short* qTb = qT + (size_t)bh * SS * DD;
    const unsigned short* kTb = kT + (size_t)bh * SS * DD;
    const unsigned short* vTb = vT + (size_t)bh * DD * SS;
    const float* cpb = cp + (size_t)bh * SS * 63 + (size_t)qb0 * 63;
    const float* pcb = pc + (size_t)bh * SS * 63;
    const int* mkb = mask + b * SS;

    for (int i = t; i < 1023; i += 256) btab[i] = bucket[i];
    for (int i = t; i < 1008; i += 256) ((float4*)cps)[i] = ((const float4*)cpb)[i];

    bf16x8 aq[2];
#pragma unroll
    for (int dc = 0; dc < 2; ++dc)
        aq[dc] = *(const bf16x8*)&qTb[(size_t)(q0 + rA) * DD + dc * 32 + kA];

    f32x4 o[4] = {};
    float mrow[4], lrow[4];
#pragma unroll
    for (int i = 0; i < 4; ++i) { mrow[i] = -INFINITY; lrow[i] = 0.f; }

    for (int kt = 0; kt < 8; ++kt) {
        int k0 = kt * 64;
        __syncthreads();
        {
            const float4* src = (const float4*)(pcb + (size_t)k0 * 63);
            for (int i = t; i < 1008; i += 256) ((float4*)pcs)[i] = src[i];
        }
        f32x4 sa[4] = {};
#pragma unroll
        for (int n = 0; n < 4; ++n) {
            bf16x8 bk0 = *(const bf16x8*)&kTb[(size_t)(k0 + n * 16 + rA) * DD + kA];
            bf16x8 bk1 = *(const bf16x8*)&kTb[(size_t)(k0 + n * 16 + rA) * DD + 32 + kA];
            sa[n] = __builtin_amdgcn_mfma_f32_16x16x32_bf16(aq[0], bk0, sa[n], 0, 0, 0);
            sa[n] = __builtin_amdgcn_mfma_f32_16x16x32_bf16(aq[1], bk1, sa[n], 0, 0, 0);
        }
        int mk[4];
#pragma unroll
        for (int n = 0; n < 4; ++n) mk[n] = mkb[k0 + n * 16 + rA];
        __syncthreads();

        float pv[4][4];
#pragma unroll
        for (int i = 0; i < 4; ++i) {
            int qr = wid * 16 + g * 4 + i;
            int q = qb0 + qr;
            float sv[4];
            float tmax = -INFINITY;
#pragma unroll
            for (int n = 0; n < 4; ++n) {
                int kr = n * 16 + rA;
                int id = btab[q - (k0 + kr) + 511];
                float v = (sa[n][i] + cps[qr * 63 + id] + pcs[kr * 63 + id]) * SCALE_F;
                v = mk[n] ? -1e9f : v;
                sv[n] = v;
                tmax = fmaxf(tmax, v);
            }
            tmax = fmaxf(tmax, __shfl_xor(tmax, 1, 16));
            tmax = fmaxf(tmax, __shfl_xor(tmax, 2, 16));
            tmax = fmaxf(tmax, __shfl_xor(tmax, 4, 16));
            tmax = fmaxf(tmax, __shfl_xor(tmax, 8, 16));
            float mold = mrow[i];
            float mnew = fmaxf(mold, tmax);
            float ls = 0.f;
#pragma unroll
            for (int n = 0; n < 4; ++n) {
                float p = __expf(sv[n] - mnew);
                pv[n][i] = p;
                ls += p;
            }
            ls += __shfl_xor(ls, 1, 16);
            ls += __shfl_xor(ls, 2, 16);
            ls += __shfl_xor(ls, 4, 16);
            ls += __shfl_xor(ls, 8, 16);
            if (mnew > mold) {
                float alpha = __expf(mold - mnew);
                lrow[i] = lrow[i] * alpha + ls;
                mrow[i] = mnew;
#pragma unroll
                for (int n = 0; n < 4; ++n) o[n][i] *= alpha;
            } else {
                lrow[i] += ls;
            }
        }
#pragma unroll
        for (int n = 0; n < 4; ++n)
#pragma unroll
            for (int i = 0; i < 4; ++i)
                pb[(g * 4 + i) * 72 + n * 16 + rA] = f2b(pv[n][i]);
        bf16x8 ap[2];
#pragma unroll
        for (int kc = 0; kc < 2; ++kc)
            ap[kc] = *(const bf16x8*)&pb[rA * 72 + kc * 32 + kA];
#pragma unroll
        for (int n = 0; n < 4; ++n) {
            bf16x8 bv0 = *(const bf16x8*)&vTb[(size_t)(n * 16 + rA) * SS + k0 + kA];
            bf16x8 bv1 = *(const bf16x8*)&vTb[(size_t)(n * 16 + rA) * SS + k0 + 32 + kA];
            o[n] = __builtin_amdgcn_mfma_f32_16x16x32_bf16(ap[0], bv0, o[n], 0, 0, 0);
            o[n] = __builtin_amdgcn_mfma_f32_16x16x32_bf16(ap[1], bv1, o[n], 0, 0, 0);
        }
    }
#pragma unroll
    for (int i = 0; i < 4; ++i) {
        int q = q0 + g * 4 + i;
        float inv = 1.0f / lrow[i];
#pragma unroll
        for (int n = 0; n < 4; ++n)
            ctxr[((size_t)q * BB + b) * HH + h * DD + n * 16 + rA] = o[n][i] * inv;
    }
}

// ---------------------------------------------------------------------------
// host launcher
// ---------------------------------------------------------------------------
extern "C" void kernel_launch(void* const* d_in, const int* in_sizes, int n_in,
                              void* d_out, int out_size, void* d_ws, size_t ws_size,
                              hipStream_t stream) {
    static int attr_done = 0;
    if (!attr_done) {
        hipFuncSetAttribute((const void*)&k_gemm_mid<0>,
                            hipFuncAttributeMaxDynamicSharedMemorySize, 2 * MDSLOT);
        hipFuncSetAttribute((const void*)&k_gemm_mid<1>,
                            hipFuncAttributeMaxDynamicSharedMemorySize, 2 * MDSLOT);
        attr_done = 1;
    }

    const int* ids = (const int*)d_in[0];
    const unsigned char* maskraw = (const unsigned char*)d_in[1];
    const float* word_emb = (const float*)d_in[2];
    const float* rel_emb = (const float*)d_in[3];
    const float* rel_g = (const float*)d_in[4];
    const float* rel_b = (const float*)d_in[5];
    const float* Wqk = (const float*)d_in[6];
    const float* bqk = (const float*)d_in[7];
    const float* Wvg = (const float*)d_in[8];
    const float* bvg = (const float*)d_in[9];
    const float* Wout = (const float*)d_in[10];
    const float* bout = (const float*)d_in[11];
    const float* W1 = (const float*)d_in[12];
    const float* W2 = (const float*)d_in[13];

    const size_t N_X = (size_t)SS * BB * HH;
    const size_t N_CP = (size_t)SS * BB * NHH * 63;
    const size_t N_H2 = (size_t)SS * BB * II;
    const size_t N_WQK = (size_t)2 * HH * HH;
    const size_t N_WOUT = (size_t)HH * HH;
    const size_t N_W1 = (size_t)2 * II * HH;
    const size_t N_W2 = (size_t)HH * II;
    const size_t N_HD = (size_t)BB * NHH * SS * DD;
    const size_t N_QKVG = (size_t)SS * BB * 3072;
    const size_t N_FFH = (size_t)SS * BB * 4096;
    const size_t N_PP = (size_t)128 * 1536;

    float* ws = (float*)d_ws;
    float* x = ws;
    float* ctxr = x + N_X;
    float* cp = ctxr + N_X;
    float* pc = cp + N_CP;
    unsigned short* us = (unsigned short*)(pc + N_CP);
    unsigned short* qkvg = us;
    unsigned short* hs_bf = qkvg + N_QKVG;
    unsigned short* ctx_bf = hs_bf + N_X;
    unsigned short* h2_bf = ctx_bf + N_X;
    unsigned short* ffh = h2_bf + N_H2;
    unsigned short* wqk_all = ffh + N_FFH;
    unsigned short* wvg_bf = wqk_all + 12 * N_WQK;
    unsigned short* wout_bf = wvg_bf + N_WQK;
    unsigned short* w1_bf = wout_bf + N_WOUT;
    unsigned short* w2_bf = w1_bf + N_W1;
    unsigned short* ppall = w2_bf + N_W2;
    unsigned short* rel_bf = ppall + 12 * N_PP;
    unsigned short* qT = rel_bf + 128 * HH;
    unsigned short* kT = qT + N_HD;
    unsigned short* vT = kT + N_HD;
    int* bucket = (int*)(vT + N_HD);
    int* maski = bucket + 1024;

    size_t need_bytes = ((size_t)(maski + BB * SS) - (size_t)d_ws);
    if (ws_size < need_bytes) return;  // ~205 MB required

    // ---- setup ----
    k_decode_mask<<<1, 256, 0, stream>>>(maskraw, maski, BB * SS);
    k_bucket<<<4, 256, 0, stream>>>(bucket);
    k_embed_ln<<<SS * BB, 256, 0, stream>>>(ids, word_emb, x);
    k_rel_ln_bf<<<128, 256, 0, stream>>>(rel_emb, rel_g, rel_b, rel_bf);
    k_f2b<<<(int)((12 * N_WQK / 8 + 255) / 256), 256, 0, stream>>>(Wqk, wqk_all,
                                                                   (int)(12 * N_WQK / 8));
    {
        dim3 gpp(1536 / 128, 1, 12);
        k_gemm_bf16<1><<<gpp, 256, 0, stream>>>(rel_bf, HH, wqk_all, HH, ppall, 1536,
                                                128, 1536, HH, bqk, nullptr, nullptr,
                                                N_WQK, N_PP, 2 * HH);
    }

    for (int l = 0; l < LL; ++l) {
        const unsigned short* wqk_l = wqk_all + (size_t)l * N_WQK;
        const float* bqk_l = bqk + (size_t)l * 2 * HH;
        const float* Wvg_l = Wvg + (size_t)l * N_WQK;
        const float* bvg_l = bvg + (size_t)l * 2 * HH;
        const float* Wout_l = Wout + (size_t)l * N_WOUT;
        const float* bout_l = bout + (size_t)l * HH;
        const float* W1_l = W1 + (size_t)l * N_W1;
        const float* W2_l = W2 + (size_t)l * N_W2;

        // ---- attention ----
        k_f2b_ln<<<3169 + SS * BB, 256, 0, stream>>>(Wvg_l, Wout_l, W1_l, W2_l, wvg_bf,
                                                     x, hs_bf);
        {
            dim3 g(3072 / 128, SS * BB / 128);
            k_gemm_mid<1><<<g, 512, 2 * MDSLOT, stream>>>(hs_bf, HH, wqk_l, wvg_bf, HH,
                                                          qkvg, 3072, SS * BB, 3072, HH,
                                                          bqk_l, bvg_l, qT, kT);
        }
        k_repack_cppc<<<dim3(16, 96), 256, 0, stream>>>(qkvg, ppall + (size_t)l * N_PP,
                                                        qT, kT, vT, cp, pc);
        k_attn_fused<<<dim3(SS / 64, BB * NHH), 256, 0, stream>>>(qT, kT, vT, cp, pc,
                                                                  bucket, maski, ctxr);
        k_gated_ln<<<SS * BB, 256, 0, stream>>>(ctxr, qkvg, ctx_bf);
        k_gemm_skinny<<<dim3(HH / 64, SS * BB / 64), 256, 0, stream>>>(
            ctx_bf, HH, wout_bf, HH, x, HH, SS * BB, HH, HH, bout_l, x);

        // ---- GeGLU FFN ----
        k_ln_bf<<<SS * BB, 256, 0, stream>>>(x, hs_bf);
        {
            dim3 g(4096 / 128, SS * BB / 128);
            k_gemm_mid<0><<<g, 512, 2 * MDSLOT, stream>>>(hs_bf, HH, w1_bf, nullptr, HH,
                                                          ffh, 4096, SS * BB, 4096, HH,
                                                          nullptr, nullptr, nullptr, nullptr);
        }
        k_ffn_ln<<<SS * BB, 256, 0, stream>>>(ffh, h2_bf);
        // last layer writes the residual-added output straight into d_out
        float* outC = (l == LL - 1) ? (float*)d_out : x;
        k_gemm_skinny<<<dim3(HH / 64, SS * BB / 64), 256, 0, stream>>>(
            h2_bf, II, w2_bf, II, outC, HH, SS * BB, HH, II, nullptr, x);
    }
}

// Round 16
// 2630.238 us; speedup vs baseline: 1.0752x; 1.0033x over previous
//
#include <hip/hip_runtime.h>
#include <math.h>

#define SS 512
#define BB 8
#define NHH 12
#define DD 64
#define HH 768
#define II 2048
#define LL 12
#define SCALE_F 0.07216878364870323f  /* 1/sqrt(3*64) */

typedef __attribute__((ext_vector_type(8))) short bf16x8;
typedef __attribute__((ext_vector_type(4))) float f32x4;

// f32 -> bf16 (RNE, finite values)
__device__ __forceinline__ unsigned short f2b(float f) {
    union { float f; unsigned int u; } x; x.f = f;
    unsigned int r = x.u + 0x7fffu + ((x.u >> 16) & 1u);
    return (unsigned short)(r >> 16);
}
__device__ __forceinline__ float b2f(unsigned short u) {
    union { unsigned int u; float f; } x; x.u = ((unsigned int)u) << 16;
    return x.f;
}

// ---------------------------------------------------------------------------
// block reduction helpers (blockDim.x == 256)
// ---------------------------------------------------------------------------
__device__ __forceinline__ float2 blockReduceSum2(float a, float b) {
    __shared__ float2 sm[4];
    __shared__ float2 bc;
#pragma unroll
    for (int o = 32; o > 0; o >>= 1) {
        a += __shfl_down(a, o);
        b += __shfl_down(b, o);
    }
    int t = threadIdx.x;
    if ((t & 63) == 0) sm[t >> 6] = make_float2(a, b);
    __syncthreads();
    if (t == 0) {
        float xa = sm[0].x + sm[1].x + sm[2].x + sm[3].x;
        float xb = sm[0].y + sm[1].y + sm[2].y + sm[3].y;
        bc = make_float2(xa, xb);
    }
    __syncthreads();
    return bc;
}

__device__ __forceinline__ float gelu_erf(float v) {
    return 0.5f * v * (1.0f + erff(v * 0.70710678118654752f));
}
__device__ __forceinline__ float gelu_tanh(float v) {
    const float c = 0.7978845608028654f;
    return 0.5f * v * (1.0f + tanhf(c * (v + 0.044715f * v * v * v)));
}

// ---------------------------------------------------------------------------
// mask decode: handle bool-as-u8 or bool-as-int32 layouts
// ---------------------------------------------------------------------------
__global__ __launch_bounds__(256) void k_decode_mask(const unsigned char* __restrict__ raw,
                                                     int* __restrict__ mask, int n) {
    __shared__ int s_any;
    if (threadIdx.x == 0) s_any = 0;
    __syncthreads();
    int local = 0;
    for (int i = threadIdx.x; i < n; i += blockDim.x)
        if ((i & 3) && raw[i]) local = 1;
    if (local) atomicOr(&s_any, 1);
    __syncthreads();
    bool isU8 = (s_any != 0);
    const int* as_int = (const int*)raw;
    for (int i = threadIdx.x; i < n; i += blockDim.x)
        mask[i] = isU8 ? (raw[i] != 0) : (as_int[i] != 0);
}

// ---------------------------------------------------------------------------
// DeBERTa log-bucket table: rel in [-511,511] -> idx in [0,62]
// ---------------------------------------------------------------------------
__global__ __launch_bounds__(256) void k_bucket(int* __restrict__ tab) {
    int i = blockIdx.x * 256 + threadIdx.x;
    if (i >= 1023) return;
    int rel = i - 511;
    int a = rel < 0 ? -rel : rel;
    int abs_pos = (a < 16) ? 15 : (a < 511 ? a : 511);
    int bucket;
    if (abs_pos <= 16) {
        bucket = rel;
    } else {
        double lp = ceil(log((double)abs_pos / 16.0) / log(511.0 / 16.0) * 15.0);
        int l = (int)lp + 16;
        bucket = (rel > 0) ? l : -l;
    }
    int idx = bucket + 31;
    if (idx < 0) idx = 0;
    if (idx > 62) idx = 62;
    tab[i] = idx;
}

// ---------------------------------------------------------------------------
// generic f32 -> bf16 bulk conversion (8 elems/thread)
// ---------------------------------------------------------------------------
__global__ __launch_bounds__(256) void k_f2b(const float* __restrict__ in,
                                             unsigned short* __restrict__ out, int n8) {
    int i = blockIdx.x * 256 + threadIdx.x;
    if (i >= n8) return;
    float4 a = ((const float4*)in)[2 * (size_t)i];
    float4 b = ((const float4*)in)[2 * (size_t)i + 1];
    ushort4 lo, hi;
    lo.x = f2b(a.x); lo.y = f2b(a.y); lo.z = f2b(a.z); lo.w = f2b(a.w);
    hi.x = f2b(b.x); hi.y = f2b(b.y); hi.z = f2b(b.z); hi.w = f2b(b.w);
    ((ushort4*)out)[2 * (size_t)i] = lo;
    ((ushort4*)out)[2 * (size_t)i + 1] = hi;
}

// ---------------------------------------------------------------------------
// merged: per-layer weight conversion (blocks 0..3168) + LN of x (blocks 3169..7264)
// ---------------------------------------------------------------------------
__global__ __launch_bounds__(256) void k_f2b_ln(const float* __restrict__ wvg,
                                                const float* __restrict__ wout,
                                                const float* __restrict__ w1,
                                                const float* __restrict__ w2,
                                                unsigned short* __restrict__ wbf,
                                                const float* __restrict__ x,
                                                unsigned short* __restrict__ hs) {
    int bid = blockIdx.x;
    int t = threadIdx.x;
    if (bid < 3169) {
        int i = bid * 256 + t;
        if (i >= 811008) return;
        const float* src;
        int off;
        if (i < 221184) {
            if (i < 147456) { src = wvg;  off = i; }
            else            { src = wout; off = i - 147456; }
        } else if (i < 614400) { src = w1; off = i - 221184; }
        else                   { src = w2; off = i - 614400; }
        float4 a = ((const float4*)src)[2 * (size_t)off];
        float4 b = ((const float4*)src)[2 * (size_t)off + 1];
        ushort4 lo, hi;
        lo.x = f2b(a.x); lo.y = f2b(a.y); lo.z = f2b(a.z); lo.w = f2b(a.w);
        hi.x = f2b(b.x); hi.y = f2b(b.y); hi.z = f2b(b.z); hi.w = f2b(b.w);
        ((ushort4*)wbf)[2 * (size_t)i] = lo;
        ((ushort4*)wbf)[2 * (size_t)i + 1] = hi;
    } else {
        int row = bid - 3169;
        const float* r = x + (size_t)row * HH;
        float v0 = r[t], v1 = r[t + 256], v2 = r[t + 512];
        float s = v0 + v1 + v2;
        float ss = v0 * v0 + v1 * v1 + v2 * v2;
        float2 r2 = blockReduceSum2(s, ss);
        float mean = r2.x * (1.0f / HH);
        float var = r2.y * (1.0f / HH) - mean * mean;
        float rs = rsqrtf(var + 1e-7f);
        unsigned short* o = hs + (size_t)row * HH;
        o[t] = f2b((v0 - mean) * rs);
        o[t + 256] = f2b((v1 - mean) * rs);
        o[t + 512] = f2b((v2 - mean) * rs);
    }
}

// ---------------------------------------------------------------------------
// LayerNorm family; EPS = 1e-7, biased variance
// ---------------------------------------------------------------------------
__global__ __launch_bounds__(256) void k_ln_bf(const float* __restrict__ in,
                                               unsigned short* __restrict__ out) {
    int row = blockIdx.x, t = threadIdx.x;
    const float* r = in + (size_t)row * HH;
    float v0 = r[t], v1 = r[t + 256], v2 = r[t + 512];
    float s = v0 + v1 + v2;
    float ss = v0 * v0 + v1 * v1 + v2 * v2;
    float2 r2 = blockReduceSum2(s, ss);
    float mean = r2.x * (1.0f / HH);
    float var = r2.y * (1.0f / HH) - mean * mean;
    float rs = rsqrtf(var + 1e-7f);
    unsigned short* o = out + (size_t)row * HH;
    o[t] = f2b((v0 - mean) * rs);
    o[t + 256] = f2b((v1 - mean) * rs);
    o[t + 512] = f2b((v2 - mean) * rs);
}

__global__ __launch_bounds__(256) void k_embed_ln(const int* __restrict__ ids,
                                                  const float* __restrict__ emb,
                                                  float* __restrict__ out) {
    int row = blockIdx.x, t = threadIdx.x;
    const float* r = emb + (size_t)ids[row] * HH;
    float v0 = r[t], v1 = r[t + 256], v2 = r[t + 512];
    float s = v0 + v1 + v2;
    float ss = v0 * v0 + v1 * v1 + v2 * v2;
    float2 r2 = blockReduceSum2(s, ss);
    float mean = r2.x * (1.0f / HH);
    float var = r2.y * (1.0f / HH) - mean * mean;
    float rs = rsqrtf(var + 1e-7f);
    float* o = out + (size_t)row * HH;
    o[t] = (v0 - mean) * rs;
    o[t + 256] = (v1 - mean) * rs;
    o[t + 512] = (v2 - mean) * rs;
}

// rel LN -> bf16, padded to 128 rows (rows 63..127 zero)
__global__ __launch_bounds__(256) void k_rel_ln_bf(const float* __restrict__ rel_emb,
                                                   const float* __restrict__ g,
                                                   const float* __restrict__ b,
                                                   unsigned short* __restrict__ out) {
    int row = blockIdx.x, t = threadIdx.x;
    unsigned short* o = out + (size_t)row * HH;
    if (row >= 63) {
        o[t] = 0; o[t + 256] = 0; o[t + 512] = 0;
        return;
    }
    const float* r = rel_emb + (size_t)row * HH;
    float v0 = r[t], v1 = r[t + 256], v2 = r[t + 512];
    float s = v0 + v1 + v2;
    float ss = v0 * v0 + v1 * v1 + v2 * v2;
    float2 r2 = blockReduceSum2(s, ss);
    float mean = r2.x * (1.0f / HH);
    float var = r2.y * (1.0f / HH) - mean * mean;
    float rs = rsqrtf(var + 1e-7f);
    o[t] = f2b((v0 - mean) * rs * g[t] + b[t]);
    o[t + 256] = f2b((v1 - mean) * rs * g[t + 256] + b[t + 256]);
    o[t + 512] = f2b((v2 - mean) * rs * g[t + 512] + b[t + 512]);
}

// ctx_bf = bf16(LN(ctxr * gelu_exact(g))), g = qkvg[..., 2304:3072] (bf16)
__global__ __launch_bounds__(256) void k_gated_ln(const float* __restrict__ ctxr,
                                                  const unsigned short* __restrict__ qkvg,
                                                  unsigned short* __restrict__ out) {
    int row = blockIdx.x, t = threadIdx.x;
    const float* cr = ctxr + (size_t)row * HH;
    const unsigned short* gr = qkvg + (size_t)row * 3072 + 2304;
    float v[3];
    float s = 0.f, ss = 0.f;
#pragma unroll
    for (int e = 0; e < 3; ++e) {
        int i = t + e * 256;
        float x = cr[i] * gelu_erf(b2f(gr[i]));
        v[e] = x;
        s += x; ss += x * x;
    }
    float2 r2 = blockReduceSum2(s, ss);
    float mean = r2.x * (1.0f / HH);
    float var = r2.y * (1.0f / HH) - mean * mean;
    float rs = rsqrtf(var + 1e-7f);
    unsigned short* o = out + (size_t)row * HH;
#pragma unroll
    for (int e = 0; e < 3; ++e) o[t + e * 256] = f2b((v[e] - mean) * rs);
}

// h2_bf = bf16(LN(ffh[:, :I] * gelu_tanh(ffh[:, I:])))  (ffh bf16 [row][4096])
__global__ __launch_bounds__(256) void k_ffn_ln(const unsigned short* __restrict__ ffh,
                                                unsigned short* __restrict__ out) {
    int row = blockIdx.x, t = threadIdx.x;
    const unsigned short* ar = ffh + (size_t)row * 4096 + t * 8;
    const unsigned short* gr = ar + II;
    ushort4 a0 = *(const ushort4*)ar;
    ushort4 a1 = *(const ushort4*)(ar + 4);
    ushort4 g0 = *(const ushort4*)gr;
    ushort4 g1 = *(const ushort4*)(gr + 4);
    float av[8] = {b2f(a0.x), b2f(a0.y), b2f(a0.z), b2f(a0.w),
                   b2f(a1.x), b2f(a1.y), b2f(a1.z), b2f(a1.w)};
    float gv[8] = {b2f(g0.x), b2f(g0.y), b2f(g0.z), b2f(g0.w),
                   b2f(g1.x), b2f(g1.y), b2f(g1.z), b2f(g1.w)};
    float v[8];
    float s = 0.f, ss = 0.f;
#pragma unroll
    for (int e = 0; e < 8; ++e) {
        float x = av[e] * gelu_tanh(gv[e]);
        v[e] = x;
        s += x; ss += x * x;
    }
    float2 r2 = blockReduceSum2(s, ss);
    float mean = r2.x * (1.0f / II);
    float var = r2.y * (1.0f / II) - mean * mean;
    float rs = rsqrtf(var + 1e-7f);
    ushort4 o0, o1;
    o0.x = f2b((v[0] - mean) * rs); o0.y = f2b((v[1] - mean) * rs);
    o0.z = f2b((v[2] - mean) * rs); o0.w = f2b((v[3] - mean) * rs);
    o1.x = f2b((v[4] - mean) * rs); o1.y = f2b((v[5] - mean) * rs);
    o1.z = f2b((v[6] - mean) * rs); o1.w = f2b((v[7] - mean) * rs);
    unsigned short* o = out + (size_t)row * II + t * 8;
    *(ushort4*)o = o0;
    *(ushort4*)(o + 4) = o1;
}

// ---------------------------------------------------------------------------
// bf16 MFMA GEMM (m97 structure + bijective XCD swizzle + z-batch) —
// used only for the batched posproj at setup.
// ---------------------------------------------------------------------------
template <int OBF>
__global__ __launch_bounds__(256) void k_gemm_bf16(const unsigned short* __restrict__ A, int lda,
                                                   const unsigned short* __restrict__ W, int ldw,
                                                   void* __restrict__ Cv, int ldc,
                                                   int M, int N, int K,
                                                   const float* __restrict__ bias,
                                                   const float* __restrict__ bias2,
                                                   const float* __restrict__ res,
                                                   size_t wz, size_t cz, size_t bz) {
    __shared__ unsigned short As[128 * 32];
    __shared__ unsigned short Ws[128 * 32];
    int zz = blockIdx.z;
    W += (size_t)zz * wz;
    if (bias) bias += (size_t)zz * bz;
    int nwg = gridDim.x * gridDim.y;
    int orig = blockIdx.y * gridDim.x + blockIdx.x;
    int qq = nwg >> 3, rr = nwg & 7;
    int xcd = orig & 7, idx = orig >> 3;
    int wg = (xcd < rr ? xcd * (qq + 1) : rr * (qq + 1) + (xcd - rr) * qq) + idx;
    int bx = wg % gridDim.x, by = wg / gridDim.x;

    const int t = threadIdx.x;
    const int lane = t & 63, wid = t >> 6;
    const int row0 = by * 128, col0 = bx * 128;
    const int wr = (wid >> 1) * 64, wc = (wid & 1) * 64;
    const int rA = lane & 15, kA = (lane >> 4) * 8;

    f32x4 acc[4][4] = {};

    for (int k0 = 0; k0 < K; k0 += 32) {
#pragma unroll
        for (int j = 0; j < 2; ++j) {
            int c = t + j * 256;
            int r = c >> 2, ko = (c & 3) * 8;
            const unsigned short* srcA = A + (size_t)(row0 + r) * lda + k0 + ko;
            const unsigned short* srcB = W + (size_t)(col0 + r) * ldw + k0 + ko;
            unsigned short* dstA = As + (size_t)(j * 256 + wid * 64) * 8;
            unsigned short* dstB = Ws + (size_t)(j * 256 + wid * 64) * 8;
            __builtin_amdgcn_global_load_lds(
                (const __attribute__((address_space(1))) void*)srcA,
                (__attribute__((address_space(3))) void*)dstA, 16, 0, 0);
            __builtin_amdgcn_global_load_lds(
                (const __attribute__((address_space(1))) void*)srcB,
                (__attribute__((address_space(3))) void*)dstB, 16, 0, 0);
        }
        __syncthreads();
        bf16x8 af[4], bfr[4];
#pragma unroll
        for (int m = 0; m < 4; ++m)
            af[m] = *(const bf16x8*)&As[(wr + m * 16 + rA) * 32 + kA];
#pragma unroll
        for (int n = 0; n < 4; ++n)
            bfr[n] = *(const bf16x8*)&Ws[(wc + n * 16 + rA) * 32 + kA];
#pragma unroll
        for (int m = 0; m < 4; ++m)
#pragma unroll
            for (int n = 0; n < 4; ++n)
                acc[m][n] = __builtin_amdgcn_mfma_f32_16x16x32_bf16(af[m], bfr[n], acc[m][n], 0, 0, 0);
        __syncthreads();
    }

    float* Cf = (float*)Cv + (size_t)zz * cz;
    unsigned short* Cb = (unsigned short*)Cv + (size_t)zz * cz;
    const int cl = lane & 15, rg = (lane >> 4) * 4;
#pragma unroll
    for (int n = 0; n < 4; ++n) {
        int gc = col0 + wc + n * 16 + cl;
        float bv = 0.0f;
        if (bias) bv = (bias2 && gc >= 1536) ? bias2[gc - 1536] : bias[gc];
#pragma unroll
        for (int m = 0; m < 4; ++m) {
#pragma unroll
            for (int i = 0; i < 4; ++i) {
                int gr = row0 + wr + m * 16 + rg + i;
                float v = acc[m][n][i] + bv;
                if (OBF) {
                    Cb[(size_t)gr * ldc + gc] = f2b(v);
                } else {
                    if (res) v += res[(size_t)gr * ldc + gc];
                    Cf[(size_t)gr * ldc + gc] = v;
                }
            }
        }
    }
}

// ---------------------------------------------------------------------------
// Skinny bf16 MFMA GEMM for N=768 (Wout, W2), 2-slot pipelined
// ---------------------------------------------------------------------------
#define SKSLOT 16384  /* 16 KB per slot: A 8KB @0, B 8KB @8192 */

__device__ __forceinline__ void sk_stage(const unsigned short* __restrict__ Ab, int lda,
                                         const unsigned short* __restrict__ Wb, int ldw,
                                         unsigned char* slot, int t, int wid) {
    int rit = t >> 3;
    int kb = (t & 7) << 4;
#pragma unroll
    for (int c = 0; c < 2; ++c) {
        int row = c * 32 + rit;
        int gkb = kb ^ ((row & 7) << 4);
        const unsigned short* src = Ab + (size_t)row * lda + (gkb >> 1);
        unsigned char* dst = slot + c * 4096 + wid * 1024;
        __builtin_amdgcn_global_load_lds(
            (const __attribute__((address_space(1))) void*)src,
            (__attribute__((address_space(3))) void*)dst, 16, 0, 0);
    }
#pragma unroll
    for (int c = 0; c < 2; ++c) {
        int row = c * 32 + rit;
        int gkb = kb ^ ((row & 7) << 4);
        const unsigned short* src = Wb + (size_t)row * ldw + (gkb >> 1);
        unsigned char* dst = slot + 8192 + c * 4096 + wid * 1024;
        __builtin_amdgcn_global_load_lds(
            (const __attribute__((address_space(1))) void*)src,
            (__attribute__((address_space(3))) void*)dst, 16, 0, 0);
    }
}

__device__ __forceinline__ void sk_compute(const unsigned char* slot, int wr, int wc,
                                           int rA, int g16, f32x4 acc[2][2]) {
    const unsigned char* Ab = slot;
    const unsigned char* Bb = slot + 8192;
    bf16x8 a[2][2], b[2][2];
#pragma unroll
    for (int m = 0; m < 2; ++m) {
        int row = wr + m * 16 + rA;
        int sw = (row & 7) << 4;
#pragma unroll
        for (int s = 0; s < 2; ++s)
            a[m][s] = *(const bf16x8*)(Ab + row * 128 + ((s * 64 + g16 * 16) ^ sw));
    }
#pragma unroll
    for (int n = 0; n < 2; ++n) {
        int row = wc + n * 16 + rA;
        int sw = (row & 7) << 4;
#pragma unroll
        for (int s = 0; s < 2; ++s)
            b[n][s] = *(const bf16x8*)(Bb + row * 128 + ((s * 64 + g16 * 16) ^ sw));
    }
    __builtin_amdgcn_s_setprio(1);
#pragma unroll
    for (int m = 0; m < 2; ++m)
#pragma unroll
        for (int n = 0; n < 2; ++n) {
            acc[m][n] = __builtin_amdgcn_mfma_f32_16x16x32_bf16(a[m][0], b[n][0], acc[m][n], 0, 0, 0);
            acc[m][n] = __builtin_amdgcn_mfma_f32_16x16x32_bf16(a[m][1], b[n][1], acc[m][n], 0, 0, 0);
        }
    __builtin_amdgcn_s_setprio(0);
}

__global__ __launch_bounds__(256) void k_gemm_skinny(const unsigned short* __restrict__ A, int lda,
                                                     const unsigned short* __restrict__ W, int ldw,
                                                     float* __restrict__ C, int ldc,
                                                     int M, int N, int K,
                                                     const float* __restrict__ bias,
                                                     const float* __restrict__ res) {
    __shared__ unsigned char smem[2 * SKSLOT];
    int nwg = gridDim.x * gridDim.y;
    int orig = blockIdx.y * gridDim.x + blockIdx.x;
    int qq = nwg >> 3, rr = nwg & 7;
    int xcd = orig & 7, idx = orig >> 3;
    int wg = (xcd < rr ? xcd * (qq + 1) : rr * (qq + 1) + (xcd - rr) * qq) + idx;
    int bx = wg % gridDim.x, by = wg / gridDim.x;

    const int t = threadIdx.x;
    const int lane = t & 63, wid = t >> 6;
    const int row0 = by * 64, col0 = bx * 64;
    const int wr = (wid >> 1) * 32, wc = (wid & 1) * 32;
    const int rA = lane & 15, g16 = lane >> 4;
    const unsigned short* Abase = A + (size_t)row0 * lda;
    const unsigned short* Wbase = W + (size_t)col0 * ldw;

    const int nt = K >> 6;
    f32x4 acc[2][2] = {};

    sk_stage(Abase, lda, Wbase, ldw, smem, t, wid);

    for (int tt = 0; tt < nt; ++tt) {
        asm volatile("s_barrier" ::: "memory");
        if (tt + 1 < nt) {
            sk_stage(Abase + (size_t)(tt + 1) * 64, lda, Wbase + (size_t)(tt + 1) * 64,
                     ldw, smem + (size_t)((tt + 1) & 1) * SKSLOT, t, wid);
            asm volatile("s_waitcnt vmcnt(4)" ::: "memory");
        } else {
            asm volatile("s_waitcnt vmcnt(0)" ::: "memory");
        }
        asm volatile("s_barrier" ::: "memory");
        sk_compute(smem + (size_t)(tt & 1) * SKSLOT, wr, wc, rA, g16, acc);
    }

    const int cl = lane & 15, rg = (lane >> 4) * 4;
#pragma unroll
    for (int n = 0; n < 2; ++n) {
        int gc = col0 + wc + n * 16 + cl;
        float bv = bias ? bias[gc] : 0.0f;
#pragma unroll
        for (int m = 0; m < 2; ++m) {
#pragma unroll
            for (int i = 0; i < 4; ++i) {
                int gr = row0 + wr + m * 16 + rg + i;
                float v = acc[m][n][i] + bv;
                if (res) v += res[(size_t)gr * ldc + gc];
                C[(size_t)gr * ldc + gc] = v;
            }
        }
    }
}

// ---------------------------------------------------------------------------
// Mid bf16 MFMA GEMM (qkvg, W1): BM=128, BN=128, BK=64, 512 threads
// (8 waves 2x4, 64x32 out per wave), 2 LDS slots of 32 KB, 2 blocks/CU.
// SCATTER=1 (qkvg): q cols [0,768) -> qT[b,h,s,d], k cols [768,1536) ->
// kT[b,h,s,d]; v,g cols >= 1536 written to Cb normally.
// ---------------------------------------------------------------------------
#define MDSLOT 32768  /* 32 KB per slot: A 16KB @0, B 16KB @16384 */

__device__ __forceinline__ void md_stage(const unsigned short* __restrict__ Ab, int lda,
                                         const unsigned short* __restrict__ Wb, int ldw,
                                         unsigned char* slot, int t, int wid) {
    int rit = t >> 3;             // 0..63
    int kb = (t & 7) << 4;
#pragma unroll
    for (int c = 0; c < 2; ++c) { // A: 128 rows
        int row = c * 64 + rit;
        int gkb = kb ^ ((row & 7) << 4);
        const unsigned short* src = Ab + (size_t)row * lda + (gkb >> 1);
        unsigned char* dst = slot + c * 8192 + wid * 1024;
        __builtin_amdgcn_global_load_lds(
            (const __attribute__((address_space(1))) void*)src,
            (__attribute__((address_space(3))) void*)dst, 16, 0, 0);
    }
#pragma unroll
    for (int c = 0; c < 2; ++c) { // B: 128 rows
        int row = c * 64 + rit;
        int gkb = kb ^ ((row & 7) << 4);
        const unsigned short* src = Wb + (size_t)row * ldw + (gkb >> 1);
        unsigned char* dst = slot + 16384 + c * 8192 + wid * 1024;
        __builtin_amdgcn_global_load_lds(
            (const __attribute__((address_space(1))) void*)src,
            (__attribute__((address_space(3))) void*)dst, 16, 0, 0);
    }
}

__device__ __forceinline__ void md_compute(const unsigned char* slot, int wm, int wn,
                                           int rA, int g16, f32x4 acc[4][2]) {
    const unsigned char* Ab = slot;
    const unsigned char* Bb = slot + 16384;
    bf16x8 a[4][2], b[2][2];
#pragma unroll
    for (int m = 0; m < 4; ++m) {
        int row = wm * 64 + m * 16 + rA;
        int sw = (row & 7) << 4;
#pragma unroll
        for (int s = 0; s < 2; ++s)
            a[m][s] = *(const bf16x8*)(Ab + row * 128 + ((s * 64 + g16 * 16) ^ sw));
    }
#pragma unroll
    for (int n = 0; n < 2; ++n) {
        int row = wn * 32 + n * 16 + rA;
        int sw = (row & 7) << 4;
#pragma unroll
        for (int s = 0; s < 2; ++s)
            b[n][s] = *(const bf16x8*)(Bb + row * 128 + ((s * 64 + g16 * 16) ^ sw));
    }
    __builtin_amdgcn_s_setprio(1);
#pragma unroll
    for (int m = 0; m < 4; ++m)
#pragma unroll
        for (int n = 0; n < 2; ++n) {
            acc[m][n] = __builtin_amdgcn_mfma_f32_16x16x32_bf16(a[m][0], b[n][0], acc[m][n], 0, 0, 0);
            acc[m][n] = __builtin_amdgcn_mfma_f32_16x16x32_bf16(a[m][1], b[n][1], acc[m][n], 0, 0, 0);
        }
    __builtin_amdgcn_s_setprio(0);
}

template <int SCATTER>
__global__ __launch_bounds__(512) void k_gemm_mid(const unsigned short* __restrict__ A, int lda,
                                                  const unsigned short* __restrict__ W,
                                                  const unsigned short* __restrict__ Wb2, int ldw,
                                                  unsigned short* __restrict__ Cb, int ldc,
                                                  int M, int N, int K,
                                                  const float* __restrict__ bias,
                                                  const float* __restrict__ bias2,
                                                  unsigned short* __restrict__ qT,
                                                  unsigned short* __restrict__ kT) {
    extern __shared__ unsigned char smem[];
    int nwg = gridDim.x * gridDim.y;
    int orig = blockIdx.y * gridDim.x + blockIdx.x;
    int qq = nwg >> 3, rr = nwg & 7;
    int xcd = orig & 7, idx = orig >> 3;
    int wg = (xcd < rr ? xcd * (qq + 1) : rr * (qq + 1) + (xcd - rr) * qq) + idx;
    int bx = wg % gridDim.x, by = wg / gridDim.x;

    const int t = threadIdx.x;
    const int lane = t & 63, wid = t >> 6;
    const int wm = wid >> 2, wn = wid & 3;
    const int rA = lane & 15, g16 = lane >> 4;
    const int row0 = by * 128, col0 = bx * 128;
    const unsigned short* Abase = A + (size_t)row0 * lda;
    const unsigned short* Wbase = (Wb2 && col0 >= 1536)
                                      ? Wb2 + (size_t)(col0 - 1536) * ldw
                                      : W + (size_t)col0 * ldw;

    const int nt = K >> 6;
    f32x4 acc[4][2] = {};

    md_stage(Abase, lda, Wbase, ldw, smem, t, wid);

    for (int tt = 0; tt < nt; ++tt) {
        asm volatile("s_barrier" ::: "memory");
        if (tt + 1 < nt) {
            md_stage(Abase + (size_t)(tt + 1) * 64, lda, Wbase + (size_t)(tt + 1) * 64,
                     ldw, smem + (size_t)((tt + 1) & 1) * MDSLOT, t, wid);
            asm volatile("s_waitcnt vmcnt(4)" ::: "memory");
        } else {
            asm volatile("s_waitcnt vmcnt(0)" ::: "memory");
        }
        asm volatile("s_barrier" ::: "memory");
        md_compute(smem + (size_t)(tt & 1) * MDSLOT, wm, wn, rA, g16, acc);
    }

    const int cl = lane & 15, rg = (lane >> 4) * 4;
#pragma unroll
    for (int n = 0; n < 2; ++n) {
        int gc = col0 + wn * 32 + n * 16 + cl;
        float bv = 0.0f;
        if (bias) bv = (bias2 && gc >= 1536) ? bias2[gc - 1536] : bias[gc];
        if (SCATTER && gc < 1536) {
            int isk = gc >= HH;
            unsigned short* dst = isk ? kT : qT;
            int h = (isk ? gc - HH : gc) >> 6;
            int d = gc & 63;
#pragma unroll
            for (int m = 0; m < 4; ++m) {
#pragma unroll
                for (int i = 0; i < 4; ++i) {
                    int gr = row0 + wm * 64 + m * 16 + rg + i;
                    int s = gr >> 3, b = gr & 7;
                    dst[(((size_t)(b * NHH + h)) * SS + s) * DD + d] = f2b(acc[m][n][i] + bv);
                }
            }
        } else {
#pragma unroll
            for (int m = 0; m < 4; ++m) {
#pragma unroll
                for (int i = 0; i < 4; ++i) {
                    int gr = row0 + wm * 64 + m * 16 + rg + i;
                    Cb[(size_t)gr * ldc + gc] = f2b(acc[m][n][i] + bv);
                }
            }
        }
    }
}

// ---------------------------------------------------------------------------
// merged: v-transpose repack (blockIdx.x<8) + cp/pc MFMA (blockIdx.x>=8)
// ---------------------------------------------------------------------------
__global__ __launch_bounds__(256) void k_repack_cppc(const unsigned short* __restrict__ qkvg,
                                                     const unsigned short* __restrict__ pp,
                                                     const unsigned short* __restrict__ qT,
                                                     const unsigned short* __restrict__ kT,
                                                     unsigned short* __restrict__ vT,
                                                     float* __restrict__ cp,
                                                     float* __restrict__ pc) {
    __shared__ unsigned char shmem[12288];
    int t = threadIdx.x;
    if (blockIdx.x < 8) {
        unsigned short (*tile)[72] = (unsigned short(*)[72])shmem;
        int bh = blockIdx.y;
        int b = bh / NHH, h = bh % NHH;
        int s0 = blockIdx.x * 64;
#pragma unroll
        for (int j = 0; j < 4; ++j) {
            int idx = t + j * 256;
            int r = idx >> 4, c4 = idx & 15;
            ushort4 u = *(const ushort4*)(qkvg + ((size_t)(s0 + r) * BB + b) * 3072 + 1536 + h * DD + c4 * 4);
            *(ushort4*)&tile[r][c4 * 4] = u;
        }
        __syncthreads();
#pragma unroll
        for (int j = 0; j < 2; ++j) {
            int idx = t + j * 256;
            int d = idx >> 3, s8 = idx & 7;
            ushort4 a, c;
            a.x = tile[s8 * 8 + 0][d]; a.y = tile[s8 * 8 + 1][d];
            a.z = tile[s8 * 8 + 2][d]; a.w = tile[s8 * 8 + 3][d];
            c.x = tile[s8 * 8 + 4][d]; c.y = tile[s8 * 8 + 5][d];
            c.z = tile[s8 * 8 + 6][d]; c.w = tile[s8 * 8 + 7][d];
            unsigned short* dst = vT + ((size_t)bh * DD + d) * SS + s0 + s8 * 8;
            *(ushort4*)dst = a; *(ushort4*)(dst + 4) = c;
        }
    } else {
        int cid = (blockIdx.x - 8) * 96 + blockIdx.y;
        int z = cid >= 384;
        int rem = cid - (z ? 384 : 0);
        int h = rem >> 5;
        int mt = rem & 31;
        int toff = z ? 0 : HH;
        float* out = z ? pc : cp;
        const unsigned short* srcbase = z ? kT : qT;
        unsigned short* As = (unsigned short*)shmem;
        unsigned short* Bs = (unsigned short*)(shmem + 8192);
        const int lane = t & 63, wid = t >> 6;
        const int rA = lane & 15, kA = (lane >> 4) * 8;

        f32x4 acc[2][4] = {};

        for (int k0 = 0; k0 < 64; k0 += 32) {
#pragma unroll
            for (int j = 0; j < 2; ++j) {
                int c = t + j * 256;
                int r = c >> 2, ko = (c & 3) * 8;
                int row = mt * 128 + r;
                int s = row >> 3, b = row & 7;
                const unsigned short* srcA =
                    srcbase + (((size_t)(b * NHH + h)) * SS + s) * DD + k0 + ko;
                unsigned short* dstA = As + (size_t)(j * 256 + wid * 64) * 8;
                __builtin_amdgcn_global_load_lds(
                    (const __attribute__((address_space(1))) void*)srcA,
                    (__attribute__((address_space(3))) void*)dstA, 16, 0, 0);
            }
            {
                int r = t >> 2, ko = (t & 3) * 8;
                const unsigned short* srcB = pp + (size_t)r * 1536 + toff + h * DD + k0 + ko;
                unsigned short* dstB = Bs + (size_t)(wid * 64) * 8;
                __builtin_amdgcn_global_load_lds(
                    (const __attribute__((address_space(1))) void*)srcB,
                    (__attribute__((address_space(3))) void*)dstB, 16, 0, 0);
            }
            __syncthreads();
            bf16x8 af[2], bfr[4];
#pragma unroll
            for (int m = 0; m < 2; ++m)
                af[m] = *(const bf16x8*)&As[(wid * 32 + m * 16 + rA) * 32 + kA];
#pragma unroll
            for (int n = 0; n < 4; ++n)
                bfr[n] = *(const bf16x8*)&Bs[(n * 16 + rA) * 32 + kA];
#pragma unroll
            for (int m = 0; m < 2; ++m)
#pragma unroll
                for (int n = 0; n < 4; ++n)
                    acc[m][n] = __builtin_amdgcn_mfma_f32_16x16x32_bf16(af[m], bfr[n], acc[m][n], 0, 0, 0);
            __syncthreads();
        }

        const int cl = lane & 15, rg = (lane >> 4) * 4;
#pragma unroll
        for (int m = 0; m < 2; ++m)
#pragma unroll
            for (int n = 0; n < 4; ++n) {
                int gc = n * 16 + cl;
                if (gc < 63) {
#pragma unroll
                    for (int i = 0; i < 4; ++i) {
                        int gr = mt * 128 + wid * 32 + m * 16 + rg + i;
                        int sIdx = gr >> 3, bIdx = gr & 7;
                        out[(((size_t)(bIdx * NHH + h)) * SS + sIdx) * 63 + gc] = acc[m][n][i];
                    }
                }
            }
    }
}

// ---------------------------------------------------------------------------
// fused disentangled flash attention v5: no-max softmax.
// Scores bounded (LN'd q,k: |s*SCALE| << 88), so P = exp(s*SCALE) directly;
// masked lanes underflow to exactly 0. Removes per-tile max reduction
// (4 fmax + 4 shfl per i-iter) and the entire rescale path. P/l identical
// to the max-subtracted form by softmax shift invariance.
// ---------------------------------------------------------------------------
__global__ __launch_bounds__(256) void k_attn_fused(
    const unsigned short* __restrict__ qT, const unsigned short* __restrict__ kT,
    const unsigned short* __restrict__ vT, const float* __restrict__ cp,
    const float* __restrict__ pc, const int* __restrict__ bucket,
    const int* __restrict__ mask, float* __restrict__ ctxr) {
    __shared__ float cps[64 * 63];
    __shared__ float pcs[64 * 63];
    __shared__ unsigned short pb_all[4][16 * 72];
    __shared__ int btab[1023];
    int t = threadIdx.x;
    int lane = t & 63, wid = t >> 6;
    int bh = blockIdx.y;
    int b = bh / NHH, h = bh % NHH;
    int qb0 = blockIdx.x * 64;
    int q0 = qb0 + wid * 16;
    int rA = lane & 15, g = lane >> 4, kA = g * 8;
    unsigned short* pb = pb_all[wid];
    const unsigned short* qTb = qT + (size_t)bh * SS * DD;
    const unsigned short* kTb = kT + (size_t)bh * SS * DD;
    const unsigned short* vTb = vT + (size_t)bh * DD * SS;
    const float* cpb = cp + (size_t)bh * SS * 63 + (size_t)qb0 * 63;
    const float* pcb = pc + (size_t)bh * SS * 63;
    const int* mkb = mask + b * SS;

    for (int i = t; i < 1023; i += 256) btab[i] = bucket[i];
    for (int i = t; i < 1008; i += 256) ((float4*)cps)[i] = ((const float4*)cpb)[i];

    bf16x8 aq[2];
#pragma unroll
    for (int dc = 0; dc < 2; ++dc)
        aq[dc] = *(const bf16x8*)&qTb[(size_t)(q0 + rA) * DD + dc * 32 + kA];

    f32x4 o[4] = {};
    float lrow[4];
#pragma unroll
    for (int i = 0; i < 4; ++i) lrow[i] = 0.f;

    for (int kt = 0; kt < 8; ++kt) {
        int k0 = kt * 64;
        __syncthreads();
        {
            const float4* src = (const float4*)(pcb + (size_t)k0 * 63);
            for (int i = t; i < 1008; i += 256) ((float4*)pcs)[i] = src[i];
        }
        f32x4 sa[4] = {};
#pragma unroll
        for (int n = 0; n < 4; ++n) {
            bf16x8 bk0 = *(const bf16x8*)&kTb[(size_t)(k0 + n * 16 + rA) * DD + kA];
            bf16x8 bk1 = *(const bf16x8*)&kTb[(size_t)(k0 + n * 16 + rA) * DD + 32 + kA];
            sa[n] = __builtin_amdgcn_mfma_f32_16x16x32_bf16(aq[0], bk0, sa[n], 0, 0, 0);
            sa[n] = __builtin_amdgcn_mfma_f32_16x16x32_bf16(aq[1], bk1, sa[n], 0, 0, 0);
        }
        int mk[4];
#pragma unroll
        for (int n = 0; n < 4; ++n) mk[n] = mkb[k0 + n * 16 + rA];
        __syncthreads();

        float pv[4][4];
#pragma unroll
        for (int i = 0; i < 4; ++i) {
            int qr = wid * 16 + g * 4 + i;
            int q = qb0 + qr;
            float ls = 0.f;
#pragma unroll
            for (int n = 0; n < 4; ++n) {
                int kr = n * 16 + rA;
                int id = btab[q - (k0 + kr) + 511];
                float v = (sa[n][i] + cps[qr * 63 + id] + pcs[kr * 63 + id]) * SCALE_F;
                v = mk[n] ? -1e9f : v;
                float p = __expf(v);   // masked -> exp(-1e9) == 0 exactly
                pv[n][i] = p;
                ls += p;
            }
            ls += __shfl_xor(ls, 1, 16);
            ls += __shfl_xor(ls, 2, 16);
            ls += __shfl_xor(ls, 4, 16);
            ls += __shfl_xor(ls, 8, 16);
            lrow[i] += ls;
        }
#pragma unroll
        for (int n = 0; n < 4; ++n)
#pragma unroll
            for (int i = 0; i < 4; ++i)
                pb[(g * 4 + i) * 72 + n * 16 + rA] = f2b(pv[n][i]);
        bf16x8 ap[2];
#pragma unroll
        for (int kc = 0; kc < 2; ++kc)
            ap[kc] = *(const bf16x8*)&pb[rA * 72 + kc * 32 + kA];
#pragma unroll
        for (int n = 0; n < 4; ++n) {
            bf16x8 bv0 = *(const bf16x8*)&vTb[(size_t)(n * 16 + rA) * SS + k0 + kA];
            bf16x8 bv1 = *(const bf16x8*)&vTb[(size_t)(n * 16 + rA) * SS + k0 + 32 + kA];
            o[n] = __builtin_amdgcn_mfma_f32_16x16x32_bf16(ap[0], bv0, o[n], 0, 0, 0);
            o[n] = __builtin_amdgcn_mfma_f32_16x16x32_bf16(ap[1], bv1, o[n], 0, 0, 0);
        }
    }
#pragma unroll
    for (int i = 0; i < 4; ++i) {
        int q = q0 + g * 4 + i;
        float inv = 1.0f / lrow[i];
#pragma unroll
        for (int n = 0; n < 4; ++n)
            ctxr[((size_t)q * BB + b) * HH + h * DD + n * 16 + rA] = o[n][i] * inv;
    }
}

// ---------------------------------------------------------------------------
// host launcher
// ---------------------------------------------------------------------------
extern "C" void kernel_launch(void* const* d_in, const int* in_sizes, int n_in,
                              void* d_out, int out_size, void* d_ws, size_t ws_size,
                              hipStream_t stream) {
    static int attr_done = 0;
    if (!attr_done) {
        hipFuncSetAttribute((const void*)&k_gemm_mid<0>,
                            hipFuncAttributeMaxDynamicSharedMemorySize, 2 * MDSLOT);
        hipFuncSetAttribute((const void*)&k_gemm_mid<1>,
                            hipFuncAttributeMaxDynamicSharedMemorySize, 2 * MDSLOT);
        attr_done = 1;
    }

    const int* ids = (const int*)d_in[0];
    const unsigned char* maskraw = (const unsigned char*)d_in[1];
    const float* word_emb = (const float*)d_in[2];
    const float* rel_emb = (const float*)d_in[3];
    const float* rel_g = (const float*)d_in[4];
    const float* rel_b = (const float*)d_in[5];
    const float* Wqk = (const float*)d_in[6];
    const float* bqk = (const float*)d_in[7];
    const float* Wvg = (const float*)d_in[8];
    const float* bvg = (const float*)d_in[9];
    const float* Wout = (const float*)d_in[10];
    const float* bout = (const float*)d_in[11];
    const float* W1 = (const float*)d_in[12];
    const float* W2 = (const float*)d_in[13];

    const size_t N_X = (size_t)SS * BB * HH;
    const size_t N_CP = (size_t)SS * BB * NHH * 63;
    const size_t N_H2 = (size_t)SS * BB * II;
    const size_t N_WQK = (size_t)2 * HH * HH;
    const size_t N_WOUT = (size_t)HH * HH;
    const size_t N_W1 = (size_t)2 * II * HH;
    const size_t N_W2 = (size_t)HH * II;
    const size_t N_HD = (size_t)BB * NHH * SS * DD;
    const size_t N_QKVG = (size_t)SS * BB * 3072;
    const size_t N_FFH = (size_t)SS * BB * 4096;
    const size_t N_PP = (size_t)128 * 1536;

    float* ws = (float*)d_ws;
    float* x = ws;
    float* ctxr = x + N_X;
    float* cp = ctxr + N_X;
    float* pc = cp + N_CP;
    unsigned short* us = (unsigned short*)(pc + N_CP);
    unsigned short* qkvg = us;
    unsigned short* hs_bf = qkvg + N_QKVG;
    unsigned short* ctx_bf = hs_bf + N_X;
    unsigned short* h2_bf = ctx_bf + N_X;
    unsigned short* ffh = h2_bf + N_H2;
    unsigned short* wqk_all = ffh + N_FFH;
    unsigned short* wvg_bf = wqk_all + 12 * N_WQK;
    unsigned short* wout_bf = wvg_bf + N_WQK;
    unsigned short* w1_bf = wout_bf + N_WOUT;
    unsigned short* w2_bf = w1_bf + N_W1;
    unsigned short* ppall = w2_bf + N_W2;
    unsigned short* rel_bf = ppall + 12 * N_PP;
    unsigned short* qT = rel_bf + 128 * HH;
    unsigned short* kT = qT + N_HD;
    unsigned short* vT = kT + N_HD;
    int* bucket = (int*)(vT + N_HD);
    int* maski = bucket + 1024;

    size_t need_bytes = ((size_t)(maski + BB * SS) - (size_t)d_ws);
    if (ws_size < need_bytes) return;  // ~205 MB required

    // ---- setup ----
    k_decode_mask<<<1, 256, 0, stream>>>(maskraw, maski, BB * SS);
    k_bucket<<<4, 256, 0, stream>>>(bucket);
    k_embed_ln<<<SS * BB, 256, 0, stream>>>(ids, word_emb, x);
    k_rel_ln_bf<<<128, 256, 0, stream>>>(rel_emb, rel_g, rel_b, rel_bf);
    k_f2b<<<(int)((12 * N_WQK / 8 + 255) / 256), 256, 0, stream>>>(Wqk, wqk_all,
                                                                   (int)(12 * N_WQK / 8));
    {
        dim3 gpp(1536 / 128, 1, 12);
        k_gemm_bf16<1><<<gpp, 256, 0, stream>>>(rel_bf, HH, wqk_all, HH, ppall, 1536,
                                                128, 1536, HH, bqk, nullptr, nullptr,
                                                N_WQK, N_PP, 2 * HH);
    }

    for (int l = 0; l < LL; ++l) {
        const unsigned short* wqk_l = wqk_all + (size_t)l * N_WQK;
        const float* bqk_l = bqk + (size_t)l * 2 * HH;
        const float* Wvg_l = Wvg + (size_t)l * N_WQK;
        const float* bvg_l = bvg + (size_t)l * 2 * HH;
        const float* Wout_l = Wout + (size_t)l * N_WOUT;
        const float* bout_l = bout + (size_t)l * HH;
        const float* W1_l = W1 + (size_t)l * N_W1;
        const float* W2_l = W2 + (size_t)l * N_W2;

        // ---- attention ----
        k_f2b_ln<<<3169 + SS * BB, 256, 0, stream>>>(Wvg_l, Wout_l, W1_l, W2_l, wvg_bf,
                                                     x, hs_bf);
        {
            dim3 g(3072 / 128, SS * BB / 128);
            k_gemm_mid<1><<<g, 512, 2 * MDSLOT, stream>>>(hs_bf, HH, wqk_l, wvg_bf, HH,
                                                          qkvg, 3072, SS * BB, 3072, HH,
                                                          bqk_l, bvg_l, qT, kT);
        }
        k_repack_cppc<<<dim3(16, 96), 256, 0, stream>>>(qkvg, ppall + (size_t)l * N_PP,
                                                        qT, kT, vT, cp, pc);
        k_attn_fused<<<dim3(SS / 64, BB * NHH), 256, 0, stream>>>(qT, kT, vT, cp, pc,
                                                                  bucket, maski, ctxr);
        k_gated_ln<<<SS * BB, 256, 0, stream>>>(ctxr, qkvg, ctx_bf);
        k_gemm_skinny<<<dim3(HH / 64, SS * BB / 64), 256, 0, stream>>>(
            ctx_bf, HH, wout_bf, HH, x, HH, SS * BB, HH, HH, bout_l, x);

        // ---- GeGLU FFN ----
        k_ln_bf<<<SS * BB, 256, 0, stream>>>(x, hs_bf);
        {
            dim3 g(4096 / 128, SS * BB / 128);
            k_gemm_mid<0><<<g, 512, 2 * MDSLOT, stream>>>(hs_bf, HH, w1_bf, nullptr, HH,
                                                          ffh, 4096, SS * BB, 4096, HH,
                                                          nullptr, nullptr, nullptr, nullptr);
        }
        k_ffn_ln<<<SS * BB, 256, 0, stream>>>(ffh, h2_bf);
        // last layer writes the residual-added output straight into d_out
        float* outC = (l == LL - 1) ? (float*)d_out : x;
        k_gemm_skinny<<<dim3(HH / 64, SS * BB / 64), 256, 0, stream>>>(
            h2_bf, II, w2_bf, II, outC, HH, SS * BB, HH, II, nullptr, x);
    }
}

// Round 17
// 2598.420 us; speedup vs baseline: 1.0884x; 1.0122x over previous
//
#include <hip/hip_runtime.h>
#include <math.h>

#define SS 512
#define BB 8
#define NHH 12
#define DD 64
#define HH 768
#define II 2048
#define LL 12
#define SCALE_F 0.07216878364870323f  /* 1/sqrt(3*64) */

typedef __attribute__((ext_vector_type(8))) short bf16x8;
typedef __attribute__((ext_vector_type(4))) float f32x4;

// f32 -> bf16 (RNE, finite values)
__device__ __forceinline__ unsigned short f2b(float f) {
    union { float f; unsigned int u; } x; x.f = f;
    unsigned int r = x.u + 0x7fffu + ((x.u >> 16) & 1u);
    return (unsigned short)(r >> 16);
}
__device__ __forceinline__ float b2f(unsigned short u) {
    union { unsigned int u; float f; } x; x.u = ((unsigned int)u) << 16;
    return x.f;
}

// ---------------------------------------------------------------------------
// block reduction helpers (blockDim.x == 256)
// ---------------------------------------------------------------------------
__device__ __forceinline__ float2 blockReduceSum2(float a, float b) {
    __shared__ float2 sm[4];
    __shared__ float2 bc;
#pragma unroll
    for (int o = 32; o > 0; o >>= 1) {
        a += __shfl_down(a, o);
        b += __shfl_down(b, o);
    }
    int t = threadIdx.x;
    if ((t & 63) == 0) sm[t >> 6] = make_float2(a, b);
    __syncthreads();
    if (t == 0) {
        float xa = sm[0].x + sm[1].x + sm[2].x + sm[3].x;
        float xb = sm[0].y + sm[1].y + sm[2].y + sm[3].y;
        bc = make_float2(xa, xb);
    }
    __syncthreads();
    return bc;
}

__device__ __forceinline__ float gelu_erf(float v) {
    return 0.5f * v * (1.0f + erff(v * 0.70710678118654752f));
}
__device__ __forceinline__ float gelu_tanh(float v) {
    const float c = 0.7978845608028654f;
    return 0.5f * v * (1.0f + tanhf(c * (v + 0.044715f * v * v * v)));
}

// ---------------------------------------------------------------------------
// mask decode: handle bool-as-u8 or bool-as-int32 layouts
// ---------------------------------------------------------------------------
__global__ __launch_bounds__(256) void k_decode_mask(const unsigned char* __restrict__ raw,
                                                     int* __restrict__ mask, int n) {
    __shared__ int s_any;
    if (threadIdx.x == 0) s_any = 0;
    __syncthreads();
    int local = 0;
    for (int i = threadIdx.x; i < n; i += blockDim.x)
        if ((i & 3) && raw[i]) local = 1;
    if (local) atomicOr(&s_any, 1);
    __syncthreads();
    bool isU8 = (s_any != 0);
    const int* as_int = (const int*)raw;
    for (int i = threadIdx.x; i < n; i += blockDim.x)
        mask[i] = isU8 ? (raw[i] != 0) : (as_int[i] != 0);
}

// ---------------------------------------------------------------------------
// DeBERTa log-bucket table: rel in [-511,511] -> idx in [0,62]
// ---------------------------------------------------------------------------
__global__ __launch_bounds__(256) void k_bucket(int* __restrict__ tab) {
    int i = blockIdx.x * 256 + threadIdx.x;
    if (i >= 1023) return;
    int rel = i - 511;
    int a = rel < 0 ? -rel : rel;
    int abs_pos = (a < 16) ? 15 : (a < 511 ? a : 511);
    int bucket;
    if (abs_pos <= 16) {
        bucket = rel;
    } else {
        double lp = ceil(log((double)abs_pos / 16.0) / log(511.0 / 16.0) * 15.0);
        int l = (int)lp + 16;
        bucket = (rel > 0) ? l : -l;
    }
    int idx = bucket + 31;
    if (idx < 0) idx = 0;
    if (idx > 62) idx = 62;
    tab[i] = idx;
}

// ---------------------------------------------------------------------------
// generic f32 -> bf16 bulk conversion (8 elems/thread)
// ---------------------------------------------------------------------------
__global__ __launch_bounds__(256) void k_f2b(const float* __restrict__ in,
                                             unsigned short* __restrict__ out, int n8) {
    int i = blockIdx.x * 256 + threadIdx.x;
    if (i >= n8) return;
    float4 a = ((const float4*)in)[2 * (size_t)i];
    float4 b = ((const float4*)in)[2 * (size_t)i + 1];
    ushort4 lo, hi;
    lo.x = f2b(a.x); lo.y = f2b(a.y); lo.z = f2b(a.z); lo.w = f2b(a.w);
    hi.x = f2b(b.x); hi.y = f2b(b.y); hi.z = f2b(b.z); hi.w = f2b(b.w);
    ((ushort4*)out)[2 * (size_t)i] = lo;
    ((ushort4*)out)[2 * (size_t)i + 1] = hi;
}

// ---------------------------------------------------------------------------
// merged: per-layer weight conversion (blocks 0..3168) + LN of x (blocks 3169..7264)
// ---------------------------------------------------------------------------
__global__ __launch_bounds__(256) void k_f2b_ln(const float* __restrict__ wvg,
                                                const float* __restrict__ wout,
                                                const float* __restrict__ w1,
                                                const float* __restrict__ w2,
                                                unsigned short* __restrict__ wbf,
                                                const float* __restrict__ x,
                                                unsigned short* __restrict__ hs) {
    int bid = blockIdx.x;
    int t = threadIdx.x;
    if (bid < 3169) {
        int i = bid * 256 + t;
        if (i >= 811008) return;
        const float* src;
        int off;
        if (i < 221184) {
            if (i < 147456) { src = wvg;  off = i; }
            else            { src = wout; off = i - 147456; }
        } else if (i < 614400) { src = w1; off = i - 221184; }
        else                   { src = w2; off = i - 614400; }
        float4 a = ((const float4*)src)[2 * (size_t)off];
        float4 b = ((const float4*)src)[2 * (size_t)off + 1];
        ushort4 lo, hi;
        lo.x = f2b(a.x); lo.y = f2b(a.y); lo.z = f2b(a.z); lo.w = f2b(a.w);
        hi.x = f2b(b.x); hi.y = f2b(b.y); hi.z = f2b(b.z); hi.w = f2b(b.w);
        ((ushort4*)wbf)[2 * (size_t)i] = lo;
        ((ushort4*)wbf)[2 * (size_t)i + 1] = hi;
    } else {
        int row = bid - 3169;
        const float* r = x + (size_t)row * HH;
        float v0 = r[t], v1 = r[t + 256], v2 = r[t + 512];
        float s = v0 + v1 + v2;
        float ss = v0 * v0 + v1 * v1 + v2 * v2;
        float2 r2 = blockReduceSum2(s, ss);
        float mean = r2.x * (1.0f / HH);
        float var = r2.y * (1.0f / HH) - mean * mean;
        float rs = rsqrtf(var + 1e-7f);
        unsigned short* o = hs + (size_t)row * HH;
        o[t] = f2b((v0 - mean) * rs);
        o[t + 256] = f2b((v1 - mean) * rs);
        o[t + 512] = f2b((v2 - mean) * rs);
    }
}

// ---------------------------------------------------------------------------
// LayerNorm family; EPS = 1e-7, biased variance
// ---------------------------------------------------------------------------
__global__ __launch_bounds__(256) void k_ln_bf(const float* __restrict__ in,
                                               unsigned short* __restrict__ out) {
    int row = blockIdx.x, t = threadIdx.x;
    const float* r = in + (size_t)row * HH;
    float v0 = r[t], v1 = r[t + 256], v2 = r[t + 512];
    float s = v0 + v1 + v2;
    float ss = v0 * v0 + v1 * v1 + v2 * v2;
    float2 r2 = blockReduceSum2(s, ss);
    float mean = r2.x * (1.0f / HH);
    float var = r2.y * (1.0f / HH) - mean * mean;
    float rs = rsqrtf(var + 1e-7f);
    unsigned short* o = out + (size_t)row * HH;
    o[t] = f2b((v0 - mean) * rs);
    o[t + 256] = f2b((v1 - mean) * rs);
    o[t + 512] = f2b((v2 - mean) * rs);
}

__global__ __launch_bounds__(256) void k_embed_ln(const int* __restrict__ ids,
                                                  const float* __restrict__ emb,
                                                  float* __restrict__ out) {
    int row = blockIdx.x, t = threadIdx.x;
    const float* r = emb + (size_t)ids[row] * HH;
    float v0 = r[t], v1 = r[t + 256], v2 = r[t + 512];
    float s = v0 + v1 + v2;
    float ss = v0 * v0 + v1 * v1 + v2 * v2;
    float2 r2 = blockReduceSum2(s, ss);
    float mean = r2.x * (1.0f / HH);
    float var = r2.y * (1.0f / HH) - mean * mean;
    float rs = rsqrtf(var + 1e-7f);
    float* o = out + (size_t)row * HH;
    o[t] = (v0 - mean) * rs;
    o[t + 256] = (v1 - mean) * rs;
    o[t + 512] = (v2 - mean) * rs;
}

// rel LN -> bf16, padded to 128 rows (rows 63..127 zero)
__global__ __launch_bounds__(256) void k_rel_ln_bf(const float* __restrict__ rel_emb,
                                                   const float* __restrict__ g,
                                                   const float* __restrict__ b,
                                                   unsigned short* __restrict__ out) {
    int row = blockIdx.x, t = threadIdx.x;
    unsigned short* o = out + (size_t)row * HH;
    if (row >= 63) {
        o[t] = 0; o[t + 256] = 0; o[t + 512] = 0;
        return;
    }
    const float* r = rel_emb + (size_t)row * HH;
    float v0 = r[t], v1 = r[t + 256], v2 = r[t + 512];
    float s = v0 + v1 + v2;
    float ss = v0 * v0 + v1 * v1 + v2 * v2;
    float2 r2 = blockReduceSum2(s, ss);
    float mean = r2.x * (1.0f / HH);
    float var = r2.y * (1.0f / HH) - mean * mean;
    float rs = rsqrtf(var + 1e-7f);
    o[t] = f2b((v0 - mean) * rs * g[t] + b[t]);
    o[t + 256] = f2b((v1 - mean) * rs * g[t + 256] + b[t + 256]);
    o[t + 512] = f2b((v2 - mean) * rs * g[t + 512] + b[t + 512]);
}

// ctx_bf = bf16(LN(ctxr * gelu_exact(g))), g = qkvg[..., 2304:3072] (bf16)
__global__ __launch_bounds__(256) void k_gated_ln(const float* __restrict__ ctxr,
                                                  const unsigned short* __restrict__ qkvg,
                                                  unsigned short* __restrict__ out) {
    int row = blockIdx.x, t = threadIdx.x;
    const float* cr = ctxr + (size_t)row * HH;
    const unsigned short* gr = qkvg + (size_t)row * 3072 + 2304;
    float v[3];
    float s = 0.f, ss = 0.f;
#pragma unroll
    for (int e = 0; e < 3; ++e) {
        int i = t + e * 256;
        float x = cr[i] * gelu_erf(b2f(gr[i]));
        v[e] = x;
        s += x; ss += x * x;
    }
    float2 r2 = blockReduceSum2(s, ss);
    float mean = r2.x * (1.0f / HH);
    float var = r2.y * (1.0f / HH) - mean * mean;
    float rs = rsqrtf(var + 1e-7f);
    unsigned short* o = out + (size_t)row * HH;
#pragma unroll
    for (int e = 0; e < 3; ++e) o[t + e * 256] = f2b((v[e] - mean) * rs);
}

// h2_bf = bf16(LN(ffh[:, :I] * gelu_tanh(ffh[:, I:])))  (ffh bf16 [row][4096])
__global__ __launch_bounds__(256) void k_ffn_ln(const unsigned short* __restrict__ ffh,
                                                unsigned short* __restrict__ out) {
    int row = blockIdx.x, t = threadIdx.x;
    const unsigned short* ar = ffh + (size_t)row * 4096 + t * 8;
    const unsigned short* gr = ar + II;
    ushort4 a0 = *(const ushort4*)ar;
    ushort4 a1 = *(const ushort4*)(ar + 4);
    ushort4 g0 = *(const ushort4*)gr;
    ushort4 g1 = *(const ushort4*)(gr + 4);
    float av[8] = {b2f(a0.x), b2f(a0.y), b2f(a0.z), b2f(a0.w),
                   b2f(a1.x), b2f(a1.y), b2f(a1.z), b2f(a1.w)};
    float gv[8] = {b2f(g0.x), b2f(g0.y), b2f(g0.z), b2f(g0.w),
                   b2f(g1.x), b2f(g1.y), b2f(g1.z), b2f(g1.w)};
    float v[8];
    float s = 0.f, ss = 0.f;
#pragma unroll
    for (int e = 0; e < 8; ++e) {
        float x = av[e] * gelu_tanh(gv[e]);
        v[e] = x;
        s += x; ss += x * x;
    }
    float2 r2 = blockReduceSum2(s, ss);
    float mean = r2.x * (1.0f / II);
    float var = r2.y * (1.0f / II) - mean * mean;
    float rs = rsqrtf(var + 1e-7f);
    ushort4 o0, o1;
    o0.x = f2b((v[0] - mean) * rs); o0.y = f2b((v[1] - mean) * rs);
    o0.z = f2b((v[2] - mean) * rs); o0.w = f2b((v[3] - mean) * rs);
    o1.x = f2b((v[4] - mean) * rs); o1.y = f2b((v[5] - mean) * rs);
    o1.z = f2b((v[6] - mean) * rs); o1.w = f2b((v[7] - mean) * rs);
    unsigned short* o = out + (size_t)row * II + t * 8;
    *(ushort4*)o = o0;
    *(ushort4*)(o + 4) = o1;
}

// ---------------------------------------------------------------------------
// bf16 MFMA GEMM (m97 structure + bijective XCD swizzle + z-batch) —
// used only for the batched posproj at setup.
// ---------------------------------------------------------------------------
template <int OBF>
__global__ __launch_bounds__(256) void k_gemm_bf16(const unsigned short* __restrict__ A, int lda,
                                                   const unsigned short* __restrict__ W, int ldw,
                                                   void* __restrict__ Cv, int ldc,
                                                   int M, int N, int K,
                                                   const float* __restrict__ bias,
                                                   const float* __restrict__ bias2,
                                                   const float* __restrict__ res,
                                                   size_t wz, size_t cz, size_t bz) {
    __shared__ unsigned short As[128 * 32];
    __shared__ unsigned short Ws[128 * 32];
    int zz = blockIdx.z;
    W += (size_t)zz * wz;
    if (bias) bias += (size_t)zz * bz;
    int nwg = gridDim.x * gridDim.y;
    int orig = blockIdx.y * gridDim.x + blockIdx.x;
    int qq = nwg >> 3, rr = nwg & 7;
    int xcd = orig & 7, idx = orig >> 3;
    int wg = (xcd < rr ? xcd * (qq + 1) : rr * (qq + 1) + (xcd - rr) * qq) + idx;
    int bx = wg % gridDim.x, by = wg / gridDim.x;

    const int t = threadIdx.x;
    const int lane = t & 63, wid = t >> 6;
    const int row0 = by * 128, col0 = bx * 128;
    const int wr = (wid >> 1) * 64, wc = (wid & 1) * 64;
    const int rA = lane & 15, kA = (lane >> 4) * 8;

    f32x4 acc[4][4] = {};

    for (int k0 = 0; k0 < K; k0 += 32) {
#pragma unroll
        for (int j = 0; j < 2; ++j) {
            int c = t + j * 256;
            int r = c >> 2, ko = (c & 3) * 8;
            const unsigned short* srcA = A + (size_t)(row0 + r) * lda + k0 + ko;
            const unsigned short* srcB = W + (size_t)(col0 + r) * ldw + k0 + ko;
            unsigned short* dstA = As + (size_t)(j * 256 + wid * 64) * 8;
            unsigned short* dstB = Ws + (size_t)(j * 256 + wid * 64) * 8;
            __builtin_amdgcn_global_load_lds(
                (const __attribute__((address_space(1))) void*)srcA,
                (__attribute__((address_space(3))) void*)dstA, 16, 0, 0);
            __builtin_amdgcn_global_load_lds(
                (const __attribute__((address_space(1))) void*)srcB,
                (__attribute__((address_space(3))) void*)dstB, 16, 0, 0);
        }
        __syncthreads();
        bf16x8 af[4], bfr[4];
#pragma unroll
        for (int m = 0; m < 4; ++m)
            af[m] = *(const bf16x8*)&As[(wr + m * 16 + rA) * 32 + kA];
#pragma unroll
        for (int n = 0; n < 4; ++n)
            bfr[n] = *(const bf16x8*)&Ws[(wc + n * 16 + rA) * 32 + kA];
#pragma unroll
        for (int m = 0; m < 4; ++m)
#pragma unroll
            for (int n = 0; n < 4; ++n)
                acc[m][n] = __builtin_amdgcn_mfma_f32_16x16x32_bf16(af[m], bfr[n], acc[m][n], 0, 0, 0);
        __syncthreads();
    }

    float* Cf = (float*)Cv + (size_t)zz * cz;
    unsigned short* Cb = (unsigned short*)Cv + (size_t)zz * cz;
    const int cl = lane & 15, rg = (lane >> 4) * 4;
#pragma unroll
    for (int n = 0; n < 4; ++n) {
        int gc = col0 + wc + n * 16 + cl;
        float bv = 0.0f;
        if (bias) bv = (bias2 && gc >= 1536) ? bias2[gc - 1536] : bias[gc];
#pragma unroll
        for (int m = 0; m < 4; ++m) {
#pragma unroll
            for (int i = 0; i < 4; ++i) {
                int gr = row0 + wr + m * 16 + rg + i;
                float v = acc[m][n][i] + bv;
                if (OBF) {
                    Cb[(size_t)gr * ldc + gc] = f2b(v);
                } else {
                    if (res) v += res[(size_t)gr * ldc + gc];
                    Cf[(size_t)gr * ldc + gc] = v;
                }
            }
        }
    }
}

// ---------------------------------------------------------------------------
// N64 bf16 MFMA GEMM for N=768 (Wout, W2): BM=128, BN=64, BK=64, 512 threads
// (8 waves 4x2, 32x32 out per wave -> 8 MFMA/K-iter/wave vs skinny's 4),
// 3 LDS slots of 24 KB (A 16KB @0, B 8KB @16384) = 72 KB -> 2 blocks/CU,
// depth-2 prefetch with counted vmcnt (6/3/0; 3 loads/thread/stage), raw
// barrier pairs (proven gemm_big skeleton), XOR-swizzle both-sides, setprio.
// f32 out + bias + res. Requires M%128==0, N%64==0, K%64==0, K/64>=3.
// ---------------------------------------------------------------------------
#define N64SLOT 24576  /* 24 KB: A 16KB @0, B 8KB @16384 */

__device__ __forceinline__ void n64_stage(const unsigned short* __restrict__ Ab, int lda,
                                          const unsigned short* __restrict__ Wb, int ldw,
                                          unsigned char* slot, int t, int wid) {
    int rit = t >> 3;             // 0..63
    int kb = (t & 7) << 4;        // byte offset of 16B chunk within 128B row
#pragma unroll
    for (int c = 0; c < 2; ++c) { // A: 128 rows
        int row = c * 64 + rit;
        int gkb = kb ^ ((row & 7) << 4);
        const unsigned short* src = Ab + (size_t)row * lda + (gkb >> 1);
        unsigned char* dst = slot + c * 8192 + wid * 1024;
        __builtin_amdgcn_global_load_lds(
            (const __attribute__((address_space(1))) void*)src,
            (__attribute__((address_space(3))) void*)dst, 16, 0, 0);
    }
    {                             // B: 64 rows
        int row = rit;
        int gkb = kb ^ ((row & 7) << 4);
        const unsigned short* src = Wb + (size_t)row * ldw + (gkb >> 1);
        unsigned char* dst = slot + 16384 + wid * 1024;
        __builtin_amdgcn_global_load_lds(
            (const __attribute__((address_space(1))) void*)src,
            (__attribute__((address_space(3))) void*)dst, 16, 0, 0);
    }
}

__device__ __forceinline__ void n64_compute(const unsigned char* slot, int wm, int wn,
                                            int rA, int g16, f32x4 acc[2][2]) {
    const unsigned char* Ab = slot;
    const unsigned char* Bb = slot + 16384;
    bf16x8 a[2][2], b[2][2];
#pragma unroll
    for (int m = 0; m < 2; ++m) {
        int row = wm * 32 + m * 16 + rA;
        int sw = (row & 7) << 4;
#pragma unroll
        for (int s = 0; s < 2; ++s)
            a[m][s] = *(const bf16x8*)(Ab + row * 128 + ((s * 64 + g16 * 16) ^ sw));
    }
#pragma unroll
    for (int n = 0; n < 2; ++n) {
        int row = wn * 32 + n * 16 + rA;
        int sw = (row & 7) << 4;
#pragma unroll
        for (int s = 0; s < 2; ++s)
            b[n][s] = *(const bf16x8*)(Bb + row * 128 + ((s * 64 + g16 * 16) ^ sw));
    }
    __builtin_amdgcn_s_setprio(1);
#pragma unroll
    for (int m = 0; m < 2; ++m)
#pragma unroll
        for (int n = 0; n < 2; ++n) {
            acc[m][n] = __builtin_amdgcn_mfma_f32_16x16x32_bf16(a[m][0], b[n][0], acc[m][n], 0, 0, 0);
            acc[m][n] = __builtin_amdgcn_mfma_f32_16x16x32_bf16(a[m][1], b[n][1], acc[m][n], 0, 0, 0);
        }
    __builtin_amdgcn_s_setprio(0);
}

__global__ __launch_bounds__(512) void k_gemm_n64(const unsigned short* __restrict__ A, int lda,
                                                  const unsigned short* __restrict__ W, int ldw,
                                                  float* __restrict__ C, int ldc,
                                                  int M, int N, int K,
                                                  const float* __restrict__ bias,
                                                  const float* __restrict__ res) {
    extern __shared__ unsigned char smem[];
    int nwg = gridDim.x * gridDim.y;
    int orig = blockIdx.y * gridDim.x + blockIdx.x;
    int qq = nwg >> 3, rr = nwg & 7;
    int xcd = orig & 7, idx = orig >> 3;
    int wg = (xcd < rr ? xcd * (qq + 1) : rr * (qq + 1) + (xcd - rr) * qq) + idx;
    int bx = wg % gridDim.x, by = wg / gridDim.x;

    const int t = threadIdx.x;
    const int lane = t & 63, wid = t >> 6;
    const int wm = wid >> 1, wn = wid & 1;      // 4 x 2 wave grid (32x32 per wave)
    const int rA = lane & 15, g16 = lane >> 4;
    const int row0 = by * 128, col0 = bx * 64;
    const unsigned short* Abase = A + (size_t)row0 * lda;
    const unsigned short* Wbase = W + (size_t)col0 * ldw;

    const int nt = K >> 6;
    f32x4 acc[2][2] = {};

    // prologue: stage tiles 0,1 into slots 0,1 (3 loads per thread each)
    n64_stage(Abase, lda, Wbase, ldw, smem, t, wid);
    n64_stage(Abase + 64, lda, Wbase + 64, ldw, smem + N64SLOT, t, wid);

#define NBAR() asm volatile("s_barrier" ::: "memory")
#define NITER(T, STG, VMSTR)                                                         \
    do {                                                                             \
        NBAR(); /* all waves done reading slot (T+2)%3 (tile T-1's compute) */       \
        if (STG)                                                                     \
            n64_stage(Abase + (size_t)(T + 2) * 64, lda, Wbase + (size_t)(T + 2) * 64,\
                      ldw, smem + (size_t)((T + 2) % 3) * N64SLOT, t, wid);          \
        asm volatile(VMSTR ::: "memory"); /* tile T landed (per-wave) */             \
        NBAR(); /* tile T visible to all waves */                                    \
        n64_compute(smem + (size_t)((T) % 3) * N64SLOT, wm, wn, rA, g16, acc);       \
    } while (0)

    int tt = 0;
    for (; tt < nt - 2; ++tt) NITER(tt, true, "s_waitcnt vmcnt(6)");
    NITER(tt, false, "s_waitcnt vmcnt(3)");
    ++tt;
    NITER(tt, false, "s_waitcnt vmcnt(0)");
#undef NITER
#undef NBAR

    const int cl = lane & 15, rg = (lane >> 4) * 4;
#pragma unroll
    for (int n = 0; n < 2; ++n) {
        int gc = col0 + wn * 32 + n * 16 + cl;
        float bv = bias ? bias[gc] : 0.0f;
#pragma unroll
        for (int m = 0; m < 2; ++m) {
#pragma unroll
            for (int i = 0; i < 4; ++i) {
                int gr = row0 + wm * 32 + m * 16 + rg + i;
                float v = acc[m][n][i] + bv;
                if (res) v += res[(size_t)gr * ldc + gc];
                C[(size_t)gr * ldc + gc] = v;
            }
        }
    }
}

// ---------------------------------------------------------------------------
// Mid bf16 MFMA GEMM (qkvg, W1): BM=128, BN=128, BK=64, 512 threads
// (8 waves 2x4, 64x32 out per wave), 2 LDS slots of 32 KB, 2 blocks/CU.
// SCATTER=1 (qkvg): q cols [0,768) -> qT[b,h,s,d], k cols [768,1536) ->
// kT[b,h,s,d]; v,g cols >= 1536 written to Cb normally.
// ---------------------------------------------------------------------------
#define MDSLOT 32768  /* 32 KB per slot: A 16KB @0, B 16KB @16384 */

__device__ __forceinline__ void md_stage(const unsigned short* __restrict__ Ab, int lda,
                                         const unsigned short* __restrict__ Wb, int ldw,
                                         unsigned char* slot, int t, int wid) {
    int rit = t >> 3;             // 0..63
    int kb = (t & 7) << 4;
#pragma unroll
    for (int c = 0; c < 2; ++c) { // A: 128 rows
        int row = c * 64 + rit;
        int gkb = kb ^ ((row & 7) << 4);
        const unsigned short* src = Ab + (size_t)row * lda + (gkb >> 1);
        unsigned char* dst = slot + c * 8192 + wid * 1024;
        __builtin_amdgcn_global_load_lds(
            (const __attribute__((address_space(1))) void*)src,
            (__attribute__((address_space(3))) void*)dst, 16, 0, 0);
    }
#pragma unroll
    for (int c = 0; c < 2; ++c) { // B: 128 rows
        int row = c * 64 + rit;
        int gkb = kb ^ ((row & 7) << 4);
        const unsigned short* src = Wb + (size_t)row * ldw + (gkb >> 1);
        unsigned char* dst = slot + 16384 + c * 8192 + wid * 1024;
        __builtin_amdgcn_global_load_lds(
            (const __attribute__((address_space(1))) void*)src,
            (__attribute__((address_space(3))) void*)dst, 16, 0, 0);
    }
}

__device__ __forceinline__ void md_compute(const unsigned char* slot, int wm, int wn,
                                           int rA, int g16, f32x4 acc[4][2]) {
    const unsigned char* Ab = slot;
    const unsigned char* Bb = slot + 16384;
    bf16x8 a[4][2], b[2][2];
#pragma unroll
    for (int m = 0; m < 4; ++m) {
        int row = wm * 64 + m * 16 + rA;
        int sw = (row & 7) << 4;
#pragma unroll
        for (int s = 0; s < 2; ++s)
            a[m][s] = *(const bf16x8*)(Ab + row * 128 + ((s * 64 + g16 * 16) ^ sw));
    }
#pragma unroll
    for (int n = 0; n < 2; ++n) {
        int row = wn * 32 + n * 16 + rA;
        int sw = (row & 7) << 4;
#pragma unroll
        for (int s = 0; s < 2; ++s)
            b[n][s] = *(const bf16x8*)(Bb + row * 128 + ((s * 64 + g16 * 16) ^ sw));
    }
    __builtin_amdgcn_s_setprio(1);
#pragma unroll
    for (int m = 0; m < 4; ++m)
#pragma unroll
        for (int n = 0; n < 2; ++n) {
            acc[m][n] = __builtin_amdgcn_mfma_f32_16x16x32_bf16(a[m][0], b[n][0], acc[m][n], 0, 0, 0);
            acc[m][n] = __builtin_amdgcn_mfma_f32_16x16x32_bf16(a[m][1], b[n][1], acc[m][n], 0, 0, 0);
        }
    __builtin_amdgcn_s_setprio(0);
}

template <int SCATTER>
__global__ __launch_bounds__(512) void k_gemm_mid(const unsigned short* __restrict__ A, int lda,
                                                  const unsigned short* __restrict__ W,
                                                  const unsigned short* __restrict__ Wb2, int ldw,
                                                  unsigned short* __restrict__ Cb, int ldc,
                                                  int M, int N, int K,
                                                  const float* __restrict__ bias,
                                                  const float* __restrict__ bias2,
                                                  unsigned short* __restrict__ qT,
                                                  unsigned short* __restrict__ kT) {
    extern __shared__ unsigned char smem[];
    int nwg = gridDim.x * gridDim.y;
    int orig = blockIdx.y * gridDim.x + blockIdx.x;
    int qq = nwg >> 3, rr = nwg & 7;
    int xcd = orig & 7, idx = orig >> 3;
    int wg = (xcd < rr ? xcd * (qq + 1) : rr * (qq + 1) + (xcd - rr) * qq) + idx;
    int bx = wg % gridDim.x, by = wg / gridDim.x;

    const int t = threadIdx.x;
    const int lane = t & 63, wid = t >> 6;
    const int wm = wid >> 2, wn = wid & 3;
    const int rA = lane & 15, g16 = lane >> 4;
    const int row0 = by * 128, col0 = bx * 128;
    const unsigned short* Abase = A + (size_t)row0 * lda;
    const unsigned short* Wbase = (Wb2 && col0 >= 1536)
                                      ? Wb2 + (size_t)(col0 - 1536) * ldw
                                      : W + (size_t)col0 * ldw;

    const int nt = K >> 6;
    f32x4 acc[4][2] = {};

    md_stage(Abase, lda, Wbase, ldw, smem, t, wid);

    for (int tt = 0; tt < nt; ++tt) {
        asm volatile("s_barrier" ::: "memory");
        if (tt + 1 < nt) {
            md_stage(Abase + (size_t)(tt + 1) * 64, lda, Wbase + (size_t)(tt + 1) * 64,
                     ldw, smem + (size_t)((tt + 1) & 1) * MDSLOT, t, wid);
            asm volatile("s_waitcnt vmcnt(4)" ::: "memory");
        } else {
            asm volatile("s_waitcnt vmcnt(0)" ::: "memory");
        }
        asm volatile("s_barrier" ::: "memory");
        md_compute(smem + (size_t)(tt & 1) * MDSLOT, wm, wn, rA, g16, acc);
    }

    const int cl = lane & 15, rg = (lane >> 4) * 4;
#pragma unroll
    for (int n = 0; n < 2; ++n) {
        int gc = col0 + wn * 32 + n * 16 + cl;
        float bv = 0.0f;
        if (bias) bv = (bias2 && gc >= 1536) ? bias2[gc - 1536] : bias[gc];
        if (SCATTER && gc < 1536) {
            int isk = gc >= HH;
            unsigned short* dst = isk ? kT : qT;
            int h = (isk ? gc - HH : gc) >> 6;
            int d = gc & 63;
#pragma unroll
            for (int m = 0; m < 4; ++m) {
#pragma unroll
                for (int i = 0; i < 4; ++i) {
                    int gr = row0 + wm * 64 + m * 16 + rg + i;
                    int s = gr >> 3, b = gr & 7;
                    dst[(((size_t)(b * NHH + h)) * SS + s) * DD + d] = f2b(acc[m][n][i] + bv);
                }
            }
        } else {
#pragma unroll
            for (int m = 0; m < 4; ++m) {
#pragma unroll
                for (int i = 0; i < 4; ++i) {
                    int gr = row0 + wm * 64 + m * 16 + rg + i;
                    Cb[(size_t)gr * ldc + gc] = f2b(acc[m][n][i] + bv);
                }
            }
        }
    }
}

// ---------------------------------------------------------------------------
// merged: v-transpose repack (blockIdx.x<8) + cp/pc MFMA (blockIdx.x>=8)
// ---------------------------------------------------------------------------
__global__ __launch_bounds__(256) void k_repack_cppc(const unsigned short* __restrict__ qkvg,
                                                     const unsigned short* __restrict__ pp,
                                                     const unsigned short* __restrict__ qT,
                                                     const unsigned short* __restrict__ kT,
                                                     unsigned short* __restrict__ vT,
                                                     float* __restrict__ cp,
                                                     float* __restrict__ pc) {
    __shared__ unsigned char shmem[12288];
    int t = threadIdx.x;
    if (blockIdx.x < 8) {
        unsigned short (*tile)[72] = (unsigned short(*)[72])shmem;
        int bh = blockIdx.y;
        int b = bh / NHH, h = bh % NHH;
        int s0 = blockIdx.x * 64;
#pragma unroll
        for (int j = 0; j < 4; ++j) {
            int idx = t + j * 256;
            int r = idx >> 4, c4 = idx & 15;
            ushort4 u = *(const ushort4*)(qkvg + ((size_t)(s0 + r) * BB + b) * 3072 + 1536 + h * DD + c4 * 4);
            *(ushort4*)&tile[r][c4 * 4] = u;
        }
        __syncthreads();
#pragma unroll
        for (int j = 0; j < 2; ++j) {
            int idx = t + j * 256;
            int d = idx >> 3, s8 = idx & 7;
            ushort4 a, c;
            a.x = tile[s8 * 8 + 0][d]; a.y = tile[s8 * 8 + 1][d];
            a.z = tile[s8 * 8 + 2][d]; a.w = tile[s8 * 8 + 3][d];
            c.x = tile[s8 * 8 + 4][d]; c.y = tile[s8 * 8 + 5][d];
            c.z = tile[s8 * 8 + 6][d]; c.w = tile[s8 * 8 + 7][d];
            unsigned short* dst = vT + ((size_t)bh * DD + d) * SS + s0 + s8 * 8;
            *(ushort4*)dst = a; *(ushort4*)(dst + 4) = c;
        }
    } else {
        int cid = (blockIdx.x - 8) * 96 + blockIdx.y;
        int z = cid >= 384;
        int rem = cid - (z ? 384 : 0);
        int h = rem >> 5;
        int mt = rem & 31;
        int toff = z ? 0 : HH;
        float* out = z ? pc : cp;
        const unsigned short* srcbase = z ? kT : qT;
        unsigned short* As = (unsigned short*)shmem;
        unsigned short* Bs = (unsigned short*)(shmem + 8192);
        const int lane = t & 63, wid = t >> 6;
        const int rA = lane & 15, kA = (lane >> 4) * 8;

        f32x4 acc[2][4] = {};

        for (int k0 = 0; k0 < 64; k0 += 32) {
#pragma unroll
            for (int j = 0; j < 2; ++j) {
                int c = t + j * 256;
                int r = c >> 2, ko = (c & 3) * 8;
                int row = mt * 128 + r;
                int s = row >> 3, b = row & 7;
                const unsigned short* srcA =
                    srcbase + (((size_t)(b * NHH + h)) * SS + s) * DD + k0 + ko;
                unsigned short* dstA = As + (size_t)(j * 256 + wid * 64) * 8;
                __builtin_amdgcn_global_load_lds(
                    (const __attribute__((address_space(1))) void*)srcA,
                    (__attribute__((address_space(3))) void*)dstA, 16, 0, 0);
            }
            {
                int r = t >> 2, ko = (t & 3) * 8;
                const unsigned short* srcB = pp + (size_t)r * 1536 + toff + h * DD + k0 + ko;
                unsigned short* dstB = Bs + (size_t)(wid * 64) * 8;
                __builtin_amdgcn_global_load_lds(
                    (const __attribute__((address_space(1))) void*)srcB,
                    (__attribute__((address_space(3))) void*)dstB, 16, 0, 0);
            }
            __syncthreads();
            bf16x8 af[2], bfr[4];
#pragma unroll
            for (int m = 0; m < 2; ++m)
                af[m] = *(const bf16x8*)&As[(wid * 32 + m * 16 + rA) * 32 + kA];
#pragma unroll
            for (int n = 0; n < 4; ++n)
                bfr[n] = *(const bf16x8*)&Bs[(n * 16 + rA) * 32 + kA];
#pragma unroll
            for (int m = 0; m < 2; ++m)
#pragma unroll
                for (int n = 0; n < 4; ++n)
                    acc[m][n] = __builtin_amdgcn_mfma_f32_16x16x32_bf16(af[m], bfr[n], acc[m][n], 0, 0, 0);
            __syncthreads();
        }

        const int cl = lane & 15, rg = (lane >> 4) * 4;
#pragma unroll
        for (int m = 0; m < 2; ++m)
#pragma unroll
            for (int n = 0; n < 4; ++n) {
                int gc = n * 16 + cl;
                if (gc < 63) {
#pragma unroll
                    for (int i = 0; i < 4; ++i) {
                        int gr = mt * 128 + wid * 32 + m * 16 + rg + i;
                        int sIdx = gr >> 3, bIdx = gr & 7;
                        out[(((size_t)(bIdx * NHH + h)) * SS + sIdx) * 63 + gc] = acc[m][n][i];
                    }
                }
            }
    }
}

// ---------------------------------------------------------------------------
// fused disentangled flash attention v5: no-max softmax (round-16 proven)
// ---------------------------------------------------------------------------
__global__ __launch_bounds__(256) void k_attn_fused(
    const unsigned short* __restrict__ qT, const unsigned short* __restrict__ kT,
    const unsigned short* __restrict__ vT, const float* __restrict__ cp,
    const float* __restrict__ pc, const int* __restrict__ bucket,
    const int* __restrict__ mask, float* __restrict__ ctxr) {
    __shared__ float cps[64 * 63];
    __shared__ float pcs[64 * 63];
    __shared__ unsigned short pb_all[4][16 * 72];
    __shared__ int btab[1023];
    int t = threadIdx.x;
    int lane = t & 63, wid = t >> 6;
    int bh = blockIdx.y;
    int b = bh / NHH, h = bh % NHH;
    int qb0 = blockIdx.x * 64;
    int q0 = qb0 + wid * 16;
    int rA = lane & 15, g = lane >> 4, kA = g * 8;
    unsigned short* pb = pb_all[wid];
    const unsigned short* qTb = qT + (size_t)bh * SS * DD;
    const unsigned short* kTb = kT + (size_t)bh * SS * DD;
    const unsigned short* vTb = vT + (size_t)bh * DD * SS;
    const float* cpb = cp + (size_t)bh * SS * 63 + (size_t)qb0 * 63;
    const float* pcb = pc + (size_t)bh * SS * 63;
    const int* mkb = mask + b * SS;

    for (int i = t; i < 1023; i += 256) btab[i] = bucket[i];
    for (int i = t; i < 1008; i += 256) ((float4*)cps)[i] = ((const float4*)cpb)[i];

    bf16x8 aq[2];
#pragma unroll
    for (int dc = 0; dc < 2; ++dc)
        aq[dc] = *(const bf16x8*)&qTb[(size_t)(q0 + rA) * DD + dc * 32 + kA];

    f32x4 o[4] = {};
    float lrow[4];
#pragma unroll
    for (int i = 0; i < 4; ++i) lrow[i] = 0.f;

    for (int kt = 0; kt < 8; ++kt) {
        int k0 = kt * 64;
        __syncthreads();
        {
            const float4* src = (const float4*)(pcb + (size_t)k0 * 63);
            for (int i = t; i < 1008; i += 256) ((float4*)pcs)[i] = src[i];
        }
        f32x4 sa[4] = {};
#pragma unroll
        for (int n = 0; n < 4; ++n) {
            bf16x8 bk0 = *(const bf16x8*)&kTb[(size_t)(k0 + n * 16 + rA) * DD + kA];
            bf16x8 bk1 = *(const bf16x8*)&kTb[(size_t)(k0 + n * 16 + rA) * DD + 32 + kA];
            sa[n] = __builtin_amdgcn_mfma_f32_16x16x32_bf16(aq[0], bk0, sa[n], 0, 0, 0);
            sa[n] = __builtin_amdgcn_mfma_f32_16x16x32_bf16(aq[1], bk1, sa[n], 0, 0, 0);
        }
        int mk[4];
#pragma unroll
        for (int n = 0; n < 4; ++n) mk[n] = mkb[k0 + n * 16 + rA];
        __syncthreads();

        float pv[4][4];
#pragma unroll
        for (int i = 0; i < 4; ++i) {
            int qr = wid * 16 + g * 4 + i;
            int q = qb0 + qr;
            float ls = 0.f;
#pragma unroll
            for (int n = 0; n < 4; ++n) {
                int kr = n * 16 + rA;
                int id = btab[q - (k0 + kr) + 511];
                float v = (sa[n][i] + cps[qr * 63 + id] + pcs[kr * 63 + id]) * SCALE_F;
                v = mk[n] ? -1e9f : v;
                float p = __expf(v);
                pv[n][i] = p;
                ls += p;
            }
            ls += __shfl_xor(ls, 1, 16);
            ls += __shfl_xor(ls, 2, 16);
            ls += __shfl_xor(ls, 4, 16);
            ls += __shfl_xor(ls, 8, 16);
            lrow[i] += ls;
        }
#pragma unroll
        for (int n = 0; n < 4; ++n)
#pragma unroll
            for (int i = 0; i < 4; ++i)
                pb[(g * 4 + i) * 72 + n * 16 + rA] = f2b(pv[n][i]);
        bf16x8 ap[2];
#pragma unroll
        for (int kc = 0; kc < 2; ++kc)
            ap[kc] = *(const bf16x8*)&pb[rA * 72 + kc * 32 + kA];
#pragma unroll
        for (int n = 0; n < 4; ++n) {
            bf16x8 bv0 = *(const bf16x8*)&vTb[(size_t)(n * 16 + rA) * SS + k0 + kA];
            bf16x8 bv1 = *(const bf16x8*)&vTb[(size_t)(n * 16 + rA) * SS + k0 + 32 + kA];
            o[n] = __builtin_amdgcn_mfma_f32_16x16x32_bf16(ap[0], bv0, o[n], 0, 0, 0);
            o[n] = __builtin_amdgcn_mfma_f32_16x16x32_bf16(ap[1], bv1, o[n], 0, 0, 0);
        }
    }
#pragma unroll
    for (int i = 0; i < 4; ++i) {
        int q = q0 + g * 4 + i;
        float inv = 1.0f / lrow[i];
#pragma unroll
        for (int n = 0; n < 4; ++n)
            ctxr[((size_t)q * BB + b) * HH + h * DD + n * 16 + rA] = o[n][i] * inv;
    }
}

// ---------------------------------------------------------------------------
// host launcher
// ---------------------------------------------------------------------------
extern "C" void kernel_launch(void* const* d_in, const int* in_sizes, int n_in,
                              void* d_out, int out_size, void* d_ws, size_t ws_size,
                              hipStream_t stream) {
    static int attr_done = 0;
    if (!attr_done) {
        hipFuncSetAttribute((const void*)&k_gemm_mid<0>,
                            hipFuncAttributeMaxDynamicSharedMemorySize, 2 * MDSLOT);
        hipFuncSetAttribute((const void*)&k_gemm_mid<1>,
                            hipFuncAttributeMaxDynamicSharedMemorySize, 2 * MDSLOT);
        hipFuncSetAttribute((const void*)&k_gemm_n64,
                            hipFuncAttributeMaxDynamicSharedMemorySize, 3 * N64SLOT);
        attr_done = 1;
    }

    const int* ids = (const int*)d_in[0];
    const unsigned char* maskraw = (const unsigned char*)d_in[1];
    const float* word_emb = (const float*)d_in[2];
    const float* rel_emb = (const float*)d_in[3];
    const float* rel_g = (const float*)d_in[4];
    const float* rel_b = (const float*)d_in[5];
    const float* Wqk = (const float*)d_in[6];
    const float* bqk = (const float*)d_in[7];
    const float* Wvg = (const float*)d_in[8];
    const float* bvg = (const float*)d_in[9];
    const float* Wout = (const float*)d_in[10];
    const float* bout = (const float*)d_in[11];
    const float* W1 = (const float*)d_in[12];
    const float* W2 = (const float*)d_in[13];

    const size_t N_X = (size_t)SS * BB * HH;
    const size_t N_CP = (size_t)SS * BB * NHH * 63;
    const size_t N_H2 = (size_t)SS * BB * II;
    const size_t N_WQK = (size_t)2 * HH * HH;
    const size_t N_WOUT = (size_t)HH * HH;
    const size_t N_W1 = (size_t)2 * II * HH;
    const size_t N_W2 = (size_t)HH * II;
    const size_t N_HD = (size_t)BB * NHH * SS * DD;
    const size_t N_QKVG = (size_t)SS * BB * 3072;
    const size_t N_FFH = (size_t)SS * BB * 4096;
    const size_t N_PP = (size_t)128 * 1536;

    float* ws = (float*)d_ws;
    float* x = ws;
    float* ctxr = x + N_X;
    float* cp = ctxr + N_X;
    float* pc = cp + N_CP;
    unsigned short* us = (unsigned short*)(pc + N_CP);
    unsigned short* qkvg = us;
    unsigned short* hs_bf = qkvg + N_QKVG;
    unsigned short* ctx_bf = hs_bf + N_X;
    unsigned short* h2_bf = ctx_bf + N_X;
    unsigned short* ffh = h2_bf + N_H2;
    unsigned short* wqk_all = ffh + N_FFH;
    unsigned short* wvg_bf = wqk_all + 12 * N_WQK;
    unsigned short* wout_bf = wvg_bf + N_WQK;
    unsigned short* w1_bf = wout_bf + N_WOUT;
    unsigned short* w2_bf = w1_bf + N_W1;
    unsigned short* ppall = w2_bf + N_W2;
    unsigned short* rel_bf = ppall + 12 * N_PP;
    unsigned short* qT = rel_bf + 128 * HH;
    unsigned short* kT = qT + N_HD;
    unsigned short* vT = kT + N_HD;
    int* bucket = (int*)(vT + N_HD);
    int* maski = bucket + 1024;

    size_t need_bytes = ((size_t)(maski + BB * SS) - (size_t)d_ws);
    if (ws_size < need_bytes) return;  // ~205 MB required

    // ---- setup ----
    k_decode_mask<<<1, 256, 0, stream>>>(maskraw, maski, BB * SS);
    k_bucket<<<4, 256, 0, stream>>>(bucket);
    k_embed_ln<<<SS * BB, 256, 0, stream>>>(ids, word_emb, x);
    k_rel_ln_bf<<<128, 256, 0, stream>>>(rel_emb, rel_g, rel_b, rel_bf);
    k_f2b<<<(int)((12 * N_WQK / 8 + 255) / 256), 256, 0, stream>>>(Wqk, wqk_all,
                                                                   (int)(12 * N_WQK / 8));
    {
        dim3 gpp(1536 / 128, 1, 12);
        k_gemm_bf16<1><<<gpp, 256, 0, stream>>>(rel_bf, HH, wqk_all, HH, ppall, 1536,
                                                128, 1536, HH, bqk, nullptr, nullptr,
                                                N_WQK, N_PP, 2 * HH);
    }

    for (int l = 0; l < LL; ++l) {
        const unsigned short* wqk_l = wqk_all + (size_t)l * N_WQK;
        const float* bqk_l = bqk + (size_t)l * 2 * HH;
        const float* Wvg_l = Wvg + (size_t)l * N_WQK;
        const float* bvg_l = bvg + (size_t)l * 2 * HH;
        const float* Wout_l = Wout + (size_t)l * N_WOUT;
        const float* bout_l = bout + (size_t)l * HH;
        const float* W1_l = W1 + (size_t)l * N_W1;
        const float* W2_l = W2 + (size_t)l * N_W2;

        // ---- attention ----
        k_f2b_ln<<<3169 + SS * BB, 256, 0, stream>>>(Wvg_l, Wout_l, W1_l, W2_l, wvg_bf,
                                                     x, hs_bf);
        {
            dim3 g(3072 / 128, SS * BB / 128);
            k_gemm_mid<1><<<g, 512, 2 * MDSLOT, stream>>>(hs_bf, HH, wqk_l, wvg_bf, HH,
                                                          qkvg, 3072, SS * BB, 3072, HH,
                                                          bqk_l, bvg_l, qT, kT);
        }
        k_repack_cppc<<<dim3(16, 96), 256, 0, stream>>>(qkvg, ppall + (size_t)l * N_PP,
                                                        qT, kT, vT, cp, pc);
        k_attn_fused<<<dim3(SS / 64, BB * NHH), 256, 0, stream>>>(qT, kT, vT, cp, pc,
                                                                  bucket, maski, ctxr);
        k_gated_ln<<<SS * BB, 256, 0, stream>>>(ctxr, qkvg, ctx_bf);
        k_gemm_n64<<<dim3(HH / 64, SS * BB / 128), 512, 3 * N64SLOT, stream>>>(
            ctx_bf, HH, wout_bf, HH, x, HH, SS * BB, HH, HH, bout_l, x);

        // ---- GeGLU FFN ----
        k_ln_bf<<<SS * BB, 256, 0, stream>>>(x, hs_bf);
        {
            dim3 g(4096 / 128, SS * BB / 128);
            k_gemm_mid<0><<<g, 512, 2 * MDSLOT, stream>>>(hs_bf, HH, w1_bf, nullptr, HH,
                                                          ffh, 4096, SS * BB, 4096, HH,
                                                          nullptr, nullptr, nullptr, nullptr);
        }
        k_ffn_ln<<<SS * BB, 256, 0, stream>>>(ffh, h2_bf);
        // last layer writes the residual-added output straight into d_out
        float* outC = (l == LL - 1) ? (float*)d_out : x;
        k_gemm_n64<<<dim3(HH / 64, SS * BB / 128), 512, 3 * N64SLOT, stream>>>(
            h2_bf, II, w2_bf, II, outC, HH, SS * BB, HH, II, nullptr, x);
    }
}

// Round 18
// 2597.688 us; speedup vs baseline: 1.0887x; 1.0003x over previous
//
#include <hip/hip_runtime.h>
#include <math.h>

#define SS 512
#define BB 8
#define NHH 12
#define DD 64
#define HH 768
#define II 2048
#define LL 12
#define SCALE_F 0.07216878364870323f  /* 1/sqrt(3*64) */

typedef __attribute__((ext_vector_type(8))) short bf16x8;
typedef __attribute__((ext_vector_type(4))) float f32x4;

// f32 -> bf16 (RNE, finite values)
__device__ __forceinline__ unsigned short f2b(float f) {
    union { float f; unsigned int u; } x; x.f = f;
    unsigned int r = x.u + 0x7fffu + ((x.u >> 16) & 1u);
    return (unsigned short)(r >> 16);
}
__device__ __forceinline__ float b2f(unsigned short u) {
    union { unsigned int u; float f; } x; x.u = ((unsigned int)u) << 16;
    return x.f;
}

// ---------------------------------------------------------------------------
// block reduction helpers (blockDim.x == 256)
// ---------------------------------------------------------------------------
__device__ __forceinline__ float2 blockReduceSum2(float a, float b) {
    __shared__ float2 sm[4];
    __shared__ float2 bc;
#pragma unroll
    for (int o = 32; o > 0; o >>= 1) {
        a += __shfl_down(a, o);
        b += __shfl_down(b, o);
    }
    int t = threadIdx.x;
    if ((t & 63) == 0) sm[t >> 6] = make_float2(a, b);
    __syncthreads();
    if (t == 0) {
        float xa = sm[0].x + sm[1].x + sm[2].x + sm[3].x;
        float xb = sm[0].y + sm[1].y + sm[2].y + sm[3].y;
        bc = make_float2(xa, xb);
    }
    __syncthreads();
    return bc;
}

__device__ __forceinline__ float gelu_erf(float v) {
    return 0.5f * v * (1.0f + erff(v * 0.70710678118654752f));
}
__device__ __forceinline__ float gelu_tanh(float v) {
    const float c = 0.7978845608028654f;
    return 0.5f * v * (1.0f + tanhf(c * (v + 0.044715f * v * v * v)));
}

// ---------------------------------------------------------------------------
// mask decode: handle bool-as-u8 or bool-as-int32 layouts
// ---------------------------------------------------------------------------
__global__ __launch_bounds__(256) void k_decode_mask(const unsigned char* __restrict__ raw,
                                                     int* __restrict__ mask, int n) {
    __shared__ int s_any;
    if (threadIdx.x == 0) s_any = 0;
    __syncthreads();
    int local = 0;
    for (int i = threadIdx.x; i < n; i += blockDim.x)
        if ((i & 3) && raw[i]) local = 1;
    if (local) atomicOr(&s_any, 1);
    __syncthreads();
    bool isU8 = (s_any != 0);
    const int* as_int = (const int*)raw;
    for (int i = threadIdx.x; i < n; i += blockDim.x)
        mask[i] = isU8 ? (raw[i] != 0) : (as_int[i] != 0);
}

// ---------------------------------------------------------------------------
// DeBERTa log-bucket table: rel in [-511,511] -> idx in [0,62]
// ---------------------------------------------------------------------------
__global__ __launch_bounds__(256) void k_bucket(int* __restrict__ tab) {
    int i = blockIdx.x * 256 + threadIdx.x;
    if (i >= 1023) return;
    int rel = i - 511;
    int a = rel < 0 ? -rel : rel;
    int abs_pos = (a < 16) ? 15 : (a < 511 ? a : 511);
    int bucket;
    if (abs_pos <= 16) {
        bucket = rel;
    } else {
        double lp = ceil(log((double)abs_pos / 16.0) / log(511.0 / 16.0) * 15.0);
        int l = (int)lp + 16;
        bucket = (rel > 0) ? l : -l;
    }
    int idx = bucket + 31;
    if (idx < 0) idx = 0;
    if (idx > 62) idx = 62;
    tab[i] = idx;
}

// ---------------------------------------------------------------------------
// generic f32 -> bf16 bulk conversion (8 elems/thread)
// ---------------------------------------------------------------------------
__global__ __launch_bounds__(256) void k_f2b(const float* __restrict__ in,
                                             unsigned short* __restrict__ out, int n8) {
    int i = blockIdx.x * 256 + threadIdx.x;
    if (i >= n8) return;
    float4 a = ((const float4*)in)[2 * (size_t)i];
    float4 b = ((const float4*)in)[2 * (size_t)i + 1];
    ushort4 lo, hi;
    lo.x = f2b(a.x); lo.y = f2b(a.y); lo.z = f2b(a.z); lo.w = f2b(a.w);
    hi.x = f2b(b.x); hi.y = f2b(b.y); hi.z = f2b(b.z); hi.w = f2b(b.w);
    ((ushort4*)out)[2 * (size_t)i] = lo;
    ((ushort4*)out)[2 * (size_t)i + 1] = hi;
}

// ---------------------------------------------------------------------------
// merged: per-layer weight conversion (blocks 0..3168) + LN of x (blocks 3169..7264)
// ---------------------------------------------------------------------------
__global__ __launch_bounds__(256) void k_f2b_ln(const float* __restrict__ wvg,
                                                const float* __restrict__ wout,
                                                const float* __restrict__ w1,
                                                const float* __restrict__ w2,
                                                unsigned short* __restrict__ wbf,
                                                const float* __restrict__ x,
                                                unsigned short* __restrict__ hs) {
    int bid = blockIdx.x;
    int t = threadIdx.x;
    if (bid < 3169) {
        int i = bid * 256 + t;
        if (i >= 811008) return;
        const float* src;
        int off;
        if (i < 221184) {
            if (i < 147456) { src = wvg;  off = i; }
            else            { src = wout; off = i - 147456; }
        } else if (i < 614400) { src = w1; off = i - 221184; }
        else                   { src = w2; off = i - 614400; }
        float4 a = ((const float4*)src)[2 * (size_t)off];
        float4 b = ((const float4*)src)[2 * (size_t)off + 1];
        ushort4 lo, hi;
        lo.x = f2b(a.x); lo.y = f2b(a.y); lo.z = f2b(a.z); lo.w = f2b(a.w);
        hi.x = f2b(b.x); hi.y = f2b(b.y); hi.z = f2b(b.z); hi.w = f2b(b.w);
        ((ushort4*)wbf)[2 * (size_t)i] = lo;
        ((ushort4*)wbf)[2 * (size_t)i + 1] = hi;
    } else {
        int row = bid - 3169;
        const float* r = x + (size_t)row * HH;
        float v0 = r[t], v1 = r[t + 256], v2 = r[t + 512];
        float s = v0 + v1 + v2;
        float ss = v0 * v0 + v1 * v1 + v2 * v2;
        float2 r2 = blockReduceSum2(s, ss);
        float mean = r2.x * (1.0f / HH);
        float var = r2.y * (1.0f / HH) - mean * mean;
        float rs = rsqrtf(var + 1e-7f);
        unsigned short* o = hs + (size_t)row * HH;
        o[t] = f2b((v0 - mean) * rs);
        o[t + 256] = f2b((v1 - mean) * rs);
        o[t + 512] = f2b((v2 - mean) * rs);
    }
}

// ---------------------------------------------------------------------------
// LayerNorm family; EPS = 1e-7, biased variance
// ---------------------------------------------------------------------------
__global__ __launch_bounds__(256) void k_ln_bf(const float* __restrict__ in,
                                               unsigned short* __restrict__ out) {
    int row = blockIdx.x, t = threadIdx.x;
    const float* r = in + (size_t)row * HH;
    float v0 = r[t], v1 = r[t + 256], v2 = r[t + 512];
    float s = v0 + v1 + v2;
    float ss = v0 * v0 + v1 * v1 + v2 * v2;
    float2 r2 = blockReduceSum2(s, ss);
    float mean = r2.x * (1.0f / HH);
    float var = r2.y * (1.0f / HH) - mean * mean;
    float rs = rsqrtf(var + 1e-7f);
    unsigned short* o = out + (size_t)row * HH;
    o[t] = f2b((v0 - mean) * rs);
    o[t + 256] = f2b((v1 - mean) * rs);
    o[t + 512] = f2b((v2 - mean) * rs);
}

__global__ __launch_bounds__(256) void k_embed_ln(const int* __restrict__ ids,
                                                  const float* __restrict__ emb,
                                                  float* __restrict__ out) {
    int row = blockIdx.x, t = threadIdx.x;
    const float* r = emb + (size_t)ids[row] * HH;
    float v0 = r[t], v1 = r[t + 256], v2 = r[t + 512];
    float s = v0 + v1 + v2;
    float ss = v0 * v0 + v1 * v1 + v2 * v2;
    float2 r2 = blockReduceSum2(s, ss);
    float mean = r2.x * (1.0f / HH);
    float var = r2.y * (1.0f / HH) - mean * mean;
    float rs = rsqrtf(var + 1e-7f);
    float* o = out + (size_t)row * HH;
    o[t] = (v0 - mean) * rs;
    o[t + 256] = (v1 - mean) * rs;
    o[t + 512] = (v2 - mean) * rs;
}

// rel LN -> bf16, padded to 128 rows (rows 63..127 zero)
__global__ __launch_bounds__(256) void k_rel_ln_bf(const float* __restrict__ rel_emb,
                                                   const float* __restrict__ g,
                                                   const float* __restrict__ b,
                                                   unsigned short* __restrict__ out) {
    int row = blockIdx.x, t = threadIdx.x;
    unsigned short* o = out + (size_t)row * HH;
    if (row >= 63) {
        o[t] = 0; o[t + 256] = 0; o[t + 512] = 0;
        return;
    }
    const float* r = rel_emb + (size_t)row * HH;
    float v0 = r[t], v1 = r[t + 256], v2 = r[t + 512];
    float s = v0 + v1 + v2;
    float ss = v0 * v0 + v1 * v1 + v2 * v2;
    float2 r2 = blockReduceSum2(s, ss);
    float mean = r2.x * (1.0f / HH);
    float var = r2.y * (1.0f / HH) - mean * mean;
    float rs = rsqrtf(var + 1e-7f);
    o[t] = f2b((v0 - mean) * rs * g[t] + b[t]);
    o[t + 256] = f2b((v1 - mean) * rs * g[t + 256] + b[t + 256]);
    o[t + 512] = f2b((v2 - mean) * rs * g[t + 512] + b[t + 512]);
}

// ctx_bf = bf16(LN(ctxr * gelu_exact(g))), g = qkvg[..., 2304:3072] (bf16)
__global__ __launch_bounds__(256) void k_gated_ln(const float* __restrict__ ctxr,
                                                  const unsigned short* __restrict__ qkvg,
                                                  unsigned short* __restrict__ out) {
    int row = blockIdx.x, t = threadIdx.x;
    const float* cr = ctxr + (size_t)row * HH;
    const unsigned short* gr = qkvg + (size_t)row * 3072 + 2304;
    float v[3];
    float s = 0.f, ss = 0.f;
#pragma unroll
    for (int e = 0; e < 3; ++e) {
        int i = t + e * 256;
        float x = cr[i] * gelu_erf(b2f(gr[i]));
        v[e] = x;
        s += x; ss += x * x;
    }
    float2 r2 = blockReduceSum2(s, ss);
    float mean = r2.x * (1.0f / HH);
    float var = r2.y * (1.0f / HH) - mean * mean;
    float rs = rsqrtf(var + 1e-7f);
    unsigned short* o = out + (size_t)row * HH;
#pragma unroll
    for (int e = 0; e < 3; ++e) o[t + e * 256] = f2b((v[e] - mean) * rs);
}

// h2_bf = bf16(LN(ffh[:, :I] * gelu_tanh(ffh[:, I:])))  (ffh bf16 [row][4096])
__global__ __launch_bounds__(256) void k_ffn_ln(const unsigned short* __restrict__ ffh,
                                                unsigned short* __restrict__ out) {
    int row = blockIdx.x, t = threadIdx.x;
    const unsigned short* ar = ffh + (size_t)row * 4096 + t * 8;
    const unsigned short* gr = ar + II;
    ushort4 a0 = *(const ushort4*)ar;
    ushort4 a1 = *(const ushort4*)(ar + 4);
    ushort4 g0 = *(const ushort4*)gr;
    ushort4 g1 = *(const ushort4*)(gr + 4);
    float av[8] = {b2f(a0.x), b2f(a0.y), b2f(a0.z), b2f(a0.w),
                   b2f(a1.x), b2f(a1.y), b2f(a1.z), b2f(a1.w)};
    float gv[8] = {b2f(g0.x), b2f(g0.y), b2f(g0.z), b2f(g0.w),
                   b2f(g1.x), b2f(g1.y), b2f(g1.z), b2f(g1.w)};
    float v[8];
    float s = 0.f, ss = 0.f;
#pragma unroll
    for (int e = 0; e < 8; ++e) {
        float x = av[e] * gelu_tanh(gv[e]);
        v[e] = x;
        s += x; ss += x * x;
    }
    float2 r2 = blockReduceSum2(s, ss);
    float mean = r2.x * (1.0f / II);
    float var = r2.y * (1.0f / II) - mean * mean;
    float rs = rsqrtf(var + 1e-7f);
    ushort4 o0, o1;
    o0.x = f2b((v[0] - mean) * rs); o0.y = f2b((v[1] - mean) * rs);
    o0.z = f2b((v[2] - mean) * rs); o0.w = f2b((v[3] - mean) * rs);
    o1.x = f2b((v[4] - mean) * rs); o1.y = f2b((v[5] - mean) * rs);
    o1.z = f2b((v[6] - mean) * rs); o1.w = f2b((v[7] - mean) * rs);
    unsigned short* o = out + (size_t)row * II + t * 8;
    *(ushort4*)o = o0;
    *(ushort4*)(o + 4) = o1;
}

// ---------------------------------------------------------------------------
// bf16 MFMA GEMM — used only for the batched posproj at setup.
// qpos half (cols < 768) pre-scaled by SCALE_F so attn drops its score mul
// (pc = k . (SCALE*qpos) is scaled exactly once).
// ---------------------------------------------------------------------------
template <int OBF>
__global__ __launch_bounds__(256) void k_gemm_bf16(const unsigned short* __restrict__ A, int lda,
                                                   const unsigned short* __restrict__ W, int ldw,
                                                   void* __restrict__ Cv, int ldc,
                                                   int M, int N, int K,
                                                   const float* __restrict__ bias,
                                                   const float* __restrict__ bias2,
                                                   const float* __restrict__ res,
                                                   size_t wz, size_t cz, size_t bz) {
    __shared__ unsigned short As[128 * 32];
    __shared__ unsigned short Ws[128 * 32];
    int zz = blockIdx.z;
    W += (size_t)zz * wz;
    if (bias) bias += (size_t)zz * bz;
    int nwg = gridDim.x * gridDim.y;
    int orig = blockIdx.y * gridDim.x + blockIdx.x;
    int qq = nwg >> 3, rr = nwg & 7;
    int xcd = orig & 7, idx = orig >> 3;
    int wg = (xcd < rr ? xcd * (qq + 1) : rr * (qq + 1) + (xcd - rr) * qq) + idx;
    int bx = wg % gridDim.x, by = wg / gridDim.x;

    const int t = threadIdx.x;
    const int lane = t & 63, wid = t >> 6;
    const int row0 = by * 128, col0 = bx * 128;
    const int wr = (wid >> 1) * 64, wc = (wid & 1) * 64;
    const int rA = lane & 15, kA = (lane >> 4) * 8;

    f32x4 acc[4][4] = {};

    for (int k0 = 0; k0 < K; k0 += 32) {
#pragma unroll
        for (int j = 0; j < 2; ++j) {
            int c = t + j * 256;
            int r = c >> 2, ko = (c & 3) * 8;
            const unsigned short* srcA = A + (size_t)(row0 + r) * lda + k0 + ko;
            const unsigned short* srcB = W + (size_t)(col0 + r) * ldw + k0 + ko;
            unsigned short* dstA = As + (size_t)(j * 256 + wid * 64) * 8;
            unsigned short* dstB = Ws + (size_t)(j * 256 + wid * 64) * 8;
            __builtin_amdgcn_global_load_lds(
                (const __attribute__((address_space(1))) void*)srcA,
                (__attribute__((address_space(3))) void*)dstA, 16, 0, 0);
            __builtin_amdgcn_global_load_lds(
                (const __attribute__((address_space(1))) void*)srcB,
                (__attribute__((address_space(3))) void*)dstB, 16, 0, 0);
        }
        __syncthreads();
        bf16x8 af[4], bfr[4];
#pragma unroll
        for (int m = 0; m < 4; ++m)
            af[m] = *(const bf16x8*)&As[(wr + m * 16 + rA) * 32 + kA];
#pragma unroll
        for (int n = 0; n < 4; ++n)
            bfr[n] = *(const bf16x8*)&Ws[(wc + n * 16 + rA) * 32 + kA];
#pragma unroll
        for (int m = 0; m < 4; ++m)
#pragma unroll
            for (int n = 0; n < 4; ++n)
                acc[m][n] = __builtin_amdgcn_mfma_f32_16x16x32_bf16(af[m], bfr[n], acc[m][n], 0, 0, 0);
        __syncthreads();
    }

    float* Cf = (float*)Cv + (size_t)zz * cz;
    unsigned short* Cb = (unsigned short*)Cv + (size_t)zz * cz;
    const int cl = lane & 15, rg = (lane >> 4) * 4;
#pragma unroll
    for (int n = 0; n < 4; ++n) {
        int gc = col0 + wc + n * 16 + cl;
        float bv = 0.0f;
        if (bias) bv = (bias2 && gc >= 1536) ? bias2[gc - 1536] : bias[gc];
        float scl = (gc < HH) ? SCALE_F : 1.0f;   // qpos half pre-scaled
#pragma unroll
        for (int m = 0; m < 4; ++m) {
#pragma unroll
            for (int i = 0; i < 4; ++i) {
                int gr = row0 + wr + m * 16 + rg + i;
                float v = acc[m][n][i] + bv;
                if (OBF) {
                    Cb[(size_t)gr * ldc + gc] = f2b(v * scl);
                } else {
                    if (res) v += res[(size_t)gr * ldc + gc];
                    Cf[(size_t)gr * ldc + gc] = v;
                }
            }
        }
    }
}

// ---------------------------------------------------------------------------
// N64 bf16 MFMA GEMM for N=768 (Wout, W2): 3-slot depth-2 (round-17 proven)
// ---------------------------------------------------------------------------
#define N64SLOT 24576  /* 24 KB: A 16KB @0, B 8KB @16384 */

__device__ __forceinline__ void n64_stage(const unsigned short* __restrict__ Ab, int lda,
                                          const unsigned short* __restrict__ Wb, int ldw,
                                          unsigned char* slot, int t, int wid) {
    int rit = t >> 3;
    int kb = (t & 7) << 4;
#pragma unroll
    for (int c = 0; c < 2; ++c) {
        int row = c * 64 + rit;
        int gkb = kb ^ ((row & 7) << 4);
        const unsigned short* src = Ab + (size_t)row * lda + (gkb >> 1);
        unsigned char* dst = slot + c * 8192 + wid * 1024;
        __builtin_amdgcn_global_load_lds(
            (const __attribute__((address_space(1))) void*)src,
            (__attribute__((address_space(3))) void*)dst, 16, 0, 0);
    }
    {
        int row = rit;
        int gkb = kb ^ ((row & 7) << 4);
        const unsigned short* src = Wb + (size_t)row * ldw + (gkb >> 1);
        unsigned char* dst = slot + 16384 + wid * 1024;
        __builtin_amdgcn_global_load_lds(
            (const __attribute__((address_space(1))) void*)src,
            (__attribute__((address_space(3))) void*)dst, 16, 0, 0);
    }
}

__device__ __forceinline__ void n64_compute(const unsigned char* slot, int wm, int wn,
                                            int rA, int g16, f32x4 acc[2][2]) {
    const unsigned char* Ab = slot;
    const unsigned char* Bb = slot + 16384;
    bf16x8 a[2][2], b[2][2];
#pragma unroll
    for (int m = 0; m < 2; ++m) {
        int row = wm * 32 + m * 16 + rA;
        int sw = (row & 7) << 4;
#pragma unroll
        for (int s = 0; s < 2; ++s)
            a[m][s] = *(const bf16x8*)(Ab + row * 128 + ((s * 64 + g16 * 16) ^ sw));
    }
#pragma unroll
    for (int n = 0; n < 2; ++n) {
        int row = wn * 32 + n * 16 + rA;
        int sw = (row & 7) << 4;
#pragma unroll
        for (int s = 0; s < 2; ++s)
            b[n][s] = *(const bf16x8*)(Bb + row * 128 + ((s * 64 + g16 * 16) ^ sw));
    }
    __builtin_amdgcn_s_setprio(1);
#pragma unroll
    for (int m = 0; m < 2; ++m)
#pragma unroll
        for (int n = 0; n < 2; ++n) {
            acc[m][n] = __builtin_amdgcn_mfma_f32_16x16x32_bf16(a[m][0], b[n][0], acc[m][n], 0, 0, 0);
            acc[m][n] = __builtin_amdgcn_mfma_f32_16x16x32_bf16(a[m][1], b[n][1], acc[m][n], 0, 0, 0);
        }
    __builtin_amdgcn_s_setprio(0);
}

__global__ __launch_bounds__(512) void k_gemm_n64(const unsigned short* __restrict__ A, int lda,
                                                  const unsigned short* __restrict__ W, int ldw,
                                                  float* __restrict__ C, int ldc,
                                                  int M, int N, int K,
                                                  const float* __restrict__ bias,
                                                  const float* __restrict__ res) {
    extern __shared__ unsigned char smem[];
    int nwg = gridDim.x * gridDim.y;
    int orig = blockIdx.y * gridDim.x + blockIdx.x;
    int qq = nwg >> 3, rr = nwg & 7;
    int xcd = orig & 7, idx = orig >> 3;
    int wg = (xcd < rr ? xcd * (qq + 1) : rr * (qq + 1) + (xcd - rr) * qq) + idx;
    int bx = wg % gridDim.x, by = wg / gridDim.x;

    const int t = threadIdx.x;
    const int lane = t & 63, wid = t >> 6;
    const int wm = wid >> 1, wn = wid & 1;
    const int rA = lane & 15, g16 = lane >> 4;
    const int row0 = by * 128, col0 = bx * 64;
    const unsigned short* Abase = A + (size_t)row0 * lda;
    const unsigned short* Wbase = W + (size_t)col0 * ldw;

    const int nt = K >> 6;
    f32x4 acc[2][2] = {};

    n64_stage(Abase, lda, Wbase, ldw, smem, t, wid);
    n64_stage(Abase + 64, lda, Wbase + 64, ldw, smem + N64SLOT, t, wid);

#define NBAR() asm volatile("s_barrier" ::: "memory")
#define NITER(T, STG, VMSTR)                                                         \
    do {                                                                             \
        NBAR();                                                                      \
        if (STG)                                                                     \
            n64_stage(Abase + (size_t)(T + 2) * 64, lda, Wbase + (size_t)(T + 2) * 64,\
                      ldw, smem + (size_t)((T + 2) % 3) * N64SLOT, t, wid);          \
        asm volatile(VMSTR ::: "memory");                                            \
        NBAR();                                                                      \
        n64_compute(smem + (size_t)((T) % 3) * N64SLOT, wm, wn, rA, g16, acc);       \
    } while (0)

    int tt = 0;
    for (; tt < nt - 2; ++tt) NITER(tt, true, "s_waitcnt vmcnt(6)");
    NITER(tt, false, "s_waitcnt vmcnt(3)");
    ++tt;
    NITER(tt, false, "s_waitcnt vmcnt(0)");
#undef NITER
#undef NBAR

    const int cl = lane & 15, rg = (lane >> 4) * 4;
#pragma unroll
    for (int n = 0; n < 2; ++n) {
        int gc = col0 + wn * 32 + n * 16 + cl;
        float bv = bias ? bias[gc] : 0.0f;
#pragma unroll
        for (int m = 0; m < 2; ++m) {
#pragma unroll
            for (int i = 0; i < 4; ++i) {
                int gr = row0 + wm * 32 + m * 16 + rg + i;
                float v = acc[m][n][i] + bv;
                if (res) v += res[(size_t)gr * ldc + gc];
                C[(size_t)gr * ldc + gc] = v;
            }
        }
    }
}

// ---------------------------------------------------------------------------
// Mid bf16 MFMA GEMM (qkvg, W1): 2-slot depth-1, 2 blocks/CU (round-14/15).
// SCATTER=1: q scaled by SCALE_F at scatter (QK^T and cp pick up the scale).
// ---------------------------------------------------------------------------
#define MDSLOT 32768  /* 32 KB per slot: A 16KB @0, B 16KB @16384 */

__device__ __forceinline__ void md_stage(const unsigned short* __restrict__ Ab, int lda,
                                         const unsigned short* __restrict__ Wb, int ldw,
                                         unsigned char* slot, int t, int wid) {
    int rit = t >> 3;
    int kb = (t & 7) << 4;
#pragma unroll
    for (int c = 0; c < 2; ++c) {
        int row = c * 64 + rit;
        int gkb = kb ^ ((row & 7) << 4);
        const unsigned short* src = Ab + (size_t)row * lda + (gkb >> 1);
        unsigned char* dst = slot + c * 8192 + wid * 1024;
        __builtin_amdgcn_global_load_lds(
            (const __attribute__((address_space(1))) void*)src,
            (__attribute__((address_space(3))) void*)dst, 16, 0, 0);
    }
#pragma unroll
    for (int c = 0; c < 2; ++c) {
        int row = c * 64 + rit;
        int gkb = kb ^ ((row & 7) << 4);
        const unsigned short* src = Wb + (size_t)row * ldw + (gkb >> 1);
        unsigned char* dst = slot + 16384 + c * 8192 + wid * 1024;
        __builtin_amdgcn_global_load_lds(
            (const __attribute__((address_space(1))) void*)src,
            (__attribute__((address_space(3))) void*)dst, 16, 0, 0);
    }
}

__device__ __forceinline__ void md_compute(const unsigned char* slot, int wm, int wn,
                                           int rA, int g16, f32x4 acc[4][2]) {
    const unsigned char* Ab = slot;
    const unsigned char* Bb = slot + 16384;
    bf16x8 a[4][2], b[2][2];
#pragma unroll
    for (int m = 0; m < 4; ++m) {
        int row = wm * 64 + m * 16 + rA;
        int sw = (row & 7) << 4;
#pragma unroll
        for (int s = 0; s < 2; ++s)
            a[m][s] = *(const bf16x8*)(Ab + row * 128 + ((s * 64 + g16 * 16) ^ sw));
    }
#pragma unroll
    for (int n = 0; n < 2; ++n) {
        int row = wn * 32 + n * 16 + rA;
        int sw = (row & 7) << 4;
#pragma unroll
        for (int s = 0; s < 2; ++s)
            b[n][s] = *(const bf16x8*)(Bb + row * 128 + ((s * 64 + g16 * 16) ^ sw));
    }
    __builtin_amdgcn_s_setprio(1);
#pragma unroll
    for (int m = 0; m < 4; ++m)
#pragma unroll
        for (int n = 0; n < 2; ++n) {
            acc[m][n] = __builtin_amdgcn_mfma_f32_16x16x32_bf16(a[m][0], b[n][0], acc[m][n], 0, 0, 0);
            acc[m][n] = __builtin_amdgcn_mfma_f32_16x16x32_bf16(a[m][1], b[n][1], acc[m][n], 0, 0, 0);
        }
    __builtin_amdgcn_s_setprio(0);
}

template <int SCATTER>
__global__ __launch_bounds__(512) void k_gemm_mid(const unsigned short* __restrict__ A, int lda,
                                                  const unsigned short* __restrict__ W,
                                                  const unsigned short* __restrict__ Wb2, int ldw,
                                                  unsigned short* __restrict__ Cb, int ldc,
                                                  int M, int N, int K,
                                                  const float* __restrict__ bias,
                                                  const float* __restrict__ bias2,
                                                  unsigned short* __restrict__ qT,
                                                  unsigned short* __restrict__ kT) {
    extern __shared__ unsigned char smem[];
    int nwg = gridDim.x * gridDim.y;
    int orig = blockIdx.y * gridDim.x + blockIdx.x;
    int qq = nwg >> 3, rr = nwg & 7;
    int xcd = orig & 7, idx = orig >> 3;
    int wg = (xcd < rr ? xcd * (qq + 1) : rr * (qq + 1) + (xcd - rr) * qq) + idx;
    int bx = wg % gridDim.x, by = wg / gridDim.x;

    const int t = threadIdx.x;
    const int lane = t & 63, wid = t >> 6;
    const int wm = wid >> 2, wn = wid & 3;
    const int rA = lane & 15, g16 = lane >> 4;
    const int row0 = by * 128, col0 = bx * 128;
    const unsigned short* Abase = A + (size_t)row0 * lda;
    const unsigned short* Wbase = (Wb2 && col0 >= 1536)
                                      ? Wb2 + (size_t)(col0 - 1536) * ldw
                                      : W + (size_t)col0 * ldw;

    const int nt = K >> 6;
    f32x4 acc[4][2] = {};

    md_stage(Abase, lda, Wbase, ldw, smem, t, wid);

    for (int tt = 0; tt < nt; ++tt) {
        asm volatile("s_barrier" ::: "memory");
        if (tt + 1 < nt) {
            md_stage(Abase + (size_t)(tt + 1) * 64, lda, Wbase + (size_t)(tt + 1) * 64,
                     ldw, smem + (size_t)((tt + 1) & 1) * MDSLOT, t, wid);
            asm volatile("s_waitcnt vmcnt(4)" ::: "memory");
        } else {
            asm volatile("s_waitcnt vmcnt(0)" ::: "memory");
        }
        asm volatile("s_barrier" ::: "memory");
        md_compute(smem + (size_t)(tt & 1) * MDSLOT, wm, wn, rA, g16, acc);
    }

    const int cl = lane & 15, rg = (lane >> 4) * 4;
#pragma unroll
    for (int n = 0; n < 2; ++n) {
        int gc = col0 + wn * 32 + n * 16 + cl;
        float bv = 0.0f;
        if (bias) bv = (bias2 && gc >= 1536) ? bias2[gc - 1536] : bias[gc];
        if (SCATTER && gc < 1536) {
            int isk = gc >= HH;
            unsigned short* dst = isk ? kT : qT;
            int h = (isk ? gc - HH : gc) >> 6;
            int d = gc & 63;
            float scl = isk ? 1.0f : SCALE_F;   // q pre-scaled; k unscaled
#pragma unroll
            for (int m = 0; m < 4; ++m) {
#pragma unroll
                for (int i = 0; i < 4; ++i) {
                    int gr = row0 + wm * 64 + m * 16 + rg + i;
                    int s = gr >> 3, b = gr & 7;
                    dst[(((size_t)(b * NHH + h)) * SS + s) * DD + d] = f2b((acc[m][n][i] + bv) * scl);
                }
            }
        } else {
#pragma unroll
            for (int m = 0; m < 4; ++m) {
#pragma unroll
                for (int i = 0; i < 4; ++i) {
                    int gr = row0 + wm * 64 + m * 16 + rg + i;
                    Cb[(size_t)gr * ldc + gc] = f2b(acc[m][n][i] + bv);
                }
            }
        }
    }
}

// ---------------------------------------------------------------------------
// merged: v-transpose repack (blockIdx.x<8) + cp/pc MFMA (blockIdx.x>=8)
// ---------------------------------------------------------------------------
__global__ __launch_bounds__(256) void k_repack_cppc(const unsigned short* __restrict__ qkvg,
                                                     const unsigned short* __restrict__ pp,
                                                     const unsigned short* __restrict__ qT,
                                                     const unsigned short* __restrict__ kT,
                                                     unsigned short* __restrict__ vT,
                                                     float* __restrict__ cp,
                                                     float* __restrict__ pc) {
    __shared__ unsigned char shmem[12288];
    int t = threadIdx.x;
    if (blockIdx.x < 8) {
        unsigned short (*tile)[72] = (unsigned short(*)[72])shmem;
        int bh = blockIdx.y;
        int b = bh / NHH, h = bh % NHH;
        int s0 = blockIdx.x * 64;
#pragma unroll
        for (int j = 0; j < 4; ++j) {
            int idx = t + j * 256;
            int r = idx >> 4, c4 = idx & 15;
            ushort4 u = *(const ushort4*)(qkvg + ((size_t)(s0 + r) * BB + b) * 3072 + 1536 + h * DD + c4 * 4);
            *(ushort4*)&tile[r][c4 * 4] = u;
        }
        __syncthreads();
#pragma unroll
        for (int j = 0; j < 2; ++j) {
            int idx = t + j * 256;
            int d = idx >> 3, s8 = idx & 7;
            ushort4 a, c;
            a.x = tile[s8 * 8 + 0][d]; a.y = tile[s8 * 8 + 1][d];
            a.z = tile[s8 * 8 + 2][d]; a.w = tile[s8 * 8 + 3][d];
            c.x = tile[s8 * 8 + 4][d]; c.y = tile[s8 * 8 + 5][d];
            c.z = tile[s8 * 8 + 6][d]; c.w = tile[s8 * 8 + 7][d];
            unsigned short* dst = vT + ((size_t)bh * DD + d) * SS + s0 + s8 * 8;
            *(ushort4*)dst = a; *(ushort4*)(dst + 4) = c;
        }
    } else {
        int cid = (blockIdx.x - 8) * 96 + blockIdx.y;
        int z = cid >= 384;
        int rem = cid - (z ? 384 : 0);
        int h = rem >> 5;
        int mt = rem & 31;
        int toff = z ? 0 : HH;
        float* out = z ? pc : cp;
        const unsigned short* srcbase = z ? kT : qT;
        unsigned short* As = (unsigned short*)shmem;
        unsigned short* Bs = (unsigned short*)(shmem + 8192);
        const int lane = t & 63, wid = t >> 6;
        const int rA = lane & 15, kA = (lane >> 4) * 8;

        f32x4 acc[2][4] = {};

        for (int k0 = 0; k0 < 64; k0 += 32) {
#pragma unroll
            for (int j = 0; j < 2; ++j) {
                int c = t + j * 256;
                int r = c >> 2, ko = (c & 3) * 8;
                int row = mt * 128 + r;
                int s = row >> 3, b = row & 7;
                const unsigned short* srcA =
                    srcbase + (((size_t)(b * NHH + h)) * SS + s) * DD + k0 + ko;
                unsigned short* dstA = As + (size_t)(j * 256 + wid * 64) * 8;
                __builtin_amdgcn_global_load_lds(
                    (const __attribute__((address_space(1))) void*)srcA,
                    (__attribute__((address_space(3))) void*)dstA, 16, 0, 0);
            }
            {
                int r = t >> 2, ko = (t & 3) * 8;
                const unsigned short* srcB = pp + (size_t)r * 1536 + toff + h * DD + k0 + ko;
                unsigned short* dstB = Bs + (size_t)(wid * 64) * 8;
                __builtin_amdgcn_global_load_lds(
                    (const __attribute__((address_space(1))) void*)srcB,
                    (__attribute__((address_space(3))) void*)dstB, 16, 0, 0);
            }
            __syncthreads();
            bf16x8 af[2], bfr[4];
#pragma unroll
            for (int m = 0; m < 2; ++m)
                af[m] = *(const bf16x8*)&As[(wid * 32 + m * 16 + rA) * 32 + kA];
#pragma unroll
            for (int n = 0; n < 4; ++n)
                bfr[n] = *(const bf16x8*)&Bs[(n * 16 + rA) * 32 + kA];
#pragma unroll
            for (int m = 0; m < 2; ++m)
#pragma unroll
                for (int n = 0; n < 4; ++n)
                    acc[m][n] = __builtin_amdgcn_mfma_f32_16x16x32_bf16(af[m], bfr[n], acc[m][n], 0, 0, 0);
            __syncthreads();
        }

        const int cl = lane & 15, rg = (lane >> 4) * 4;
#pragma unroll
        for (int m = 0; m < 2; ++m)
#pragma unroll
            for (int n = 0; n < 4; ++n) {
                int gc = n * 16 + cl;
                if (gc < 63) {
#pragma unroll
                    for (int i = 0; i < 4; ++i) {
                        int gr = mt * 128 + wid * 32 + m * 16 + rg + i;
                        int sIdx = gr >> 3, bIdx = gr & 7;
                        out[(((size_t)(bIdx * NHH + h)) * SS + sIdx) * 63 + gc] = acc[m][n][i];
                    }
                }
            }
    }
}

// ---------------------------------------------------------------------------
// fused disentangled flash attention v6: no-max softmax, SCALE pre-folded
// into q and qpos (score = sa + cps + pcs directly, no per-element mul).
// ---------------------------------------------------------------------------
__global__ __launch_bounds__(256) void k_attn_fused(
    const unsigned short* __restrict__ qT, const unsigned short* __restrict__ kT,
    const unsigned short* __restrict__ vT, const float* __restrict__ cp,
    const float* __restrict__ pc, const int* __restrict__ bucket,
    const int* __restrict__ mask, float* __restrict__ ctxr) {
    __shared__ float cps[64 * 63];
    __shared__ float pcs[64 * 63];
    __shared__ unsigned short pb_all[4][16 * 72];
    __shared__ int btab[1023];
    int t = threadIdx.x;
    int lane = t & 63, wid = t >> 6;
    int bh = blockIdx.y;
    int b = bh / NHH, h = bh % NHH;
    int qb0 = blockIdx.x * 64;
    int q0 = qb0 + wid * 16;
    int rA = lane & 15, g = lane >> 4, kA = g * 8;
    unsigned short* pb = pb_all[wid];
    const unsigned short* qTb = qT + (size_t)bh * SS * DD;
    const unsigned short* kTb = kT + (size_t)bh * SS * DD;
    const unsigned short* vTb = vT + (size_t)bh * DD * SS;
    const float* cpb = cp + (size_t)bh * SS * 63 + (size_t)qb0 * 63;
    const float* pcb = pc + (size_t)bh * SS * 63;
    const int* mkb = mask + b * SS;

    for (int i = t; i < 1023; i += 256) btab[i] = bucket[i];
    for (int i = t; i < 1008; i += 256) ((float4*)cps)[i] = ((const float4*)cpb)[i];

    bf16x8 aq[2];
#pragma unroll
    for (int dc = 0; dc < 2; ++dc)
        aq[dc] = *(const bf16x8*)&qTb[(size_t)(q0 + rA) * DD + dc * 32 + kA];

    f32x4 o[4] = {};
    float lrow[4];
#pragma unroll
    for (int i = 0; i < 4; ++i) lrow[i] = 0.f;

    for (int kt = 0; kt < 8; ++kt) {
        int k0 = kt * 64;
        __syncthreads();
        {
            const float4* src = (const float4*)(pcb + (size_t)k0 * 63);
            for (int i = t; i < 1008; i += 256) ((float4*)pcs)[i] = src[i];
        }
        f32x4 sa[4] = {};
#pragma unroll
        for (int n = 0; n < 4; ++n) {
            bf16x8 bk0 = *(const bf16x8*)&kTb[(size_t)(k0 + n * 16 + rA) * DD + kA];
            bf16x8 bk1 = *(const bf16x8*)&kTb[(size_t)(k0 + n * 16 + rA) * DD + 32 + kA];
            sa[n] = __builtin_amdgcn_mfma_f32_16x16x32_bf16(aq[0], bk0, sa[n], 0, 0, 0);
            sa[n] = __builtin_amdgcn_mfma_f32_16x16x32_bf16(aq[1], bk1, sa[n], 0, 0, 0);
        }
        int mk[4];
#pragma unroll
        for (int n = 0; n < 4; ++n) mk[n] = mkb[k0 + n * 16 + rA];
        __syncthreads();

        float pv[4][4];
#pragma unroll
        for (int i = 0; i < 4; ++i) {
            int qr = wid * 16 + g * 4 + i;
            int q = qb0 + qr;
            float ls = 0.f;
#pragma unroll
            for (int n = 0; n < 4; ++n) {
                int kr = n * 16 + rA;
                int id = btab[q - (k0 + kr) + 511];
                float v = sa[n][i] + cps[qr * 63 + id] + pcs[kr * 63 + id];
                v = mk[n] ? -1e9f : v;
                float p = __expf(v);   // masked -> exp(-1e9) == 0 exactly
                pv[n][i] = p;
                ls += p;
            }
            ls += __shfl_xor(ls, 1, 16);
            ls += __shfl_xor(ls, 2, 16);
            ls += __shfl_xor(ls, 4, 16);
            ls += __shfl_xor(ls, 8, 16);
            lrow[i] += ls;
        }
#pragma unroll
        for (int n = 0; n < 4; ++n)
#pragma unroll
            for (int i = 0; i < 4; ++i)
                pb[(g * 4 + i) * 72 + n * 16 + rA] = f2b(pv[n][i]);
        bf16x8 ap[2];
#pragma unroll
        for (int kc = 0; kc < 2; ++kc)
            ap[kc] = *(const bf16x8*)&pb[rA * 72 + kc * 32 + kA];
#pragma unroll
        for (int n = 0; n < 4; ++n) {
            bf16x8 bv0 = *(const bf16x8*)&vTb[(size_t)(n * 16 + rA) * SS + k0 + kA];
            bf16x8 bv1 = *(const bf16x8*)&vTb[(size_t)(n * 16 + rA) * SS + k0 + 32 + kA];
            o[n] = __builtin_amdgcn_mfma_f32_16x16x32_bf16(ap[0], bv0, o[n], 0, 0, 0);
            o[n] = __builtin_amdgcn_mfma_f32_16x16x32_bf16(ap[1], bv1, o[n], 0, 0, 0);
        }
    }
#pragma unroll
    for (int i = 0; i < 4; ++i) {
        int q = q0 + g * 4 + i;
        float inv = 1.0f / lrow[i];
#pragma unroll
        for (int n = 0; n < 4; ++n)
            ctxr[((size_t)q * BB + b) * HH + h * DD + n * 16 + rA] = o[n][i] * inv;
    }
}

// ---------------------------------------------------------------------------
// host launcher
// ---------------------------------------------------------------------------
extern "C" void kernel_launch(void* const* d_in, const int* in_sizes, int n_in,
                              void* d_out, int out_size, void* d_ws, size_t ws_size,
                              hipStream_t stream) {
    static int attr_done = 0;
    if (!attr_done) {
        hipFuncSetAttribute((const void*)&k_gemm_mid<0>,
                            hipFuncAttributeMaxDynamicSharedMemorySize, 2 * MDSLOT);
        hipFuncSetAttribute((const void*)&k_gemm_mid<1>,
                            hipFuncAttributeMaxDynamicSharedMemorySize, 2 * MDSLOT);
        hipFuncSetAttribute((const void*)&k_gemm_n64,
                            hipFuncAttributeMaxDynamicSharedMemorySize, 3 * N64SLOT);
        attr_done = 1;
    }

    const int* ids = (const int*)d_in[0];
    const unsigned char* maskraw = (const unsigned char*)d_in[1];
    const float* word_emb = (const float*)d_in[2];
    const float* rel_emb = (const float*)d_in[3];
    const float* rel_g = (const float*)d_in[4];
    const float* rel_b = (const float*)d_in[5];
    const float* Wqk = (const float*)d_in[6];
    const float* bqk = (const float*)d_in[7];
    const float* Wvg = (const float*)d_in[8];
    const float* bvg = (const float*)d_in[9];
    const float* Wout = (const float*)d_in[10];
    const float* bout = (const float*)d_in[11];
    const float* W1 = (const float*)d_in[12];
    const float* W2 = (const float*)d_in[13];

    const size_t N_X = (size_t)SS * BB * HH;
    const size_t N_CP = (size_t)SS * BB * NHH * 63;
    const size_t N_H2 = (size_t)SS * BB * II;
    const size_t N_WQK = (size_t)2 * HH * HH;
    const size_t N_WOUT = (size_t)HH * HH;
    const size_t N_W1 = (size_t)2 * II * HH;
    const size_t N_W2 = (size_t)HH * II;
    const size_t N_HD = (size_t)BB * NHH * SS * DD;
    const size_t N_QKVG = (size_t)SS * BB * 3072;
    const size_t N_FFH = (size_t)SS * BB * 4096;
    const size_t N_PP = (size_t)128 * 1536;

    float* ws = (float*)d_ws;
    float* x = ws;
    float* ctxr = x + N_X;
    float* cp = ctxr + N_X;
    float* pc = cp + N_CP;
    unsigned short* us = (unsigned short*)(pc + N_CP);
    unsigned short* qkvg = us;
    unsigned short* hs_bf = qkvg + N_QKVG;
    unsigned short* ctx_bf = hs_bf + N_X;
    unsigned short* h2_bf = ctx_bf + N_X;
    unsigned short* ffh = h2_bf + N_H2;
    unsigned short* wqk_all = ffh + N_FFH;
    unsigned short* wvg_bf = wqk_all + 12 * N_WQK;
    unsigned short* wout_bf = wvg_bf + N_WQK;
    unsigned short* w1_bf = wout_bf + N_WOUT;
    unsigned short* w2_bf = w1_bf + N_W1;
    unsigned short* ppall = w2_bf + N_W2;
    unsigned short* rel_bf = ppall + 12 * N_PP;
    unsigned short* qT = rel_bf + 128 * HH;
    unsigned short* kT = qT + N_HD;
    unsigned short* vT = kT + N_HD;
    int* bucket = (int*)(vT + N_HD);
    int* maski = bucket + 1024;

    size_t need_bytes = ((size_t)(maski + BB * SS) - (size_t)d_ws);
    if (ws_size < need_bytes) return;  // ~205 MB required

    // ---- setup ----
    k_decode_mask<<<1, 256, 0, stream>>>(maskraw, maski, BB * SS);
    k_bucket<<<4, 256, 0, stream>>>(bucket);
    k_embed_ln<<<SS * BB, 256, 0, stream>>>(ids, word_emb, x);
    k_rel_ln_bf<<<128, 256, 0, stream>>>(rel_emb, rel_g, rel_b, rel_bf);
    k_f2b<<<(int)((12 * N_WQK / 8 + 255) / 256), 256, 0, stream>>>(Wqk, wqk_all,
                                                                   (int)(12 * N_WQK / 8));
    {
        dim3 gpp(1536 / 128, 1, 12);
        k_gemm_bf16<1><<<gpp, 256, 0, stream>>>(rel_bf, HH, wqk_all, HH, ppall, 1536,
                                                128, 1536, HH, bqk, nullptr, nullptr,
                                                N_WQK, N_PP, 2 * HH);
    }

    for (int l = 0; l < LL; ++l) {
        const unsigned short* wqk_l = wqk_all + (size_t)l * N_WQK;
        const float* bqk_l = bqk + (size_t)l * 2 * HH;
        const float* Wvg_l = Wvg + (size_t)l * N_WQK;
        const float* bvg_l = bvg + (size_t)l * 2 * HH;
        const float* Wout_l = Wout + (size_t)l * N_WOUT;
        const float* bout_l = bout + (size_t)l * HH;
        const float* W1_l = W1 + (size_t)l * N_W1;
        const float* W2_l = W2 + (size_t)l * N_W2;

        // ---- attention ----
        k_f2b_ln<<<3169 + SS * BB, 256, 0, stream>>>(Wvg_l, Wout_l, W1_l, W2_l, wvg_bf,
                                                     x, hs_bf);
        {
            dim3 g(3072 / 128, SS * BB / 128);
            k_gemm_mid<1><<<g, 512, 2 * MDSLOT, stream>>>(hs_bf, HH, wqk_l, wvg_bf, HH,
                                                          qkvg, 3072, SS * BB, 3072, HH,
                                                          bqk_l, bvg_l, qT, kT);
        }
        k_repack_cppc<<<dim3(16, 96), 256, 0, stream>>>(qkvg, ppall + (size_t)l * N_PP,
                                                        qT, kT, vT, cp, pc);
        k_attn_fused<<<dim3(SS / 64, BB * NHH), 256, 0, stream>>>(qT, kT, vT, cp, pc,
                                                                  bucket, maski, ctxr);
        k_gated_ln<<<SS * BB, 256, 0, stream>>>(ctxr, qkvg, ctx_bf);
        k_gemm_n64<<<dim3(HH / 64, SS * BB / 128), 512, 3 * N64SLOT, stream>>>(
            ctx_bf, HH, wout_bf, HH, x, HH, SS * BB, HH, HH, bout_l, x);

        // ---- GeGLU FFN ----
        k_ln_bf<<<SS * BB, 256, 0, stream>>>(x, hs_bf);
        {
            dim3 g(4096 / 128, SS * BB / 128);
            k_gemm_mid<0><<<g, 512, 2 * MDSLOT, stream>>>(hs_bf, HH, w1_bf, nullptr, HH,
                                                          ffh, 4096, SS * BB, 4096, HH,
                                                          nullptr, nullptr, nullptr, nullptr);
        }
        k_ffn_ln<<<SS * BB, 256, 0, stream>>>(ffh, h2_bf);
        // last layer writes the residual-added output straight into d_out
        float* outC = (l == LL - 1) ? (float*)d_out : x;
        k_gemm_n64<<<dim3(HH / 64, SS * BB / 128), 512, 3 * N64SLOT, stream>>>(
            h2_bf, II, w2_bf, II, outC, HH, SS * BB, HH, II, nullptr, x);
    }
}